// Round 4
// baseline (463.372 us; speedup 1.0000x reference)
//
#include <hip/hip_runtime.h>
#include <vector>
#include <algorithm>
#include <cstdint>
#include <cstring>
#include <cmath>

// ===================== host-side JAX threefry replication =====================
static inline uint32_t tf_rotl(uint32_t x, int r) { return (x << r) | (x >> (32 - r)); }

static void tf2x32(uint32_t k0, uint32_t k1, uint32_t x0, uint32_t x1,
                   uint32_t* o0, uint32_t* o1) {
  uint32_t ks2 = k0 ^ k1 ^ 0x1BD11BDAu;
  uint32_t v0 = x0 + k0, v1 = x1 + k1;
  static const int R0[4] = {13, 15, 26, 6}, R1[4] = {17, 29, 16, 24};
#define RND4(R) do { for (int i_ = 0; i_ < 4; ++i_) { v0 += v1; v1 = tf_rotl(v1, R[i_]); v1 ^= v0; } } while (0)
  RND4(R0); v0 += k1;  v1 += ks2 + 1u;
  RND4(R1); v0 += ks2; v1 += k0 + 2u;
  RND4(R0); v0 += k0;  v1 += k1 + 3u;
  RND4(R1); v0 += k1;  v1 += ks2 + 4u;
  RND4(R0); v0 += ks2; v1 += k0 + 5u;
#undef RND4
  *o0 = v0; *o1 = v1;
}

static void jax_permutation(uint32_t seed, int n, int rounds, int* x) {
  uint32_t k0 = 0u, k1 = seed;
  for (int i = 0; i < n; ++i) x[i] = i;
  std::vector<uint32_t> bits(n);
  std::vector<int> ord(n), xn(n);
  for (int r = 0; r < rounds; ++r) {
    uint32_t nk0, nk1, sk0, sk1;
    tf2x32(k0, k1, 0u, 0u, &nk0, &nk1);
    tf2x32(k0, k1, 0u, 1u, &sk0, &sk1);
    for (int i = 0; i < n; ++i) {
      uint32_t h, l;
      tf2x32(sk0, sk1, 0u, (uint32_t)i, &h, &l);
      bits[i] = h ^ l;
    }
    for (int i = 0; i < n; ++i) ord[i] = i;
    std::stable_sort(ord.begin(), ord.end(),
                     [&](int a, int b) { return bits[a] < bits[b]; });
    for (int i = 0; i < n; ++i) xn[i] = x[ord[i]];
    memcpy(x, xn.data(), (size_t)n * sizeof(int));
    k0 = nk0; k1 = nk1;
  }
}

// ===================== device kernels =====================
#define NEI 20

__device__ __forceinline__ float san(float v) {
  v = (v != v) ? 0.0f : v;
  return fmaxf(-1e4f, fminf(v, 1e4f));
}

// fused setup: blocks 0..63 sanitize vertices -> AoS + packed float4{x,y,z,sq};
// blocks 64..87 normalize the 5 direction matrices.
__global__ void k_setup(const float* __restrict__ vin, float* __restrict__ outA,
                        float4* __restrict__ pk, int nverts,
                        const float* __restrict__ d0, const float* __restrict__ d1,
                        const float* __restrict__ d2, const float* __restrict__ d3,
                        const float* __restrict__ d4,
                        float* __restrict__ s0, float* __restrict__ s1,
                        float* __restrict__ s2, float* __restrict__ s3,
                        float* __restrict__ s4) {
  int blk = blockIdx.x;
  if (blk < 64) {
    int i = blk * 256 + threadIdx.x;
    if (i >= nverts) return;
    float x = san(vin[3 * i]), y = san(vin[3 * i + 1]), z = san(vin[3 * i + 2]);
    outA[3 * i] = x; outA[3 * i + 1] = y; outA[3 * i + 2] = z;
    pk[i] = make_float4(x, y, z, x * x + y * y + z * z);
    return;
  }
  int t = (blk - 64) * 256 + threadIdx.x;
  const float* d; float* s; int E, e;
  if (t < 128)       { d = d0; s = s0; E = 128;  e = t; }
  else if (t < 384)  { d = d1; s = s1; E = 256;  e = t - 128; }
  else if (t < 896)  { d = d2; s = s2; E = 512;  e = t - 384; }
  else if (t < 1920) { d = d3; s = s3; E = 1024; e = t - 896; }
  else if (t < 6016) { d = d4; s = s4; E = 4096; e = t - 1920; }
  else return;
  float a = san(d[e]);
  float b = san(d[E + e]);
  float c = san(d[2 * E + e]);
  float nrm = sqrtf(a * a + b * b + c * c);
  float m = fmaxf(nrm, 1e-12f);
  s[e] = a / m; s[E + e] = b / m; s[2 * E + e] = c / m;
}

// total-order map for fp32 bits: monotone u32 for any float (handles negatives)
__device__ __forceinline__ unsigned fmap(float f) {
  unsigned u = __float_as_uint(f);
  return u ^ ((u & 0x80000000u) ? 0xFFFFFFFFu : 0x80000000u);
}

// --- 64-lane u32 min, broadcast via readlane (SGPR, no LDS round-trip) ---
__device__ __forceinline__ unsigned dpp_min_bcast1(unsigned a) {
  unsigned t;
  t = (unsigned)__builtin_amdgcn_update_dpp((int)a, (int)a, 0xB1, 0xF, 0xF, true);
  a = t < a ? t : a;
  t = (unsigned)__builtin_amdgcn_update_dpp((int)a, (int)a, 0x4E, 0xF, 0xF, true);
  a = t < a ? t : a;
  t = (unsigned)__builtin_amdgcn_update_dpp((int)a, (int)a, 0x141, 0xF, 0xF, true);
  a = t < a ? t : a;
  t = (unsigned)__builtin_amdgcn_update_dpp((int)a, (int)a, 0x140, 0xF, 0xF, true);
  a = t < a ? t : a;
  t = (unsigned)__builtin_amdgcn_update_dpp((int)a, (int)a, 0x142, 0xA, 0xF, false);
  a = t < a ? t : a;
  t = (unsigned)__builtin_amdgcn_update_dpp((int)a, (int)a, 0x143, 0xC, 0xF, false);
  a = t < a ? t : a;
  return (unsigned)__builtin_amdgcn_readlane((int)a, 63);
}

__device__ __forceinline__ void dpp_min_bcast2(unsigned& a, unsigned& b) {
  unsigned t0, t1;
#define STEP_DPP(ctrl, rm, bc)                                                           \
  t0 = (unsigned)__builtin_amdgcn_update_dpp((int)a, (int)a, ctrl, rm, 0xF, bc);         \
  t1 = (unsigned)__builtin_amdgcn_update_dpp((int)b, (int)b, ctrl, rm, 0xF, bc);         \
  a = t0 < a ? t0 : a; b = t1 < b ? t1 : b;
  STEP_DPP(0xB1, 0xF, true)
  STEP_DPP(0x4E, 0xF, true)
  STEP_DPP(0x141, 0xF, true)
  STEP_DPP(0x140, 0xF, true)
  STEP_DPP(0x142, 0xA, false)
  STEP_DPP(0x143, 0xC, false)
#undef STEP_DPP
  a = (unsigned)__builtin_amdgcn_readlane((int)a, 63);
  b = (unsigned)__builtin_amdgcn_readlane((int)b, 63);
}

// KNN v10 (R15-proven, ~90 µs): u64-key sorted top-3 queues, float4 candidate
// loads, readlane broadcasts. DO NOT split the u64 key: R13's dist-only compare
// dropped equal-dist/smaller-index candidates (real bug, found R15 post-mortem).
// Dual-queue variants (R11/R12) spilled to scratch — do not revisit.
template <int VCAND>
__global__ __launch_bounds__(256, 8) void k_knn8(const float4* __restrict__ pk,
                                                 int* __restrict__ nidx, int V) {
  const int wid = threadIdx.x >> 6;
  const int lane = threadIdx.x & 63;
  const int row0 = blockIdx.x * 8 + wid * 2;
  const int b = row0 / V;
  const int base = b * V;
  const int i0 = row0 % V;

  float xi[2], yi[2], zi[2], sqi[2];
#pragma unroll
  for (int t = 0; t < 2; ++t) {
    float4 q = pk[base + i0 + t];
    xi[t] = q.x; yi[t] = q.y; zi[t] = q.z; sqi[t] = q.w;
  }

  unsigned long long q0[2] = {~0ULL, ~0ULL}, q1[2] = {~0ULL, ~0ULL}, q2[2] = {~0ULL, ~0ULL};
#pragma unroll 4
  for (int c = 0; c < VCAND; ++c) {
    int j = c * 64 + lane;
    float4 cj = pk[base + j];
    float xj = cj.x, yj = cj.y, zj = cj.z, sqj = cj.w;
#pragma unroll
    for (int t = 0; t < 2; ++t) {
      float dot = xi[t] * xj + yi[t] * yj + zi[t] * zj;
      float dd = (sqi[t] + sqj) - 2.0f * dot;
      unsigned long long k = (((unsigned long long)fmap(dd)) << 32) | (unsigned)j;
      if (k < q2[t]) {
        if (k < q1[t]) {
          q2[t] = q1[t];
          if (k < q0[t]) { q1[t] = q0[t]; q0[t] = k; } else { q1[t] = k; }
        } else {
          q2[t] = k;
        }
      }
    }
  }

  for (int r = 0; r < 21; ++r) {
    unsigned h0 = (unsigned)(q0[0] >> 32);
    unsigned h1 = (unsigned)(q0[1] >> 32);
    unsigned m0 = h0, m1 = h1;
    dpp_min_bcast2(m0, m1);
    unsigned long long mk0 = __ballot(h0 == m0);
    unsigned long long mk1 = __ballot(h1 == m1);
    bool win0, win1;
    if (__popcll(mk0) > 1) {  // rare: dist-bit tie across lanes -> index min
      unsigned jj = (h0 == m0) ? (unsigned)q0[0] : 0xFFFFFFFFu;
      unsigned jm = dpp_min_bcast1(jj);
      win0 = (h0 == m0) && ((unsigned)q0[0] == jm);
    } else {
      win0 = (h0 == m0);
    }
    if (__popcll(mk1) > 1) {
      unsigned jj = (h1 == m1) ? (unsigned)q0[1] : 0xFFFFFFFFu;
      unsigned jm = dpp_min_bcast1(jj);
      win1 = (h1 == m1) && ((unsigned)q0[1] == jm);
    } else {
      win1 = (h1 == m1);
    }
    if (win0) {
      if (r > 0) nidx[(size_t)row0 * NEI + (r - 1)] = (int)(unsigned)q0[0];
      unsigned long long bound = q0[0];
      q0[0] = q1[0]; q1[0] = q2[0]; q2[0] = ~0ULL;
      if (q0[0] == ~0ULL) {
        unsigned long long nm = ~0ULL;
        for (int c = 0; c < VCAND; ++c) {
          int j = c * 64 + lane;
          float4 cj = pk[base + j];
          float dot = xi[0] * cj.x + yi[0] * cj.y + zi[0] * cj.z;
          float dd = (sqi[0] + cj.w) - 2.0f * dot;
          unsigned long long k = (((unsigned long long)fmap(dd)) << 32) | (unsigned)j;
          if (k > bound && k < nm) nm = k;
        }
        q0[0] = nm;
      }
    }
    if (win1) {
      if (r > 0) nidx[(size_t)(row0 + 1) * NEI + (r - 1)] = (int)(unsigned)q0[1];
      unsigned long long bound = q0[1];
      q0[1] = q1[1]; q1[1] = q2[1]; q2[1] = ~0ULL;
      if (q0[1] == ~0ULL) {
        unsigned long long nm = ~0ULL;
        for (int c = 0; c < VCAND; ++c) {
          int j = c * 64 + lane;
          float4 cj = pk[base + j];
          float dot = xi[1] * cj.x + yi[1] * cj.y + zi[1] * cj.z;
          float dd = (sqi[1] + cj.w) - 2.0f * dot;
          unsigned long long k = (((unsigned long long)fmap(dd)) << 32) | (unsigned)j;
          if (k > bound && k < nm) nm = k;
        }
        q0[1] = nm;
      }
    }
  }
}

// conv_surface: C=32, E=128. One block (128 thr) per (b,v).
__global__ __launch_bounds__(128) void k_conv_surface(const float* __restrict__ verts,
                                                      const int* __restrict__ nidx,
                                                      const float* __restrict__ sd,
                                                      float* __restrict__ fm, int V) {
  int row = blockIdx.x;
  int b = row / V, v = row % V;
  const float* vb = verts + (size_t)b * V * 3;
  __shared__ float nd[60];
  __shared__ float mcol[128];
  int tid = threadIdx.x;
  if (tid < NEI) {
    int j = nidx[(size_t)row * NEI + tid];
    float dx = vb[3 * j] - vb[3 * v];
    float dy = vb[3 * j + 1] - vb[3 * v + 1];
    float dz = vb[3 * j + 2] - vb[3 * v + 2];
    float nrm = sqrtf(dx * dx + dy * dy + dz * dz);
    float m = fmaxf(nrm, 1e-12f);
    nd[tid * 3] = dx / m; nd[tid * 3 + 1] = dy / m; nd[tid * 3 + 2] = dz / m;
  }
  __syncthreads();
  {
    int e = tid;
    float s0 = sd[e], s1 = sd[128 + e], s2 = sd[256 + e];
    float me = 0.0f;
#pragma unroll
    for (int n = 0; n < NEI; ++n) {
      float th = nd[3 * n] * s0 + nd[3 * n + 1] * s1 + nd[3 * n + 2] * s2;
      th = fmaxf(th, 0.0f);
      me = fmaxf(me, th);
    }
    mcol[e] = me;
  }
  __syncthreads();
  if (tid < 32) {
    float o = mcol[tid] + mcol[32 + tid] + mcol[64 + tid] + mcol[96 + tid];
    o = fmaxf(o, 0.0f);
    fm[(size_t)row * 32 + tid] = o;
  }
}

// fp32 tiled GEMM 64x64x16 (guarded; used for layer1): C = A*W + bias
__global__ __launch_bounds__(256) void k_gemm_bias(const float* __restrict__ A,
                                                   const float* __restrict__ W,
                                                   const float* __restrict__ bias,
                                                   float* __restrict__ Cm,
                                                   int M, int N, int K) {
  __shared__ float As[16][68];
  __shared__ float Bs[16][68];
  int n0 = blockIdx.x * 64, m0 = blockIdx.y * 64;
  int tx = threadIdx.x & 15, ty = threadIdx.x >> 4;
  float acc[4][4] = {};
  for (int k0 = 0; k0 < K; k0 += 16) {
    for (int t = threadIdx.x; t < 1024; t += 256) {
      int mm = t >> 4, kk = t & 15;
      int m = m0 + mm;
      As[kk][mm] = (m < M) ? A[(size_t)m * K + (k0 + kk)] : 0.0f;
    }
    for (int t = threadIdx.x; t < 1024; t += 256) {
      int kk = t >> 6, nn = t & 63;
      int n = n0 + nn;
      Bs[kk][nn] = (n < N) ? san(W[(size_t)(k0 + kk) * N + n]) : 0.0f;
    }
    __syncthreads();
#pragma unroll
    for (int kk = 0; kk < 16; ++kk) {
      float4 av = *(const float4*)&As[kk][ty << 2];
      float4 bv = *(const float4*)&Bs[kk][tx << 2];
      float a[4] = {av.x, av.y, av.z, av.w};
      float bb[4] = {bv.x, bv.y, bv.z, bv.w};
#pragma unroll
      for (int i = 0; i < 4; ++i)
#pragma unroll
        for (int j = 0; j < 4; ++j) acc[i][j] += a[i] * bb[j];
    }
    __syncthreads();
  }
  for (int i = 0; i < 4; ++i)
    for (int j = 0; j < 4; ++j) {
      int m = m0 + (ty << 2) + i, n = n0 + (tx << 2) + j;
      if (m < M && n < N) Cm[(size_t)m * N + n] = acc[i][j] + san(bias[n]);
    }
}

// fp32 tiled GEMM 128x128x32, requires M%128==0, N%128==0, K%32==0.
__global__ __launch_bounds__(256) void k_gemm128(const float* __restrict__ A,
                                                 const float* __restrict__ W,
                                                 const float* __restrict__ bias,
                                                 float* __restrict__ Cm,
                                                 int M, int N, int K) {
  __shared__ float As[32][132];
  __shared__ float Bs[32][132];
  const int n0 = blockIdx.x * 128, m0 = blockIdx.y * 128;
  const int tx = threadIdx.x & 15, ty = threadIdx.x >> 4;
  const int bm = ty * 8;
  float acc[8][8] = {};
  float bias_lo[4], bias_hi[4];
#pragma unroll
  for (int j = 0; j < 4; ++j) {
    bias_lo[j] = san(bias[n0 + tx * 4 + j]);
    bias_hi[j] = san(bias[n0 + 64 + tx * 4 + j]);
  }
  for (int k0 = 0; k0 < K; k0 += 32) {
#pragma unroll
    for (int r = 0; r < 4; ++r) {
      int t = r * 256 + threadIdx.x;
      int mm = t >> 3, kk = (t & 7) * 4;
      float4 v = *(const float4*)&A[(size_t)(m0 + mm) * K + k0 + kk];
      As[kk + 0][mm] = v.x; As[kk + 1][mm] = v.y; As[kk + 2][mm] = v.z; As[kk + 3][mm] = v.w;
    }
#pragma unroll
    for (int r = 0; r < 4; ++r) {
      int t = r * 256 + threadIdx.x;
      int kk = t >> 5, nn = (t & 31) * 4;
      float4 v = *(const float4*)&W[(size_t)(k0 + kk) * N + n0 + nn];
      *(float4*)&Bs[kk][nn] = v;
    }
    __syncthreads();
#pragma unroll
    for (int kk = 0; kk < 32; ++kk) {
      float4 a0 = *(const float4*)&As[kk][bm];
      float4 a1 = *(const float4*)&As[kk][bm + 4];
      float4 b0 = *(const float4*)&Bs[kk][tx * 4];
      float4 b1 = *(const float4*)&Bs[kk][64 + tx * 4];
      float a[8] = {a0.x, a0.y, a0.z, a0.w, a1.x, a1.y, a1.z, a1.w};
      float bb[8] = {b0.x, b0.y, b0.z, b0.w, b1.x, b1.y, b1.z, b1.w};
#pragma unroll
      for (int i = 0; i < 8; ++i)
#pragma unroll
        for (int j = 0; j < 8; ++j) acc[i][j] += a[i] * bb[j];
    }
    __syncthreads();
  }
#pragma unroll
  for (int i = 0; i < 8; ++i) {
    int m = m0 + bm + i;
    float4 lo = {acc[i][0] + bias_lo[0], acc[i][1] + bias_lo[1],
                 acc[i][2] + bias_lo[2], acc[i][3] + bias_lo[3]};
    float4 hi = {acc[i][4] + bias_hi[0], acc[i][5] + bias_hi[1],
                 acc[i][6] + bias_hi[2], acc[i][7] + bias_hi[3]};
    *(float4*)&Cm[(size_t)m * N + n0 + tx * 4] = lo;
    *(float4*)&Cm[(size_t)m * N + n0 + 64 + tx * 4] = hi;
  }
}

// conv layer: out[c] = f[row][c] + sum_s max_n relu(nd_n . sd_e) * f[j_n][C+e]
// v2: each thread owns 4 consecutive e-channels; the 20 neighbor gathers
// become float4 loads (4x fewer load instructions + address chains, same
// bytes, coalescing preserved). Launch with blockDim = E/4 (64..1024).
// Per-e expressions, mcol layout, and max/sum orders identical to v1.
__global__ __launch_bounds__(1024) void k_conv_layer(const float* __restrict__ f,
                                                     const float* __restrict__ verts,
                                                     const int* __restrict__ nidx,
                                                     const float* __restrict__ sd,
                                                     float* __restrict__ outf,
                                                     int V, int C, int relu_out) {
  int row = blockIdx.x;
  int b = row / V, v = row % V;
  int E = 4 * C;
  extern __shared__ float sm[];
  float* mcol = sm;
  float* nd = sm + E;
  int* jr = (int*)(nd + 60);
  int tid = threadIdx.x;
  const float* vb = verts + (size_t)b * V * 3;
  if (tid < NEI) {
    int j = nidx[(size_t)row * NEI + tid];
    jr[tid] = j;
    float dx = vb[3 * j] - vb[3 * v];
    float dy = vb[3 * j + 1] - vb[3 * v + 1];
    float dz = vb[3 * j + 2] - vb[3 * v + 2];
    float nrm = sqrtf(dx * dx + dy * dy + dz * dz);
    float m = fmaxf(nrm, 1e-12f);
    nd[tid * 3] = dx / m; nd[tid * 3 + 1] = dy / m; nd[tid * 3 + 2] = dz / m;
  }
  __syncthreads();
  size_t fb = (size_t)b * V;
  int fivec = 5 * C;
  int G = E >> 2;
  for (int g = tid; g < G; g += blockDim.x) {
    int e = g << 2;
    float4 sa = *(const float4*)&sd[e];
    float4 sb = *(const float4*)&sd[E + e];
    float4 sc = *(const float4*)&sd[2 * E + e];
    float me0 = -INFINITY, me1 = -INFINITY, me2 = -INFINITY, me3 = -INFINITY;
#pragma unroll
    for (int n = 0; n < NEI; ++n) {
      float n0 = nd[3 * n], n1 = nd[3 * n + 1], n2 = nd[3 * n + 2];
      float4 fv = *(const float4*)&f[(fb + jr[n]) * (size_t)fivec + C + e];
      float th0 = fmaxf(n0 * sa.x + n1 * sb.x + n2 * sc.x, 0.0f);
      float th1 = fmaxf(n0 * sa.y + n1 * sb.y + n2 * sc.y, 0.0f);
      float th2 = fmaxf(n0 * sa.z + n1 * sb.z + n2 * sc.z, 0.0f);
      float th3 = fmaxf(n0 * sa.w + n1 * sb.w + n2 * sc.w, 0.0f);
      me0 = fmaxf(me0, th0 * fv.x);
      me1 = fmaxf(me1, th1 * fv.y);
      me2 = fmaxf(me2, th2 * fv.z);
      me3 = fmaxf(me3, th3 * fv.w);
    }
    mcol[e] = me0; mcol[e + 1] = me1; mcol[e + 2] = me2; mcol[e + 3] = me3;
  }
  __syncthreads();
  for (int c = tid; c < C; c += blockDim.x) {
    float o = f[(size_t)row * fivec + c] + mcol[c] + mcol[C + c] + mcol[2 * C + c] + mcol[3 * C + c];
    if (relu_out) o = fmaxf(o, 0.0f);
    outf[(size_t)row * C + c] = o;
  }
}

// transpose (B, V, C) -> (B, C, V), 32x32 LDS tiles, coalesced both sides
__global__ __launch_bounds__(256) void k_transpose_vc(const float* __restrict__ in,
                                                      float* __restrict__ out,
                                                      int V, int C) {
  __shared__ float tile[32][33];
  int b = blockIdx.z;
  int c0 = blockIdx.x * 32, v0 = blockIdx.y * 32;
  int tx = threadIdx.x & 31, ty4 = threadIdx.x >> 5;
#pragma unroll
  for (int j = 0; j < 4; ++j) {
    int v = v0 + ty4 * 4 + j;
    tile[ty4 * 4 + j][tx] = in[((size_t)b * V + v) * C + c0 + tx];
  }
  __syncthreads();
#pragma unroll
  for (int j = 0; j < 4; ++j) {
    int c = c0 + ty4 * 4 + j;
    out[((size_t)b * C + c) * V + v0 + tx] = tile[tx][ty4 * 4 + j];
  }
}

// fused pool (max over neighbors at selected rows) + pooled-vertex gather
// v2: 4 channels per thread, float4 gather loads (C % 4 == 0 always here).
__global__ void k_pool_sel(const float* __restrict__ fm, const int* __restrict__ nidx,
                           const int* __restrict__ sel, float* __restrict__ outp,
                           const float* __restrict__ vinA, float* __restrict__ voutA,
                           float4* __restrict__ pkout,
                           int Vin, int Vout, int C) {
  int t = blockIdx.x * blockDim.x + threadIdx.x;
  if (t < 4 * Vout) {
    int p = t % Vout;
    int b = t / Vout;
    int src = b * Vin + sel[p];
    float x = vinA[3 * src], y = vinA[3 * src + 1], z = vinA[3 * src + 2];
    int dst = b * Vout + p;
    voutA[3 * dst] = x; voutA[3 * dst + 1] = y; voutA[3 * dst + 2] = z;
    pkout[dst] = make_float4(x, y, z, x * x + y * y + z * z);
  }
  int G = C >> 2;
  int total = 4 * Vout * G;
  if (t >= total) return;
  int gc = t % G;
  int c = gc << 2;
  int p = (t / G) % Vout;
  int b = t / (G * Vout);
  int sv = sel[p];
  const int* ir = nidx + ((size_t)b * Vin + sv) * NEI;
  float m0 = -INFINITY, m1 = -INFINITY, m2 = -INFINITY, m3 = -INFINITY;
#pragma unroll
  for (int n = 0; n < NEI; ++n) {
    float4 fv = *(const float4*)&fm[((size_t)b * Vin + ir[n]) * C + c];
    m0 = fmaxf(m0, fv.x); m1 = fmaxf(m1, fv.y);
    m2 = fmaxf(m2, fv.z); m3 = fmaxf(m3, fv.w);
  }
  float4 o = {m0, m1, m2, m3};
  *(float4*)&outp[((size_t)b * Vout + p) * C + c] = o;
}

// ===================== launch =====================
extern "C" void kernel_launch(void* const* d_in, const int* in_sizes, int n_in,
                              void* d_out, int out_size, void* d_ws, size_t ws_size,
                              hipStream_t stream) {
  (void)in_sizes; (void)n_in; (void)out_size; (void)ws_size;
  const int B = 4, V1 = 4096, V2 = 1024, V3 = 256;

  const float* vin   = (const float*)d_in[0];
  const float* dirs0 = (const float*)d_in[1];
  const float* W1 = (const float*)d_in[2];
  const float* b1 = (const float*)d_in[3];
  const float* D1 = (const float*)d_in[4];
  const float* W2 = (const float*)d_in[5];
  const float* b2 = (const float*)d_in[6];
  const float* D2 = (const float*)d_in[7];
  const float* W3 = (const float*)d_in[8];
  const float* b3 = (const float*)d_in[9];
  const float* D3 = (const float*)d_in[10];
  const float* W4 = (const float*)d_in[11];
  const float* b4 = (const float*)d_in[12];
  const float* D4 = (const float*)d_in[13];
  float* out = (float*)d_out;

  char* ws = (char*)d_ws;
  size_t off = 0;
  auto alloc = [&](size_t bytes) -> char* {
    char* p = ws + off;
    off = (off + bytes + 255) & ~(size_t)255;
    return p;
  };
  int* sel1 = (int*)alloc((size_t)V2 * 4);
  int* sel2 = (int*)alloc((size_t)V3 * 4);
  float* verts1 = (float*)alloc((size_t)B * V1 * 3 * 4);
  float* verts2 = (float*)alloc((size_t)B * V2 * 3 * 4);
  float* verts3 = (float*)alloc((size_t)B * V3 * 3 * 4);
  float4* pk1 = (float4*)alloc((size_t)B * V1 * 16);
  float4* pk2 = (float4*)alloc((size_t)B * V2 * 16);
  float4* pk3 = (float4*)alloc((size_t)B * V3 * 16);
  int* idx1 = (int*)alloc((size_t)B * V1 * NEI * 4);
  int* idx2 = (int*)alloc((size_t)B * V2 * NEI * 4);
  int* idx3 = (int*)alloc((size_t)B * V3 * NEI * 4);
  float* sd0 = (float*)alloc(3 * 128 * 4);
  float* sd1 = (float*)alloc(3 * 256 * 4);
  float* sd2 = (float*)alloc(3 * 512 * 4);
  float* sd3 = (float*)alloc(3 * 1024 * 4);
  float* sd4 = (float*)alloc(3 * 4096 * 4);
  float* bufA = (float*)alloc((size_t)B * V1 * 32 * 4);
  float* bufB = (float*)alloc((size_t)B * V1 * 64 * 4);
  float* bufC = (float*)alloc((size_t)B * V2 * 64 * 4);
  float* fbuf = (float*)alloc((size_t)B * V1 * 320 * 4);
  float* fm0 = bufA, *fm2 = bufA;
  float* fm1 = bufB, *fm3 = bufB;
  float* fm1p = bufC, *fm3p = bufC;
  float* conv4out = bufB;

  static int perm1[4096];
  static int perm2[1024];
  static int selh[1280];
  jax_permutation(42u, 4096, 2, perm1);
  jax_permutation(43u, 1024, 1, perm2);
  memcpy(selh, perm1, 1024 * sizeof(int));
  memcpy(selh + 1024, perm2, 256 * sizeof(int));
  hipMemcpyAsync(sel1, selh, 1024 * sizeof(int), hipMemcpyHostToDevice, stream);
  hipMemcpyAsync(sel2, selh + 1024, 256 * sizeof(int), hipMemcpyHostToDevice, stream);

  // fused sanitize + dirs normalize
  k_setup<<<88, 256, 0, stream>>>(vin, verts1, pk1, B * V1,
                                  dirs0, D1, D2, D3, D4, sd0, sd1, sd2, sd3, sd4);
  // knn level 1 (VCAND = 64), 2 queries/wave, 8 queries/block
  k_knn8<64><<<B * V1 / 8, 256, 0, stream>>>(pk1, idx1, V1);
  k_conv_surface<<<B * V1, 128, 0, stream>>>(verts1, idx1, sd0, fm0, V1);
  // layer1 (N=320 not /128 -> 64-tile)
  k_gemm_bias<<<dim3(5, 256), 256, 0, stream>>>(fm0, W1, b1, fbuf, B * V1, 320, 32);
  // conv layers: blockDim = E/4 (float4 gather path)
  k_conv_layer<<<B * V1, 64, (4 * 64 + 80) * 4, stream>>>(fbuf, verts1, idx1, sd1, fm1, V1, 64, 1);
  // pool1 (fused pool + vertex gather), 4 channels/thread
  {
    int total = B * V2 * (64 / 4);
    int thr = total > 4 * V2 ? total : 4 * V2;
    k_pool_sel<<<(thr + 255) / 256, 256, 0, stream>>>(fm1, idx1, sel1, fm1p,
                                                      verts1, verts2, pk2,
                                                      V1, V2, 64);
  }
  // knn level 2 (VCAND = 16)
  k_knn8<16><<<B * V2 / 8, 256, 0, stream>>>(pk2, idx2, V2);
  // layer2: 4096x640x64
  k_gemm128<<<dim3(640 / 128, 4096 / 128), 256, 0, stream>>>(fm1p, W2, b2, fbuf, B * V2, 640, 64);
  k_conv_layer<<<B * V2, 128, (4 * 128 + 80) * 4, stream>>>(fbuf, verts2, idx2, sd2, fm2, V2, 128, 1);
  // layer3: 4096x1280x128
  k_gemm128<<<dim3(1280 / 128, 4096 / 128), 256, 0, stream>>>(fm2, W3, b3, fbuf, B * V2, 1280, 128);
  k_conv_layer<<<B * V2, 256, (4 * 256 + 80) * 4, stream>>>(fbuf, verts2, idx2, sd3, fm3, V2, 256, 1);
  // pool2 (fused), 4 channels/thread
  {
    int total = B * V3 * (256 / 4);
    int thr = total > 4 * V3 ? total : 4 * V3;
    k_pool_sel<<<(thr + 255) / 256, 256, 0, stream>>>(fm3, idx2, sel2, fm3p,
                                                      verts2, verts3, pk3,
                                                      V2, V3, 256);
  }
  // knn level 3 (VCAND = 4)
  k_knn8<4><<<B * V3 / 8, 256, 0, stream>>>(pk3, idx3, V3);
  // layer4: 1024x5120x256, conv C=1024 (blockDim 1024), then coalesced transpose
  k_gemm128<<<dim3(5120 / 128, 1024 / 128), 256, 0, stream>>>(fm3p, W4, b4, fbuf, B * V3, 5120, 256);
  k_conv_layer<<<B * V3, 1024, (4 * 1024 + 80) * 4, stream>>>(fbuf, verts3, idx3, sd4, conv4out, V3, 1024, 0);
  k_transpose_vc<<<dim3(1024 / 32, 256 / 32, B), 256, 0, stream>>>(conv4out, out, V3, 1024);
}

// Round 5
// 461.018 us; speedup vs baseline: 1.0051x; 1.0051x over previous
//
#include <hip/hip_runtime.h>
#include <vector>
#include <algorithm>
#include <cstdint>
#include <cstring>
#include <cmath>

// ===================== host-side JAX threefry replication =====================
static inline uint32_t tf_rotl(uint32_t x, int r) { return (x << r) | (x >> (32 - r)); }

static void tf2x32(uint32_t k0, uint32_t k1, uint32_t x0, uint32_t x1,
                   uint32_t* o0, uint32_t* o1) {
  uint32_t ks2 = k0 ^ k1 ^ 0x1BD11BDAu;
  uint32_t v0 = x0 + k0, v1 = x1 + k1;
  static const int R0[4] = {13, 15, 26, 6}, R1[4] = {17, 29, 16, 24};
#define RND4(R) do { for (int i_ = 0; i_ < 4; ++i_) { v0 += v1; v1 = tf_rotl(v1, R[i_]); v1 ^= v0; } } while (0)
  RND4(R0); v0 += k1;  v1 += ks2 + 1u;
  RND4(R1); v0 += ks2; v1 += k0 + 2u;
  RND4(R0); v0 += k0;  v1 += k1 + 3u;
  RND4(R1); v0 += k1;  v1 += ks2 + 4u;
  RND4(R0); v0 += ks2; v1 += k0 + 5u;
#undef RND4
  *o0 = v0; *o1 = v1;
}

static void jax_permutation(uint32_t seed, int n, int rounds, int* x) {
  uint32_t k0 = 0u, k1 = seed;
  for (int i = 0; i < n; ++i) x[i] = i;
  std::vector<uint32_t> bits(n);
  std::vector<int> ord(n), xn(n);
  for (int r = 0; r < rounds; ++r) {
    uint32_t nk0, nk1, sk0, sk1;
    tf2x32(k0, k1, 0u, 0u, &nk0, &nk1);
    tf2x32(k0, k1, 0u, 1u, &sk0, &sk1);
    for (int i = 0; i < n; ++i) {
      uint32_t h, l;
      tf2x32(sk0, sk1, 0u, (uint32_t)i, &h, &l);
      bits[i] = h ^ l;
    }
    for (int i = 0; i < n; ++i) ord[i] = i;
    std::stable_sort(ord.begin(), ord.end(),
                     [&](int a, int b) { return bits[a] < bits[b]; });
    for (int i = 0; i < n; ++i) xn[i] = x[ord[i]];
    memcpy(x, xn.data(), (size_t)n * sizeof(int));
    k0 = nk0; k1 = nk1;
  }
}

// ===================== device kernels =====================
#define NEI 20

__device__ __forceinline__ float san(float v) {
  v = (v != v) ? 0.0f : v;
  return fmaxf(-1e4f, fminf(v, 1e4f));
}

// fused setup: blocks 0..63 sanitize vertices -> AoS + packed float4{x,y,z,sq};
// blocks 64..87 normalize the 5 direction matrices.
__global__ void k_setup(const float* __restrict__ vin, float* __restrict__ outA,
                        float4* __restrict__ pk, int nverts,
                        const float* __restrict__ d0, const float* __restrict__ d1,
                        const float* __restrict__ d2, const float* __restrict__ d3,
                        const float* __restrict__ d4,
                        float* __restrict__ s0, float* __restrict__ s1,
                        float* __restrict__ s2, float* __restrict__ s3,
                        float* __restrict__ s4) {
  int blk = blockIdx.x;
  if (blk < 64) {
    int i = blk * 256 + threadIdx.x;
    if (i >= nverts) return;
    float x = san(vin[3 * i]), y = san(vin[3 * i + 1]), z = san(vin[3 * i + 2]);
    outA[3 * i] = x; outA[3 * i + 1] = y; outA[3 * i + 2] = z;
    pk[i] = make_float4(x, y, z, x * x + y * y + z * z);
    return;
  }
  int t = (blk - 64) * 256 + threadIdx.x;
  const float* d; float* s; int E, e;
  if (t < 128)       { d = d0; s = s0; E = 128;  e = t; }
  else if (t < 384)  { d = d1; s = s1; E = 256;  e = t - 128; }
  else if (t < 896)  { d = d2; s = s2; E = 512;  e = t - 384; }
  else if (t < 1920) { d = d3; s = s3; E = 1024; e = t - 896; }
  else if (t < 6016) { d = d4; s = s4; E = 4096; e = t - 1920; }
  else return;
  float a = san(d[e]);
  float b = san(d[E + e]);
  float c = san(d[2 * E + e]);
  float nrm = sqrtf(a * a + b * b + c * c);
  float m = fmaxf(nrm, 1e-12f);
  s[e] = a / m; s[E + e] = b / m; s[2 * E + e] = c / m;
}

// total-order map for fp32 bits: monotone u32 for any float (handles negatives)
__device__ __forceinline__ unsigned fmap(float f) {
  unsigned u = __float_as_uint(f);
  return u ^ ((u & 0x80000000u) ? 0xFFFFFFFFu : 0x80000000u);
}

// --- 64-lane u32 min, broadcast via readlane (SGPR, no LDS round-trip) ---
__device__ __forceinline__ unsigned dpp_min_bcast1(unsigned a) {
  unsigned t;
  t = (unsigned)__builtin_amdgcn_update_dpp((int)a, (int)a, 0xB1, 0xF, 0xF, true);
  a = t < a ? t : a;
  t = (unsigned)__builtin_amdgcn_update_dpp((int)a, (int)a, 0x4E, 0xF, 0xF, true);
  a = t < a ? t : a;
  t = (unsigned)__builtin_amdgcn_update_dpp((int)a, (int)a, 0x141, 0xF, 0xF, true);
  a = t < a ? t : a;
  t = (unsigned)__builtin_amdgcn_update_dpp((int)a, (int)a, 0x140, 0xF, 0xF, true);
  a = t < a ? t : a;
  t = (unsigned)__builtin_amdgcn_update_dpp((int)a, (int)a, 0x142, 0xA, 0xF, false);
  a = t < a ? t : a;
  t = (unsigned)__builtin_amdgcn_update_dpp((int)a, (int)a, 0x143, 0xC, 0xF, false);
  a = t < a ? t : a;
  return (unsigned)__builtin_amdgcn_readlane((int)a, 63);
}

__device__ __forceinline__ void dpp_min_bcast2(unsigned& a, unsigned& b) {
  unsigned t0, t1;
#define STEP_DPP(ctrl, rm, bc)                                                           \
  t0 = (unsigned)__builtin_amdgcn_update_dpp((int)a, (int)a, ctrl, rm, 0xF, bc);         \
  t1 = (unsigned)__builtin_amdgcn_update_dpp((int)b, (int)b, ctrl, rm, 0xF, bc);         \
  a = t0 < a ? t0 : a; b = t1 < b ? t1 : b;
  STEP_DPP(0xB1, 0xF, true)
  STEP_DPP(0x4E, 0xF, true)
  STEP_DPP(0x141, 0xF, true)
  STEP_DPP(0x140, 0xF, true)
  STEP_DPP(0x142, 0xA, false)
  STEP_DPP(0x143, 0xC, false)
#undef STEP_DPP
  a = (unsigned)__builtin_amdgcn_readlane((int)a, 63);
  b = (unsigned)__builtin_amdgcn_readlane((int)b, 63);
}

// KNN v10 (R15-proven, ~90 µs): u64-key sorted top-3 queues, float4 candidate
// loads, readlane broadcasts. DO NOT split the u64 key: R13's dist-only compare
// dropped equal-dist/smaller-index candidates (real bug, found R15 post-mortem).
// Dual-queue variants (R11/R12) spilled to scratch — do not revisit.
template <int VCAND>
__global__ __launch_bounds__(256, 8) void k_knn8(const float4* __restrict__ pk,
                                                 int* __restrict__ nidx, int V) {
  const int wid = threadIdx.x >> 6;
  const int lane = threadIdx.x & 63;
  const int row0 = blockIdx.x * 8 + wid * 2;
  const int b = row0 / V;
  const int base = b * V;
  const int i0 = row0 % V;

  float xi[2], yi[2], zi[2], sqi[2];
#pragma unroll
  for (int t = 0; t < 2; ++t) {
    float4 q = pk[base + i0 + t];
    xi[t] = q.x; yi[t] = q.y; zi[t] = q.z; sqi[t] = q.w;
  }

  unsigned long long q0[2] = {~0ULL, ~0ULL}, q1[2] = {~0ULL, ~0ULL}, q2[2] = {~0ULL, ~0ULL};
#pragma unroll 4
  for (int c = 0; c < VCAND; ++c) {
    int j = c * 64 + lane;
    float4 cj = pk[base + j];
    float xj = cj.x, yj = cj.y, zj = cj.z, sqj = cj.w;
#pragma unroll
    for (int t = 0; t < 2; ++t) {
      float dot = xi[t] * xj + yi[t] * yj + zi[t] * zj;
      float dd = (sqi[t] + sqj) - 2.0f * dot;
      unsigned long long k = (((unsigned long long)fmap(dd)) << 32) | (unsigned)j;
      if (k < q2[t]) {
        if (k < q1[t]) {
          q2[t] = q1[t];
          if (k < q0[t]) { q1[t] = q0[t]; q0[t] = k; } else { q1[t] = k; }
        } else {
          q2[t] = k;
        }
      }
    }
  }

  for (int r = 0; r < 21; ++r) {
    unsigned h0 = (unsigned)(q0[0] >> 32);
    unsigned h1 = (unsigned)(q0[1] >> 32);
    unsigned m0 = h0, m1 = h1;
    dpp_min_bcast2(m0, m1);
    unsigned long long mk0 = __ballot(h0 == m0);
    unsigned long long mk1 = __ballot(h1 == m1);
    bool win0, win1;
    if (__popcll(mk0) > 1) {  // rare: dist-bit tie across lanes -> index min
      unsigned jj = (h0 == m0) ? (unsigned)q0[0] : 0xFFFFFFFFu;
      unsigned jm = dpp_min_bcast1(jj);
      win0 = (h0 == m0) && ((unsigned)q0[0] == jm);
    } else {
      win0 = (h0 == m0);
    }
    if (__popcll(mk1) > 1) {
      unsigned jj = (h1 == m1) ? (unsigned)q0[1] : 0xFFFFFFFFu;
      unsigned jm = dpp_min_bcast1(jj);
      win1 = (h1 == m1) && ((unsigned)q0[1] == jm);
    } else {
      win1 = (h1 == m1);
    }
    if (win0) {
      if (r > 0) nidx[(size_t)row0 * NEI + (r - 1)] = (int)(unsigned)q0[0];
      unsigned long long bound = q0[0];
      q0[0] = q1[0]; q1[0] = q2[0]; q2[0] = ~0ULL;
      if (q0[0] == ~0ULL) {
        unsigned long long nm = ~0ULL;
        for (int c = 0; c < VCAND; ++c) {
          int j = c * 64 + lane;
          float4 cj = pk[base + j];
          float dot = xi[0] * cj.x + yi[0] * cj.y + zi[0] * cj.z;
          float dd = (sqi[0] + cj.w) - 2.0f * dot;
          unsigned long long k = (((unsigned long long)fmap(dd)) << 32) | (unsigned)j;
          if (k > bound && k < nm) nm = k;
        }
        q0[0] = nm;
      }
    }
    if (win1) {
      if (r > 0) nidx[(size_t)(row0 + 1) * NEI + (r - 1)] = (int)(unsigned)q0[1];
      unsigned long long bound = q0[1];
      q0[1] = q1[1]; q1[1] = q2[1]; q2[1] = ~0ULL;
      if (q0[1] == ~0ULL) {
        unsigned long long nm = ~0ULL;
        for (int c = 0; c < VCAND; ++c) {
          int j = c * 64 + lane;
          float4 cj = pk[base + j];
          float dot = xi[1] * cj.x + yi[1] * cj.y + zi[1] * cj.z;
          float dd = (sqi[1] + cj.w) - 2.0f * dot;
          unsigned long long k = (((unsigned long long)fmap(dd)) << 32) | (unsigned)j;
          if (k > bound && k < nm) nm = k;
        }
        q0[1] = nm;
      }
    }
  }
}

// conv_surface: C=32, E=128. One block (128 thr) per (b,v).
__global__ __launch_bounds__(128) void k_conv_surface(const float* __restrict__ verts,
                                                      const int* __restrict__ nidx,
                                                      const float* __restrict__ sd,
                                                      float* __restrict__ fm, int V) {
  int row = blockIdx.x;
  int b = row / V, v = row % V;
  const float* vb = verts + (size_t)b * V * 3;
  __shared__ float nd[60];
  __shared__ float mcol[128];
  int tid = threadIdx.x;
  if (tid < NEI) {
    int j = nidx[(size_t)row * NEI + tid];
    float dx = vb[3 * j] - vb[3 * v];
    float dy = vb[3 * j + 1] - vb[3 * v + 1];
    float dz = vb[3 * j + 2] - vb[3 * v + 2];
    float nrm = sqrtf(dx * dx + dy * dy + dz * dz);
    float m = fmaxf(nrm, 1e-12f);
    nd[tid * 3] = dx / m; nd[tid * 3 + 1] = dy / m; nd[tid * 3 + 2] = dz / m;
  }
  __syncthreads();
  {
    int e = tid;
    float s0 = sd[e], s1 = sd[128 + e], s2 = sd[256 + e];
    float me = 0.0f;
#pragma unroll
    for (int n = 0; n < NEI; ++n) {
      float th = nd[3 * n] * s0 + nd[3 * n + 1] * s1 + nd[3 * n + 2] * s2;
      th = fmaxf(th, 0.0f);
      me = fmaxf(me, th);
    }
    mcol[e] = me;
  }
  __syncthreads();
  if (tid < 32) {
    float o = mcol[tid] + mcol[32 + tid] + mcol[64 + tid] + mcol[96 + tid];
    o = fmaxf(o, 0.0f);
    fm[(size_t)row * 32 + tid] = o;
  }
}

// fp32 tiled GEMM 64x64x16 (guarded; used for layer1): C = A*W + bias
__global__ __launch_bounds__(256) void k_gemm_bias(const float* __restrict__ A,
                                                   const float* __restrict__ W,
                                                   const float* __restrict__ bias,
                                                   float* __restrict__ Cm,
                                                   int M, int N, int K) {
  __shared__ float As[16][68];
  __shared__ float Bs[16][68];
  int n0 = blockIdx.x * 64, m0 = blockIdx.y * 64;
  int tx = threadIdx.x & 15, ty = threadIdx.x >> 4;
  float acc[4][4] = {};
  for (int k0 = 0; k0 < K; k0 += 16) {
    for (int t = threadIdx.x; t < 1024; t += 256) {
      int mm = t >> 4, kk = t & 15;
      int m = m0 + mm;
      As[kk][mm] = (m < M) ? A[(size_t)m * K + (k0 + kk)] : 0.0f;
    }
    for (int t = threadIdx.x; t < 1024; t += 256) {
      int kk = t >> 6, nn = t & 63;
      int n = n0 + nn;
      Bs[kk][nn] = (n < N) ? san(W[(size_t)(k0 + kk) * N + n]) : 0.0f;
    }
    __syncthreads();
#pragma unroll
    for (int kk = 0; kk < 16; ++kk) {
      float4 av = *(const float4*)&As[kk][ty << 2];
      float4 bv = *(const float4*)&Bs[kk][tx << 2];
      float a[4] = {av.x, av.y, av.z, av.w};
      float bb[4] = {bv.x, bv.y, bv.z, bv.w};
#pragma unroll
      for (int i = 0; i < 4; ++i)
#pragma unroll
        for (int j = 0; j < 4; ++j) acc[i][j] += a[i] * bb[j];
    }
    __syncthreads();
  }
  for (int i = 0; i < 4; ++i)
    for (int j = 0; j < 4; ++j) {
      int m = m0 + (ty << 2) + i, n = n0 + (tx << 2) + j;
      if (m < M && n < N) Cm[(size_t)m * N + n] = acc[i][j] + san(bias[n]);
    }
}

// fp32 tiled GEMM 128x128x32, requires M%128==0, N%128==0, K%32==0.
__global__ __launch_bounds__(256) void k_gemm128(const float* __restrict__ A,
                                                 const float* __restrict__ W,
                                                 const float* __restrict__ bias,
                                                 float* __restrict__ Cm,
                                                 int M, int N, int K) {
  __shared__ float As[32][132];
  __shared__ float Bs[32][132];
  const int n0 = blockIdx.x * 128, m0 = blockIdx.y * 128;
  const int tx = threadIdx.x & 15, ty = threadIdx.x >> 4;
  const int bm = ty * 8;
  float acc[8][8] = {};
  float bias_lo[4], bias_hi[4];
#pragma unroll
  for (int j = 0; j < 4; ++j) {
    bias_lo[j] = san(bias[n0 + tx * 4 + j]);
    bias_hi[j] = san(bias[n0 + 64 + tx * 4 + j]);
  }
  for (int k0 = 0; k0 < K; k0 += 32) {
#pragma unroll
    for (int r = 0; r < 4; ++r) {
      int t = r * 256 + threadIdx.x;
      int mm = t >> 3, kk = (t & 7) * 4;
      float4 v = *(const float4*)&A[(size_t)(m0 + mm) * K + k0 + kk];
      As[kk + 0][mm] = v.x; As[kk + 1][mm] = v.y; As[kk + 2][mm] = v.z; As[kk + 3][mm] = v.w;
    }
#pragma unroll
    for (int r = 0; r < 4; ++r) {
      int t = r * 256 + threadIdx.x;
      int kk = t >> 5, nn = (t & 31) * 4;
      float4 v = *(const float4*)&W[(size_t)(k0 + kk) * N + n0 + nn];
      *(float4*)&Bs[kk][nn] = v;
    }
    __syncthreads();
#pragma unroll
    for (int kk = 0; kk < 32; ++kk) {
      float4 a0 = *(const float4*)&As[kk][bm];
      float4 a1 = *(const float4*)&As[kk][bm + 4];
      float4 b0 = *(const float4*)&Bs[kk][tx * 4];
      float4 b1 = *(const float4*)&Bs[kk][64 + tx * 4];
      float a[8] = {a0.x, a0.y, a0.z, a0.w, a1.x, a1.y, a1.z, a1.w};
      float bb[8] = {b0.x, b0.y, b0.z, b0.w, b1.x, b1.y, b1.z, b1.w};
#pragma unroll
      for (int i = 0; i < 8; ++i)
#pragma unroll
        for (int j = 0; j < 8; ++j) acc[i][j] += a[i] * bb[j];
    }
    __syncthreads();
  }
#pragma unroll
  for (int i = 0; i < 8; ++i) {
    int m = m0 + bm + i;
    float4 lo = {acc[i][0] + bias_lo[0], acc[i][1] + bias_lo[1],
                 acc[i][2] + bias_lo[2], acc[i][3] + bias_lo[3]};
    float4 hi = {acc[i][4] + bias_hi[0], acc[i][5] + bias_hi[1],
                 acc[i][6] + bias_hi[2], acc[i][7] + bias_hi[3]};
    *(float4*)&Cm[(size_t)m * N + n0 + tx * 4] = lo;
    *(float4*)&Cm[(size_t)m * N + n0 + 64 + tx * 4] = hi;
  }
}

// conv layer (scalar, R15-proven): used for conv1 (E=256) and conv2 (E=512)
// with 256-thread blocks. 64-thread blocks are a trap: ~16 wg/CU cap -> only
// 16 waves/CU on a 335 MB gather (R16 regression).
__global__ __launch_bounds__(256) void k_conv_layer(const float* __restrict__ f,
                                                    const float* __restrict__ verts,
                                                    const int* __restrict__ nidx,
                                                    const float* __restrict__ sd,
                                                    float* __restrict__ outf,
                                                    int V, int C, int relu_out) {
  int row = blockIdx.x;
  int b = row / V, v = row % V;
  int E = 4 * C;
  extern __shared__ float sm[];
  float* mcol = sm;
  float* nd = sm + E;
  int* jr = (int*)(nd + 60);
  int tid = threadIdx.x;
  const float* vb = verts + (size_t)b * V * 3;
  if (tid < NEI) {
    int j = nidx[(size_t)row * NEI + tid];
    jr[tid] = j;
    float dx = vb[3 * j] - vb[3 * v];
    float dy = vb[3 * j + 1] - vb[3 * v + 1];
    float dz = vb[3 * j + 2] - vb[3 * v + 2];
    float nrm = sqrtf(dx * dx + dy * dy + dz * dz);
    float m = fmaxf(nrm, 1e-12f);
    nd[tid * 3] = dx / m; nd[tid * 3 + 1] = dy / m; nd[tid * 3 + 2] = dz / m;
  }
  __syncthreads();
  size_t fb = (size_t)b * V;
  int fivec = 5 * C;
  for (int e = tid; e < E; e += blockDim.x) {
    float s0 = sd[e], s1 = sd[E + e], s2 = sd[2 * E + e];
    float me = -INFINITY;
#pragma unroll
    for (int n = 0; n < NEI; ++n) {
      float th = nd[3 * n] * s0 + nd[3 * n + 1] * s1 + nd[3 * n + 2] * s2;
      th = fmaxf(th, 0.0f);
      float fv = f[(fb + jr[n]) * (size_t)fivec + C + e];
      me = fmaxf(me, th * fv);
    }
    mcol[e] = me;
  }
  __syncthreads();
  for (int c = tid; c < C; c += blockDim.x) {
    float o = f[(size_t)row * fivec + c] + mcol[c] + mcol[C + c] + mcol[2 * C + c] + mcol[3 * C + c];
    if (relu_out) o = fmaxf(o, 0.0f);
    outf[(size_t)row * C + c] = o;
  }
}

// conv layer, float4 gather variant: each thread owns 4 consecutive e-channels;
// the 20 neighbor gathers become one dwordx4 each (4x fewer load instructions,
// same bytes, coalescing preserved: lanes share jr[n], consecutive 16B chunks).
// Used ONLY where blockDim = E/4 >= 256 (conv3: 256 thr, conv4: 1024 thr).
// Numerics of this path validated R16 (absmax 4.9e-4 < 4.9e-3 threshold).
__global__ __launch_bounds__(1024) void k_conv_layer_v4(const float* __restrict__ f,
                                                        const float* __restrict__ verts,
                                                        const int* __restrict__ nidx,
                                                        const float* __restrict__ sd,
                                                        float* __restrict__ outf,
                                                        int V, int C, int relu_out) {
  int row = blockIdx.x;
  int b = row / V, v = row % V;
  int E = 4 * C;
  extern __shared__ float sm[];
  float* mcol = sm;
  float* nd = sm + E;
  int* jr = (int*)(nd + 60);
  int tid = threadIdx.x;
  const float* vb = verts + (size_t)b * V * 3;
  if (tid < NEI) {
    int j = nidx[(size_t)row * NEI + tid];
    jr[tid] = j;
    float dx = vb[3 * j] - vb[3 * v];
    float dy = vb[3 * j + 1] - vb[3 * v + 1];
    float dz = vb[3 * j + 2] - vb[3 * v + 2];
    float nrm = sqrtf(dx * dx + dy * dy + dz * dz);
    float m = fmaxf(nrm, 1e-12f);
    nd[tid * 3] = dx / m; nd[tid * 3 + 1] = dy / m; nd[tid * 3 + 2] = dz / m;
  }
  __syncthreads();
  size_t fb = (size_t)b * V;
  int fivec = 5 * C;
  int G = E >> 2;
  for (int g = tid; g < G; g += blockDim.x) {
    int e = g << 2;
    float4 sa = *(const float4*)&sd[e];
    float4 sb = *(const float4*)&sd[E + e];
    float4 sc = *(const float4*)&sd[2 * E + e];
    float me0 = -INFINITY, me1 = -INFINITY, me2 = -INFINITY, me3 = -INFINITY;
#pragma unroll
    for (int n = 0; n < NEI; ++n) {
      float n0 = nd[3 * n], n1 = nd[3 * n + 1], n2 = nd[3 * n + 2];
      float4 fv = *(const float4*)&f[(fb + jr[n]) * (size_t)fivec + C + e];
      float th0 = fmaxf(n0 * sa.x + n1 * sb.x + n2 * sc.x, 0.0f);
      float th1 = fmaxf(n0 * sa.y + n1 * sb.y + n2 * sc.y, 0.0f);
      float th2 = fmaxf(n0 * sa.z + n1 * sb.z + n2 * sc.z, 0.0f);
      float th3 = fmaxf(n0 * sa.w + n1 * sb.w + n2 * sc.w, 0.0f);
      me0 = fmaxf(me0, th0 * fv.x);
      me1 = fmaxf(me1, th1 * fv.y);
      me2 = fmaxf(me2, th2 * fv.z);
      me3 = fmaxf(me3, th3 * fv.w);
    }
    mcol[e] = me0; mcol[e + 1] = me1; mcol[e + 2] = me2; mcol[e + 3] = me3;
  }
  __syncthreads();
  for (int c = tid; c < C; c += blockDim.x) {
    float o = f[(size_t)row * fivec + c] + mcol[c] + mcol[C + c] + mcol[2 * C + c] + mcol[3 * C + c];
    if (relu_out) o = fmaxf(o, 0.0f);
    outf[(size_t)row * C + c] = o;
  }
}

// transpose (B, V, C) -> (B, C, V), 32x32 LDS tiles, coalesced both sides
__global__ __launch_bounds__(256) void k_transpose_vc(const float* __restrict__ in,
                                                      float* __restrict__ out,
                                                      int V, int C) {
  __shared__ float tile[32][33];
  int b = blockIdx.z;
  int c0 = blockIdx.x * 32, v0 = blockIdx.y * 32;
  int tx = threadIdx.x & 31, ty4 = threadIdx.x >> 5;
#pragma unroll
  for (int j = 0; j < 4; ++j) {
    int v = v0 + ty4 * 4 + j;
    tile[ty4 * 4 + j][tx] = in[((size_t)b * V + v) * C + c0 + tx];
  }
  __syncthreads();
#pragma unroll
  for (int j = 0; j < 4; ++j) {
    int c = c0 + ty4 * 4 + j;
    out[((size_t)b * C + c) * V + v0 + tx] = tile[tx][ty4 * 4 + j];
  }
}

// fused pool (max over neighbors at selected rows) + pooled-vertex gather
// (scalar, R15-proven)
__global__ void k_pool_sel(const float* __restrict__ fm, const int* __restrict__ nidx,
                           const int* __restrict__ sel, float* __restrict__ outp,
                           const float* __restrict__ vinA, float* __restrict__ voutA,
                           float4* __restrict__ pkout,
                           int Vin, int Vout, int C) {
  int t = blockIdx.x * blockDim.x + threadIdx.x;
  if (t < 4 * Vout) {
    int p = t % Vout;
    int b = t / Vout;
    int src = b * Vin + sel[p];
    float x = vinA[3 * src], y = vinA[3 * src + 1], z = vinA[3 * src + 2];
    int dst = b * Vout + p;
    voutA[3 * dst] = x; voutA[3 * dst + 1] = y; voutA[3 * dst + 2] = z;
    pkout[dst] = make_float4(x, y, z, x * x + y * y + z * z);
  }
  int total = 4 * Vout * C;
  if (t >= total) return;
  int c = t % C;
  int p = (t / C) % Vout;
  int b = t / (C * Vout);
  int sv = sel[p];
  const int* ir = nidx + ((size_t)b * Vin + sv) * NEI;
  float m = -INFINITY;
#pragma unroll
  for (int n = 0; n < NEI; ++n)
    m = fmaxf(m, fm[((size_t)b * Vin + ir[n]) * C + c]);
  outp[((size_t)b * Vout + p) * C + c] = m;
}

// ===================== launch =====================
extern "C" void kernel_launch(void* const* d_in, const int* in_sizes, int n_in,
                              void* d_out, int out_size, void* d_ws, size_t ws_size,
                              hipStream_t stream) {
  (void)in_sizes; (void)n_in; (void)out_size; (void)ws_size;
  const int B = 4, V1 = 4096, V2 = 1024, V3 = 256;

  const float* vin   = (const float*)d_in[0];
  const float* dirs0 = (const float*)d_in[1];
  const float* W1 = (const float*)d_in[2];
  const float* b1 = (const float*)d_in[3];
  const float* D1 = (const float*)d_in[4];
  const float* W2 = (const float*)d_in[5];
  const float* b2 = (const float*)d_in[6];
  const float* D2 = (const float*)d_in[7];
  const float* W3 = (const float*)d_in[8];
  const float* b3 = (const float*)d_in[9];
  const float* D3 = (const float*)d_in[10];
  const float* W4 = (const float*)d_in[11];
  const float* b4 = (const float*)d_in[12];
  const float* D4 = (const float*)d_in[13];
  float* out = (float*)d_out;

  char* ws = (char*)d_ws;
  size_t off = 0;
  auto alloc = [&](size_t bytes) -> char* {
    char* p = ws + off;
    off = (off + bytes + 255) & ~(size_t)255;
    return p;
  };
  int* sel1 = (int*)alloc((size_t)V2 * 4);
  int* sel2 = (int*)alloc((size_t)V3 * 4);
  float* verts1 = (float*)alloc((size_t)B * V1 * 3 * 4);
  float* verts2 = (float*)alloc((size_t)B * V2 * 3 * 4);
  float* verts3 = (float*)alloc((size_t)B * V3 * 3 * 4);
  float4* pk1 = (float4*)alloc((size_t)B * V1 * 16);
  float4* pk2 = (float4*)alloc((size_t)B * V2 * 16);
  float4* pk3 = (float4*)alloc((size_t)B * V3 * 16);
  int* idx1 = (int*)alloc((size_t)B * V1 * NEI * 4);
  int* idx2 = (int*)alloc((size_t)B * V2 * NEI * 4);
  int* idx3 = (int*)alloc((size_t)B * V3 * NEI * 4);
  float* sd0 = (float*)alloc(3 * 128 * 4);
  float* sd1 = (float*)alloc(3 * 256 * 4);
  float* sd2 = (float*)alloc(3 * 512 * 4);
  float* sd3 = (float*)alloc(3 * 1024 * 4);
  float* sd4 = (float*)alloc(3 * 4096 * 4);
  float* bufA = (float*)alloc((size_t)B * V1 * 32 * 4);
  float* bufB = (float*)alloc((size_t)B * V1 * 64 * 4);
  float* bufC = (float*)alloc((size_t)B * V2 * 64 * 4);
  float* fbuf = (float*)alloc((size_t)B * V1 * 320 * 4);
  float* fm0 = bufA, *fm2 = bufA;
  float* fm1 = bufB, *fm3 = bufB;
  float* fm1p = bufC, *fm3p = bufC;
  float* conv4out = bufB;

  static int perm1[4096];
  static int perm2[1024];
  static int selh[1280];
  jax_permutation(42u, 4096, 2, perm1);
  jax_permutation(43u, 1024, 1, perm2);
  memcpy(selh, perm1, 1024 * sizeof(int));
  memcpy(selh + 1024, perm2, 256 * sizeof(int));
  hipMemcpyAsync(sel1, selh, 1024 * sizeof(int), hipMemcpyHostToDevice, stream);
  hipMemcpyAsync(sel2, selh + 1024, 256 * sizeof(int), hipMemcpyHostToDevice, stream);

  // fused sanitize + dirs normalize
  k_setup<<<88, 256, 0, stream>>>(vin, verts1, pk1, B * V1,
                                  dirs0, D1, D2, D3, D4, sd0, sd1, sd2, sd3, sd4);
  // knn level 1 (VCAND = 64), 2 queries/wave, 8 queries/block
  k_knn8<64><<<B * V1 / 8, 256, 0, stream>>>(pk1, idx1, V1);
  k_conv_surface<<<B * V1, 128, 0, stream>>>(verts1, idx1, sd0, fm0, V1);
  // layer1 (N=320 not /128 -> 64-tile)
  k_gemm_bias<<<dim3(5, 256), 256, 0, stream>>>(fm0, W1, b1, fbuf, B * V1, 320, 32);
  k_conv_layer<<<B * V1, 256, (4 * 64 + 80) * 4, stream>>>(fbuf, verts1, idx1, sd1, fm1, V1, 64, 1);
  // pool1 (fused pool + vertex gather)
  {
    int total = B * V2 * 64;
    k_pool_sel<<<(total + 255) / 256, 256, 0, stream>>>(fm1, idx1, sel1, fm1p,
                                                        verts1, verts2, pk2,
                                                        V1, V2, 64);
  }
  // knn level 2 (VCAND = 16)
  k_knn8<16><<<B * V2 / 8, 256, 0, stream>>>(pk2, idx2, V2);
  // layer2: 4096x640x64
  k_gemm128<<<dim3(640 / 128, 4096 / 128), 256, 0, stream>>>(fm1p, W2, b2, fbuf, B * V2, 640, 64);
  k_conv_layer<<<B * V2, 256, (4 * 128 + 80) * 4, stream>>>(fbuf, verts2, idx2, sd2, fm2, V2, 128, 1);
  // layer3: 4096x1280x128, conv3 via float4 gather (G=256 -> 256 thr)
  k_gemm128<<<dim3(1280 / 128, 4096 / 128), 256, 0, stream>>>(fm2, W3, b3, fbuf, B * V2, 1280, 128);
  k_conv_layer_v4<<<B * V2, 256, (4 * 256 + 80) * 4, stream>>>(fbuf, verts2, idx2, sd3, fm3, V2, 256, 1);
  // pool2 (fused)
  {
    int total = B * V3 * 256;
    k_pool_sel<<<(total + 255) / 256, 256, 0, stream>>>(fm3, idx2, sel2, fm3p,
                                                        verts2, verts3, pk3,
                                                        V2, V3, 256);
  }
  // knn level 3 (VCAND = 4)
  k_knn8<4><<<B * V3 / 8, 256, 0, stream>>>(pk3, idx3, V3);
  // layer4: 1024x5120x256, conv4 via float4 gather (G=1024 -> 1024 thr), transpose
  k_gemm128<<<dim3(5120 / 128, 1024 / 128), 256, 0, stream>>>(fm3p, W4, b4, fbuf, B * V3, 5120, 256);
  k_conv_layer_v4<<<B * V3, 1024, (4 * 1024 + 80) * 4, stream>>>(fbuf, verts3, idx3, sd4, conv4out, V3, 1024, 0);
  k_transpose_vc<<<dim3(1024 / 32, 256 / 32, B), 256, 0, stream>>>(conv4out, out, V3, 1024);
}

// Round 7
// 447.795 us; speedup vs baseline: 1.0348x; 1.0295x over previous
//
#include <hip/hip_runtime.h>
#include <vector>
#include <algorithm>
#include <cstdint>
#include <cstring>
#include <cmath>

// ===================== host-side JAX threefry replication =====================
static inline uint32_t tf_rotl(uint32_t x, int r) { return (x << r) | (x >> (32 - r)); }

static void tf2x32(uint32_t k0, uint32_t k1, uint32_t x0, uint32_t x1,
                   uint32_t* o0, uint32_t* o1) {
  uint32_t ks2 = k0 ^ k1 ^ 0x1BD11BDAu;
  uint32_t v0 = x0 + k0, v1 = x1 + k1;
  static const int R0[4] = {13, 15, 26, 6}, R1[4] = {17, 29, 16, 24};
#define RND4(R) do { for (int i_ = 0; i_ < 4; ++i_) { v0 += v1; v1 = tf_rotl(v1, R[i_]); v1 ^= v0; } } while (0)
  RND4(R0); v0 += k1;  v1 += ks2 + 1u;
  RND4(R1); v0 += ks2; v1 += k0 + 2u;
  RND4(R0); v0 += k0;  v1 += k1 + 3u;
  RND4(R1); v0 += k1;  v1 += ks2 + 4u;
  RND4(R0); v0 += ks2; v1 += k0 + 5u;
#undef RND4
  *o0 = v0; *o1 = v1;
}

static void jax_permutation(uint32_t seed, int n, int rounds, int* x) {
  uint32_t k0 = 0u, k1 = seed;
  for (int i = 0; i < n; ++i) x[i] = i;
  std::vector<uint32_t> bits(n);
  std::vector<int> ord(n), xn(n);
  for (int r = 0; r < rounds; ++r) {
    uint32_t nk0, nk1, sk0, sk1;
    tf2x32(k0, k1, 0u, 0u, &nk0, &nk1);
    tf2x32(k0, k1, 0u, 1u, &sk0, &sk1);
    for (int i = 0; i < n; ++i) {
      uint32_t h, l;
      tf2x32(sk0, sk1, 0u, (uint32_t)i, &h, &l);
      bits[i] = h ^ l;
    }
    for (int i = 0; i < n; ++i) ord[i] = i;
    std::stable_sort(ord.begin(), ord.end(),
                     [&](int a, int b) { return bits[a] < bits[b]; });
    for (int i = 0; i < n; ++i) xn[i] = x[ord[i]];
    memcpy(x, xn.data(), (size_t)n * sizeof(int));
    k0 = nk0; k1 = nk1;
  }
}

// ===================== device kernels =====================
#define NEI 20

__device__ __forceinline__ float san(float v) {
  v = (v != v) ? 0.0f : v;
  return fmaxf(-1e4f, fminf(v, 1e4f));
}

// fused setup: blocks 0..63 sanitize vertices -> AoS + packed float4{x,y,z,sq};
// blocks 64..87 normalize the 5 direction matrices.
__global__ void k_setup(const float* __restrict__ vin, float* __restrict__ outA,
                        float4* __restrict__ pk, int nverts,
                        const float* __restrict__ d0, const float* __restrict__ d1,
                        const float* __restrict__ d2, const float* __restrict__ d3,
                        const float* __restrict__ d4,
                        float* __restrict__ s0, float* __restrict__ s1,
                        float* __restrict__ s2, float* __restrict__ s3,
                        float* __restrict__ s4) {
  int blk = blockIdx.x;
  if (blk < 64) {
    int i = blk * 256 + threadIdx.x;
    if (i >= nverts) return;
    float x = san(vin[3 * i]), y = san(vin[3 * i + 1]), z = san(vin[3 * i + 2]);
    outA[3 * i] = x; outA[3 * i + 1] = y; outA[3 * i + 2] = z;
    pk[i] = make_float4(x, y, z, x * x + y * y + z * z);
    return;
  }
  int t = (blk - 64) * 256 + threadIdx.x;
  const float* d; float* s; int E, e;
  if (t < 128)       { d = d0; s = s0; E = 128;  e = t; }
  else if (t < 384)  { d = d1; s = s1; E = 256;  e = t - 128; }
  else if (t < 896)  { d = d2; s = s2; E = 512;  e = t - 384; }
  else if (t < 1920) { d = d3; s = s3; E = 1024; e = t - 896; }
  else if (t < 6016) { d = d4; s = s4; E = 4096; e = t - 1920; }
  else return;
  float a = san(d[e]);
  float b = san(d[E + e]);
  float c = san(d[2 * E + e]);
  float nrm = sqrtf(a * a + b * b + c * c);
  float m = fmaxf(nrm, 1e-12f);
  s[e] = a / m; s[E + e] = b / m; s[2 * E + e] = c / m;
}

// total-order map for fp32 bits: monotone u32 for any float (handles negatives)
__device__ __forceinline__ unsigned fmap(float f) {
  unsigned u = __float_as_uint(f);
  return u ^ ((u & 0x80000000u) ? 0xFFFFFFFFu : 0x80000000u);
}

// --- 64-lane u32 min, broadcast via readlane (SGPR, no LDS round-trip) ---
__device__ __forceinline__ unsigned dpp_min_bcast1(unsigned a) {
  unsigned t;
  t = (unsigned)__builtin_amdgcn_update_dpp((int)a, (int)a, 0xB1, 0xF, 0xF, true);
  a = t < a ? t : a;
  t = (unsigned)__builtin_amdgcn_update_dpp((int)a, (int)a, 0x4E, 0xF, 0xF, true);
  a = t < a ? t : a;
  t = (unsigned)__builtin_amdgcn_update_dpp((int)a, (int)a, 0x141, 0xF, 0xF, true);
  a = t < a ? t : a;
  t = (unsigned)__builtin_amdgcn_update_dpp((int)a, (int)a, 0x140, 0xF, 0xF, true);
  a = t < a ? t : a;
  t = (unsigned)__builtin_amdgcn_update_dpp((int)a, (int)a, 0x142, 0xA, 0xF, false);
  a = t < a ? t : a;
  t = (unsigned)__builtin_amdgcn_update_dpp((int)a, (int)a, 0x143, 0xC, 0xF, false);
  a = t < a ? t : a;
  return (unsigned)__builtin_amdgcn_readlane((int)a, 63);
}

__device__ __forceinline__ void dpp_min_bcast2(unsigned& a, unsigned& b) {
  unsigned t0, t1;
#define STEP_DPP(ctrl, rm, bc)                                                           \
  t0 = (unsigned)__builtin_amdgcn_update_dpp((int)a, (int)a, ctrl, rm, 0xF, bc);         \
  t1 = (unsigned)__builtin_amdgcn_update_dpp((int)b, (int)b, ctrl, rm, 0xF, bc);         \
  a = t0 < a ? t0 : a; b = t1 < b ? t1 : b;
  STEP_DPP(0xB1, 0xF, true)
  STEP_DPP(0x4E, 0xF, true)
  STEP_DPP(0x141, 0xF, true)
  STEP_DPP(0x140, 0xF, true)
  STEP_DPP(0x142, 0xA, false)
  STEP_DPP(0x143, 0xC, false)
#undef STEP_DPP
  a = (unsigned)__builtin_amdgcn_readlane((int)a, 63);
  b = (unsigned)__builtin_amdgcn_readlane((int)b, 63);
}

// KNN v11: R15-proven u64-key structure + u32 pre-filter in the scan.
// The pre-filter tracks q2hi = hi32(q2); only when fmap(dd) <= q2hi do we
// build the u64 key and run the ORIGINAL u64 compare/insert (q2hi refreshed
// after any insert). u > q2hi  =>  k > q2 exactly, so skipping is exact;
// u == q2hi falls through to the full lexicographic check. Bit-exact.
// DO NOT split the u64 key (R13 bug: dist-only compare broke index ties).
// Dual-queue variants (R11/R12) spilled to scratch — do not revisit.
template <int VCAND>
__global__ __launch_bounds__(256, 8) void k_knn8(const float4* __restrict__ pk,
                                                 int* __restrict__ nidx, int V) {
  const int wid = threadIdx.x >> 6;
  const int lane = threadIdx.x & 63;
  const int row0 = blockIdx.x * 8 + wid * 2;
  const int b = row0 / V;
  const int base = b * V;
  const int i0 = row0 % V;

  float xi[2], yi[2], zi[2], sqi[2];
#pragma unroll
  for (int t = 0; t < 2; ++t) {
    float4 q = pk[base + i0 + t];
    xi[t] = q.x; yi[t] = q.y; zi[t] = q.z; sqi[t] = q.w;
  }

  unsigned long long q0[2] = {~0ULL, ~0ULL}, q1[2] = {~0ULL, ~0ULL}, q2[2] = {~0ULL, ~0ULL};
  unsigned q2hi[2] = {0xFFFFFFFFu, 0xFFFFFFFFu};
#pragma unroll 4
  for (int c = 0; c < VCAND; ++c) {
    int j = c * 64 + lane;
    float4 cj = pk[base + j];
    float xj = cj.x, yj = cj.y, zj = cj.z, sqj = cj.w;
#pragma unroll
    for (int t = 0; t < 2; ++t) {
      float dot = xi[t] * xj + yi[t] * yj + zi[t] * zj;
      float dd = (sqi[t] + sqj) - 2.0f * dot;
      unsigned u = fmap(dd);
      if (u <= q2hi[t]) {  // cheap exact-conservative filter (u32)
        unsigned long long k = (((unsigned long long)u) << 32) | (unsigned)j;
        if (k < q2[t]) {
          if (k < q1[t]) {
            q2[t] = q1[t];
            if (k < q0[t]) { q1[t] = q0[t]; q0[t] = k; } else { q1[t] = k; }
          } else {
            q2[t] = k;
          }
          q2hi[t] = (unsigned)(q2[t] >> 32);
        }
      }
    }
  }

  for (int r = 0; r < 21; ++r) {
    unsigned h0 = (unsigned)(q0[0] >> 32);
    unsigned h1 = (unsigned)(q0[1] >> 32);
    unsigned m0 = h0, m1 = h1;
    dpp_min_bcast2(m0, m1);
    unsigned long long mk0 = __ballot(h0 == m0);
    unsigned long long mk1 = __ballot(h1 == m1);
    bool win0, win1;
    if (__popcll(mk0) > 1) {  // rare: dist-bit tie across lanes -> index min
      unsigned jj = (h0 == m0) ? (unsigned)q0[0] : 0xFFFFFFFFu;
      unsigned jm = dpp_min_bcast1(jj);
      win0 = (h0 == m0) && ((unsigned)q0[0] == jm);
    } else {
      win0 = (h0 == m0);
    }
    if (__popcll(mk1) > 1) {
      unsigned jj = (h1 == m1) ? (unsigned)q0[1] : 0xFFFFFFFFu;
      unsigned jm = dpp_min_bcast1(jj);
      win1 = (h1 == m1) && ((unsigned)q0[1] == jm);
    } else {
      win1 = (h1 == m1);
    }
    if (win0) {
      if (r > 0) nidx[(size_t)row0 * NEI + (r - 1)] = (int)(unsigned)q0[0];
      unsigned long long bound = q0[0];
      q0[0] = q1[0]; q1[0] = q2[0]; q2[0] = ~0ULL;
      if (q0[0] == ~0ULL) {
        unsigned long long nm = ~0ULL;
        for (int c = 0; c < VCAND; ++c) {
          int j = c * 64 + lane;
          float4 cj = pk[base + j];
          float dot = xi[0] * cj.x + yi[0] * cj.y + zi[0] * cj.z;
          float dd = (sqi[0] + cj.w) - 2.0f * dot;
          unsigned long long k = (((unsigned long long)fmap(dd)) << 32) | (unsigned)j;
          if (k > bound && k < nm) nm = k;
        }
        q0[0] = nm;
      }
    }
    if (win1) {
      if (r > 0) nidx[(size_t)(row0 + 1) * NEI + (r - 1)] = (int)(unsigned)q0[1];
      unsigned long long bound = q0[1];
      q0[1] = q1[1]; q1[1] = q2[1]; q2[1] = ~0ULL;
      if (q0[1] == ~0ULL) {
        unsigned long long nm = ~0ULL;
        for (int c = 0; c < VCAND; ++c) {
          int j = c * 64 + lane;
          float4 cj = pk[base + j];
          float dot = xi[1] * cj.x + yi[1] * cj.y + zi[1] * cj.z;
          float dd = (sqi[1] + cj.w) - 2.0f * dot;
          unsigned long long k = (((unsigned long long)fmap(dd)) << 32) | (unsigned)j;
          if (k > bound && k < nm) nm = k;
        }
        q0[1] = nm;
      }
    }
  }
}

// conv_surface: C=32, E=128. One block (128 thr) per (b,v).
__global__ __launch_bounds__(128) void k_conv_surface(const float* __restrict__ verts,
                                                      const int* __restrict__ nidx,
                                                      const float* __restrict__ sd,
                                                      float* __restrict__ fm, int V) {
  int row = blockIdx.x;
  int b = row / V, v = row % V;
  const float* vb = verts + (size_t)b * V * 3;
  __shared__ float nd[60];
  __shared__ float mcol[128];
  int tid = threadIdx.x;
  if (tid < NEI) {
    int j = nidx[(size_t)row * NEI + tid];
    float dx = vb[3 * j] - vb[3 * v];
    float dy = vb[3 * j + 1] - vb[3 * v + 1];
    float dz = vb[3 * j + 2] - vb[3 * v + 2];
    float nrm = sqrtf(dx * dx + dy * dy + dz * dz);
    float m = fmaxf(nrm, 1e-12f);
    nd[tid * 3] = dx / m; nd[tid * 3 + 1] = dy / m; nd[tid * 3 + 2] = dz / m;
  }
  __syncthreads();
  {
    int e = tid;
    float s0 = sd[e], s1 = sd[128 + e], s2 = sd[256 + e];
    float me = 0.0f;
#pragma unroll
    for (int n = 0; n < NEI; ++n) {
      float th = nd[3 * n] * s0 + nd[3 * n + 1] * s1 + nd[3 * n + 2] * s2;
      th = fmaxf(th, 0.0f);
      me = fmaxf(me, th);
    }
    mcol[e] = me;
  }
  __syncthreads();
  if (tid < 32) {
    float o = mcol[tid] + mcol[32 + tid] + mcol[64 + tid] + mcol[96 + tid];
    o = fmaxf(o, 0.0f);
    fm[(size_t)row * 32 + tid] = o;
  }
}

// fp32 tiled GEMM 64x64x16 (guarded; used for layer1): C = A*W + bias
__global__ __launch_bounds__(256) void k_gemm_bias(const float* __restrict__ A,
                                                   const float* __restrict__ W,
                                                   const float* __restrict__ bias,
                                                   float* __restrict__ Cm,
                                                   int M, int N, int K) {
  __shared__ float As[16][68];
  __shared__ float Bs[16][68];
  int n0 = blockIdx.x * 64, m0 = blockIdx.y * 64;
  int tx = threadIdx.x & 15, ty = threadIdx.x >> 4;
  float acc[4][4] = {};
  for (int k0 = 0; k0 < K; k0 += 16) {
    for (int t = threadIdx.x; t < 1024; t += 256) {
      int mm = t >> 4, kk = t & 15;
      int m = m0 + mm;
      As[kk][mm] = (m < M) ? A[(size_t)m * K + (k0 + kk)] : 0.0f;
    }
    for (int t = threadIdx.x; t < 1024; t += 256) {
      int kk = t >> 6, nn = t & 63;
      int n = n0 + nn;
      Bs[kk][nn] = (n < N) ? san(W[(size_t)(k0 + kk) * N + n]) : 0.0f;
    }
    __syncthreads();
#pragma unroll
    for (int kk = 0; kk < 16; ++kk) {
      float4 av = *(const float4*)&As[kk][ty << 2];
      float4 bv = *(const float4*)&Bs[kk][tx << 2];
      float a[4] = {av.x, av.y, av.z, av.w};
      float bb[4] = {bv.x, bv.y, bv.z, bv.w};
#pragma unroll
      for (int i = 0; i < 4; ++i)
#pragma unroll
        for (int j = 0; j < 4; ++j) acc[i][j] += a[i] * bb[j];
    }
    __syncthreads();
  }
  for (int i = 0; i < 4; ++i)
    for (int j = 0; j < 4; ++j) {
      int m = m0 + (ty << 2) + i, n = n0 + (tx << 2) + j;
      if (m < M && n < N) Cm[(size_t)m * N + n] = acc[i][j] + san(bias[n]);
    }
}

// fp32 tiled GEMM 128x128x32, requires M%128==0, N%128==0, K%32==0.
__global__ __launch_bounds__(256) void k_gemm128(const float* __restrict__ A,
                                                 const float* __restrict__ W,
                                                 const float* __restrict__ bias,
                                                 float* __restrict__ Cm,
                                                 int M, int N, int K) {
  __shared__ float As[32][132];
  __shared__ float Bs[32][132];
  const int n0 = blockIdx.x * 128, m0 = blockIdx.y * 128;
  const int tx = threadIdx.x & 15, ty = threadIdx.x >> 4;
  const int bm = ty * 8;
  float acc[8][8] = {};
  float bias_lo[4], bias_hi[4];
#pragma unroll
  for (int j = 0; j < 4; ++j) {
    bias_lo[j] = san(bias[n0 + tx * 4 + j]);
    bias_hi[j] = san(bias[n0 + 64 + tx * 4 + j]);
  }
  for (int k0 = 0; k0 < K; k0 += 32) {
#pragma unroll
    for (int r = 0; r < 4; ++r) {
      int t = r * 256 + threadIdx.x;
      int mm = t >> 3, kk = (t & 7) * 4;
      float4 v = *(const float4*)&A[(size_t)(m0 + mm) * K + k0 + kk];
      As[kk + 0][mm] = v.x; As[kk + 1][mm] = v.y; As[kk + 2][mm] = v.z; As[kk + 3][mm] = v.w;
    }
#pragma unroll
    for (int r = 0; r < 4; ++r) {
      int t = r * 256 + threadIdx.x;
      int kk = t >> 5, nn = (t & 31) * 4;
      float4 v = *(const float4*)&W[(size_t)(k0 + kk) * N + n0 + nn];
      *(float4*)&Bs[kk][nn] = v;
    }
    __syncthreads();
#pragma unroll
    for (int kk = 0; kk < 32; ++kk) {
      float4 a0 = *(const float4*)&As[kk][bm];
      float4 a1 = *(const float4*)&As[kk][bm + 4];
      float4 b0 = *(const float4*)&Bs[kk][tx * 4];
      float4 b1 = *(const float4*)&Bs[kk][64 + tx * 4];
      float a[8] = {a0.x, a0.y, a0.z, a0.w, a1.x, a1.y, a1.z, a1.w};
      float bb[8] = {b0.x, b0.y, b0.z, b0.w, b1.x, b1.y, b1.z, b1.w};
#pragma unroll
      for (int i = 0; i < 8; ++i)
#pragma unroll
        for (int j = 0; j < 8; ++j) acc[i][j] += a[i] * bb[j];
    }
    __syncthreads();
  }
#pragma unroll
  for (int i = 0; i < 8; ++i) {
    int m = m0 + bm + i;
    float4 lo = {acc[i][0] + bias_lo[0], acc[i][1] + bias_lo[1],
                 acc[i][2] + bias_lo[2], acc[i][3] + bias_lo[3]};
    float4 hi = {acc[i][4] + bias_hi[0], acc[i][5] + bias_hi[1],
                 acc[i][6] + bias_hi[2], acc[i][7] + bias_hi[3]};
    *(float4*)&Cm[(size_t)m * N + n0 + tx * 4] = lo;
    *(float4*)&Cm[(size_t)m * N + n0 + 64 + tx * 4] = hi;
  }
}

// conv layer (scalar, R15-proven; float4-gather variants regressed +22 µs in
// R16/R17 — line closed, keep scalar): out[c] = f[row][c] + sum_s max_n ...
__global__ __launch_bounds__(256) void k_conv_layer(const float* __restrict__ f,
                                                    const float* __restrict__ verts,
                                                    const int* __restrict__ nidx,
                                                    const float* __restrict__ sd,
                                                    float* __restrict__ outf,
                                                    int V, int C, int relu_out) {
  int row = blockIdx.x;
  int b = row / V, v = row % V;
  int E = 4 * C;
  extern __shared__ float sm[];
  float* mcol = sm;
  float* nd = sm + E;
  int* jr = (int*)(nd + 60);
  int tid = threadIdx.x;
  const float* vb = verts + (size_t)b * V * 3;
  if (tid < NEI) {
    int j = nidx[(size_t)row * NEI + tid];
    jr[tid] = j;
    float dx = vb[3 * j] - vb[3 * v];
    float dy = vb[3 * j + 1] - vb[3 * v + 1];
    float dz = vb[3 * j + 2] - vb[3 * v + 2];
    float nrm = sqrtf(dx * dx + dy * dy + dz * dz);
    float m = fmaxf(nrm, 1e-12f);
    nd[tid * 3] = dx / m; nd[tid * 3 + 1] = dy / m; nd[tid * 3 + 2] = dz / m;
  }
  __syncthreads();
  size_t fb = (size_t)b * V;
  int fivec = 5 * C;
  for (int e = tid; e < E; e += blockDim.x) {
    float s0 = sd[e], s1 = sd[E + e], s2 = sd[2 * E + e];
    float me = -INFINITY;
#pragma unroll
    for (int n = 0; n < NEI; ++n) {
      float th = nd[3 * n] * s0 + nd[3 * n + 1] * s1 + nd[3 * n + 2] * s2;
      th = fmaxf(th, 0.0f);
      float fv = f[(fb + jr[n]) * (size_t)fivec + C + e];
      me = fmaxf(me, th * fv);
    }
    mcol[e] = me;
  }
  __syncthreads();
  for (int c = tid; c < C; c += blockDim.x) {
    float o = f[(size_t)row * fivec + c] + mcol[c] + mcol[C + c] + mcol[2 * C + c] + mcol[3 * C + c];
    if (relu_out) o = fmaxf(o, 0.0f);
    outf[(size_t)row * C + c] = o;
  }
}

// 1024-thread clone for the layer-4 conv (grid only B*V3=1024 blocks; 16
// waves/block -> better CU fill on the L2-latency-bound gather). Bit-exact
// vs the 256-thread version (same per-e work assignment & accumulation order).
__global__ __launch_bounds__(1024) void k_conv_layer_big(const float* __restrict__ f,
                                                         const float* __restrict__ verts,
                                                         const int* __restrict__ nidx,
                                                         const float* __restrict__ sd,
                                                         float* __restrict__ outf,
                                                         int V, int C, int relu_out) {
  int row = blockIdx.x;
  int b = row / V, v = row % V;
  int E = 4 * C;
  extern __shared__ float sm[];
  float* mcol = sm;
  float* nd = sm + E;
  int* jr = (int*)(nd + 60);
  int tid = threadIdx.x;
  const float* vb = verts + (size_t)b * V * 3;
  if (tid < NEI) {
    int j = nidx[(size_t)row * NEI + tid];
    jr[tid] = j;
    float dx = vb[3 * j] - vb[3 * v];
    float dy = vb[3 * j + 1] - vb[3 * v + 1];
    float dz = vb[3 * j + 2] - vb[3 * v + 2];
    float nrm = sqrtf(dx * dx + dy * dy + dz * dz);
    float m = fmaxf(nrm, 1e-12f);
    nd[tid * 3] = dx / m; nd[tid * 3 + 1] = dy / m; nd[tid * 3 + 2] = dz / m;
  }
  __syncthreads();
  size_t fb = (size_t)b * V;
  int fivec = 5 * C;
  for (int e = tid; e < E; e += blockDim.x) {
    float s0 = sd[e], s1 = sd[E + e], s2 = sd[2 * E + e];
    float me = -INFINITY;
#pragma unroll
    for (int n = 0; n < NEI; ++n) {
      float th = nd[3 * n] * s0 + nd[3 * n + 1] * s1 + nd[3 * n + 2] * s2;
      th = fmaxf(th, 0.0f);
      float fv = f[(fb + jr[n]) * (size_t)fivec + C + e];
      me = fmaxf(me, th * fv);
    }
    mcol[e] = me;
  }
  __syncthreads();
  for (int c = tid; c < C; c += blockDim.x) {
    float o = f[(size_t)row * fivec + c] + mcol[c] + mcol[C + c] + mcol[2 * C + c] + mcol[3 * C + c];
    if (relu_out) o = fmaxf(o, 0.0f);
    outf[(size_t)row * C + c] = o;
  }
}

// transpose (B, V, C) -> (B, C, V), 32x32 LDS tiles, coalesced both sides
__global__ __launch_bounds__(256) void k_transpose_vc(const float* __restrict__ in,
                                                      float* __restrict__ out,
                                                      int V, int C) {
  __shared__ float tile[32][33];
  int b = blockIdx.z;
  int c0 = blockIdx.x * 32, v0 = blockIdx.y * 32;
  int tx = threadIdx.x & 31, ty4 = threadIdx.x >> 5;
#pragma unroll
  for (int j = 0; j < 4; ++j) {
    int v = v0 + ty4 * 4 + j;
    tile[ty4 * 4 + j][tx] = in[((size_t)b * V + v) * C + c0 + tx];
  }
  __syncthreads();
#pragma unroll
  for (int j = 0; j < 4; ++j) {
    int c = c0 + ty4 * 4 + j;
    out[((size_t)b * C + c) * V + v0 + tx] = tile[tx][ty4 * 4 + j];
  }
}

// fused pool (max over neighbors at selected rows) + pooled-vertex gather
__global__ void k_pool_sel(const float* __restrict__ fm, const int* __restrict__ nidx,
                           const int* __restrict__ sel, float* __restrict__ outp,
                           const float* __restrict__ vinA, float* __restrict__ voutA,
                           float4* __restrict__ pkout,
                           int Vin, int Vout, int C) {
  int t = blockIdx.x * blockDim.x + threadIdx.x;
  if (t < 4 * Vout) {
    int p = t % Vout;
    int b = t / Vout;
    int src = b * Vin + sel[p];
    float x = vinA[3 * src], y = vinA[3 * src + 1], z = vinA[3 * src + 2];
    int dst = b * Vout + p;
    voutA[3 * dst] = x; voutA[3 * dst + 1] = y; voutA[3 * dst + 2] = z;
    pkout[dst] = make_float4(x, y, z, x * x + y * y + z * z);
  }
  int total = 4 * Vout * C;
  if (t >= total) return;
  int c = t % C;
  int p = (t / C) % Vout;
  int b = t / (C * Vout);
  int sv = sel[p];
  const int* ir = nidx + ((size_t)b * Vin + sv) * NEI;
  float m = -INFINITY;
#pragma unroll
  for (int n = 0; n < NEI; ++n)
    m = fmaxf(m, fm[((size_t)b * Vin + ir[n]) * C + c]);
  outp[((size_t)b * Vout + p) * C + c] = m;
}

// ===================== launch =====================
extern "C" void kernel_launch(void* const* d_in, const int* in_sizes, int n_in,
                              void* d_out, int out_size, void* d_ws, size_t ws_size,
                              hipStream_t stream) {
  (void)in_sizes; (void)n_in; (void)out_size; (void)ws_size;
  const int B = 4, V1 = 4096, V2 = 1024, V3 = 256;

  const float* vin   = (const float*)d_in[0];
  const float* dirs0 = (const float*)d_in[1];
  const float* W1 = (const float*)d_in[2];
  const float* b1 = (const float*)d_in[3];
  const float* D1 = (const float*)d_in[4];
  const float* W2 = (const float*)d_in[5];
  const float* b2 = (const float*)d_in[6];
  const float* D2 = (const float*)d_in[7];
  const float* W3 = (const float*)d_in[8];
  const float* b3 = (const float*)d_in[9];
  const float* D3 = (const float*)d_in[10];
  const float* W4 = (const float*)d_in[11];
  const float* b4 = (const float*)d_in[12];
  const float* D4 = (const float*)d_in[13];
  float* out = (float*)d_out;

  char* ws = (char*)d_ws;
  size_t off = 0;
  auto alloc = [&](size_t bytes) -> char* {
    char* p = ws + off;
    off = (off + bytes + 255) & ~(size_t)255;
    return p;
  };
  int* sel1 = (int*)alloc((size_t)V2 * 4);
  int* sel2 = (int*)alloc((size_t)V3 * 4);
  float* verts1 = (float*)alloc((size_t)B * V1 * 3 * 4);
  float* verts2 = (float*)alloc((size_t)B * V2 * 3 * 4);
  float* verts3 = (float*)alloc((size_t)B * V3 * 3 * 4);
  float4* pk1 = (float4*)alloc((size_t)B * V1 * 16);
  float4* pk2 = (float4*)alloc((size_t)B * V2 * 16);
  float4* pk3 = (float4*)alloc((size_t)B * V3 * 16);
  int* idx1 = (int*)alloc((size_t)B * V1 * NEI * 4);
  int* idx2 = (int*)alloc((size_t)B * V2 * NEI * 4);
  int* idx3 = (int*)alloc((size_t)B * V3 * NEI * 4);
  float* sd0 = (float*)alloc(3 * 128 * 4);
  float* sd1 = (float*)alloc(3 * 256 * 4);
  float* sd2 = (float*)alloc(3 * 512 * 4);
  float* sd3 = (float*)alloc(3 * 1024 * 4);
  float* sd4 = (float*)alloc(3 * 4096 * 4);
  float* bufA = (float*)alloc((size_t)B * V1 * 32 * 4);
  float* bufB = (float*)alloc((size_t)B * V1 * 64 * 4);
  float* bufC = (float*)alloc((size_t)B * V2 * 64 * 4);
  float* fbuf = (float*)alloc((size_t)B * V1 * 320 * 4);
  float* fm0 = bufA, *fm2 = bufA;
  float* fm1 = bufB, *fm3 = bufB;
  float* fm1p = bufC, *fm3p = bufC;
  float* conv4out = bufB;

  static int perm1[4096];
  static int perm2[1024];
  static int selh[1280];
  jax_permutation(42u, 4096, 2, perm1);
  jax_permutation(43u, 1024, 1, perm2);
  memcpy(selh, perm1, 1024 * sizeof(int));
  memcpy(selh + 1024, perm2, 256 * sizeof(int));
  hipMemcpyAsync(sel1, selh, 1024 * sizeof(int), hipMemcpyHostToDevice, stream);
  hipMemcpyAsync(sel2, selh + 1024, 256 * sizeof(int), hipMemcpyHostToDevice, stream);

  // fused sanitize + dirs normalize
  k_setup<<<88, 256, 0, stream>>>(vin, verts1, pk1, B * V1,
                                  dirs0, D1, D2, D3, D4, sd0, sd1, sd2, sd3, sd4);
  // knn level 1 (VCAND = 64), 2 queries/wave, 8 queries/block
  k_knn8<64><<<B * V1 / 8, 256, 0, stream>>>(pk1, idx1, V1);
  k_conv_surface<<<B * V1, 128, 0, stream>>>(verts1, idx1, sd0, fm0, V1);
  // layer1 (N=320 not /128 -> 64-tile)
  k_gemm_bias<<<dim3(5, 256), 256, 0, stream>>>(fm0, W1, b1, fbuf, B * V1, 320, 32);
  k_conv_layer<<<B * V1, 256, (4 * 64 + 80) * 4, stream>>>(fbuf, verts1, idx1, sd1, fm1, V1, 64, 1);
  // pool1 (fused pool + vertex gather)
  {
    int total = B * V2 * 64;
    k_pool_sel<<<(total + 255) / 256, 256, 0, stream>>>(fm1, idx1, sel1, fm1p,
                                                        verts1, verts2, pk2,
                                                        V1, V2, 64);
  }
  // knn level 2 (VCAND = 16)
  k_knn8<16><<<B * V2 / 8, 256, 0, stream>>>(pk2, idx2, V2);
  // layer2: 4096x640x64
  k_gemm128<<<dim3(640 / 128, 4096 / 128), 256, 0, stream>>>(fm1p, W2, b2, fbuf, B * V2, 640, 64);
  k_conv_layer<<<B * V2, 256, (4 * 128 + 80) * 4, stream>>>(fbuf, verts2, idx2, sd2, fm2, V2, 128, 1);
  // layer3: 4096x1280x128
  k_gemm128<<<dim3(1280 / 128, 4096 / 128), 256, 0, stream>>>(fm2, W3, b3, fbuf, B * V2, 1280, 128);
  k_conv_layer<<<B * V2, 256, (4 * 256 + 80) * 4, stream>>>(fbuf, verts2, idx2, sd3, fm3, V2, 256, 1);
  // pool2 (fused)
  {
    int total = B * V3 * 256;
    k_pool_sel<<<(total + 255) / 256, 256, 0, stream>>>(fm3, idx2, sel2, fm3p,
                                                        verts2, verts3, pk3,
                                                        V2, V3, 256);
  }
  // knn level 3 (VCAND = 4)
  k_knn8<4><<<B * V3 / 8, 256, 0, stream>>>(pk3, idx3, V3);
  // layer4: 1024x5120x256, conv C=1024 (1024-thread scalar clone), transpose
  k_gemm128<<<dim3(5120 / 128, 1024 / 128), 256, 0, stream>>>(fm3p, W4, b4, fbuf, B * V3, 5120, 256);
  k_conv_layer_big<<<B * V3, 1024, (4 * 1024 + 80) * 4, stream>>>(fbuf, verts3, idx3, sd4, conv4out, V3, 1024, 0);
  k_transpose_vc<<<dim3(1024 / 32, 256 / 32, B), 256, 0, stream>>>(conv4out, out, V3, 1024);
}

// Round 8
// 403.249 us; speedup vs baseline: 1.1491x; 1.1105x over previous
//
#include <hip/hip_runtime.h>
#include <vector>
#include <algorithm>
#include <cstdint>
#include <cstring>
#include <cmath>

// ===================== host-side JAX threefry replication =====================
static inline uint32_t tf_rotl(uint32_t x, int r) { return (x << r) | (x >> (32 - r)); }

static void tf2x32(uint32_t k0, uint32_t k1, uint32_t x0, uint32_t x1,
                   uint32_t* o0, uint32_t* o1) {
  uint32_t ks2 = k0 ^ k1 ^ 0x1BD11BDAu;
  uint32_t v0 = x0 + k0, v1 = x1 + k1;
  static const int R0[4] = {13, 15, 26, 6}, R1[4] = {17, 29, 16, 24};
#define RND4(R) do { for (int i_ = 0; i_ < 4; ++i_) { v0 += v1; v1 = tf_rotl(v1, R[i_]); v1 ^= v0; } } while (0)
  RND4(R0); v0 += k1;  v1 += ks2 + 1u;
  RND4(R1); v0 += ks2; v1 += k0 + 2u;
  RND4(R0); v0 += k0;  v1 += k1 + 3u;
  RND4(R1); v0 += k1;  v1 += ks2 + 4u;
  RND4(R0); v0 += ks2; v1 += k0 + 5u;
#undef RND4
  *o0 = v0; *o1 = v1;
}

static void jax_permutation(uint32_t seed, int n, int rounds, int* x) {
  uint32_t k0 = 0u, k1 = seed;
  for (int i = 0; i < n; ++i) x[i] = i;
  std::vector<uint32_t> bits(n);
  std::vector<int> ord(n), xn(n);
  for (int r = 0; r < rounds; ++r) {
    uint32_t nk0, nk1, sk0, sk1;
    tf2x32(k0, k1, 0u, 0u, &nk0, &nk1);
    tf2x32(k0, k1, 0u, 1u, &sk0, &sk1);
    for (int i = 0; i < n; ++i) {
      uint32_t h, l;
      tf2x32(sk0, sk1, 0u, (uint32_t)i, &h, &l);
      bits[i] = h ^ l;
    }
    for (int i = 0; i < n; ++i) ord[i] = i;
    std::stable_sort(ord.begin(), ord.end(),
                     [&](int a, int b) { return bits[a] < bits[b]; });
    for (int i = 0; i < n; ++i) xn[i] = x[ord[i]];
    memcpy(x, xn.data(), (size_t)n * sizeof(int));
    k0 = nk0; k1 = nk1;
  }
}

// ===================== device kernels =====================
#define NEI 20

__device__ __forceinline__ float san(float v) {
  v = (v != v) ? 0.0f : v;
  return fmaxf(-1e4f, fminf(v, 1e4f));
}

// fused setup: blocks 0..63 sanitize vertices -> AoS + packed float4{x,y,z,sq};
// blocks 64..87 normalize the 5 direction matrices.
__global__ void k_setup(const float* __restrict__ vin, float* __restrict__ outA,
                        float4* __restrict__ pk, int nverts,
                        const float* __restrict__ d0, const float* __restrict__ d1,
                        const float* __restrict__ d2, const float* __restrict__ d3,
                        const float* __restrict__ d4,
                        float* __restrict__ s0, float* __restrict__ s1,
                        float* __restrict__ s2, float* __restrict__ s3,
                        float* __restrict__ s4) {
  int blk = blockIdx.x;
  if (blk < 64) {
    int i = blk * 256 + threadIdx.x;
    if (i >= nverts) return;
    float x = san(vin[3 * i]), y = san(vin[3 * i + 1]), z = san(vin[3 * i + 2]);
    outA[3 * i] = x; outA[3 * i + 1] = y; outA[3 * i + 2] = z;
    pk[i] = make_float4(x, y, z, x * x + y * y + z * z);
    return;
  }
  int t = (blk - 64) * 256 + threadIdx.x;
  const float* d; float* s; int E, e;
  if (t < 128)       { d = d0; s = s0; E = 128;  e = t; }
  else if (t < 384)  { d = d1; s = s1; E = 256;  e = t - 128; }
  else if (t < 896)  { d = d2; s = s2; E = 512;  e = t - 384; }
  else if (t < 1920) { d = d3; s = s3; E = 1024; e = t - 896; }
  else if (t < 6016) { d = d4; s = s4; E = 4096; e = t - 1920; }
  else return;
  float a = san(d[e]);
  float b = san(d[E + e]);
  float c = san(d[2 * E + e]);
  float nrm = sqrtf(a * a + b * b + c * c);
  float m = fmaxf(nrm, 1e-12f);
  s[e] = a / m; s[E + e] = b / m; s[2 * E + e] = c / m;
}

// total-order map for fp32 bits: monotone u32 for any float (handles negatives)
__device__ __forceinline__ unsigned fmap(float f) {
  unsigned u = __float_as_uint(f);
  return u ^ ((u & 0x80000000u) ? 0xFFFFFFFFu : 0x80000000u);
}

// --- 64-lane u32 min, broadcast via readlane (SGPR, no LDS round-trip) ---
__device__ __forceinline__ unsigned dpp_min_bcast1(unsigned a) {
  unsigned t;
  t = (unsigned)__builtin_amdgcn_update_dpp((int)a, (int)a, 0xB1, 0xF, 0xF, true);
  a = t < a ? t : a;
  t = (unsigned)__builtin_amdgcn_update_dpp((int)a, (int)a, 0x4E, 0xF, 0xF, true);
  a = t < a ? t : a;
  t = (unsigned)__builtin_amdgcn_update_dpp((int)a, (int)a, 0x141, 0xF, 0xF, true);
  a = t < a ? t : a;
  t = (unsigned)__builtin_amdgcn_update_dpp((int)a, (int)a, 0x140, 0xF, 0xF, true);
  a = t < a ? t : a;
  t = (unsigned)__builtin_amdgcn_update_dpp((int)a, (int)a, 0x142, 0xA, 0xF, false);
  a = t < a ? t : a;
  t = (unsigned)__builtin_amdgcn_update_dpp((int)a, (int)a, 0x143, 0xC, 0xF, false);
  a = t < a ? t : a;
  return (unsigned)__builtin_amdgcn_readlane((int)a, 63);
}

__device__ __forceinline__ void dpp_min_bcast2(unsigned& a, unsigned& b) {
  unsigned t0, t1;
#define STEP_DPP(ctrl, rm, bc)                                                           \
  t0 = (unsigned)__builtin_amdgcn_update_dpp((int)a, (int)a, ctrl, rm, 0xF, bc);         \
  t1 = (unsigned)__builtin_amdgcn_update_dpp((int)b, (int)b, ctrl, rm, 0xF, bc);         \
  a = t0 < a ? t0 : a; b = t1 < b ? t1 : b;
  STEP_DPP(0xB1, 0xF, true)
  STEP_DPP(0x4E, 0xF, true)
  STEP_DPP(0x141, 0xF, true)
  STEP_DPP(0x140, 0xF, true)
  STEP_DPP(0x142, 0xA, false)
  STEP_DPP(0x143, 0xC, false)
#undef STEP_DPP
  a = (unsigned)__builtin_amdgcn_readlane((int)a, 63);
  b = (unsigned)__builtin_amdgcn_readlane((int)b, 63);
}

// KNN v10 (R15-proven, ~90 µs): u64-key sorted top-3 queues, float4 loads,
// readlane broadcasts. CLOSED lines: u32 pre-filter (R19: +6 µs — exec-mask
// means the insert body issues anyway, filter is pure overhead); split u64
// key (R13 bug: dist-only compare broke index ties); dual-queue (R11/R12:
// scratch spills). This is the terminal form of this algorithm.
template <int VCAND>
__global__ __launch_bounds__(256, 8) void k_knn8(const float4* __restrict__ pk,
                                                 int* __restrict__ nidx, int V) {
  const int wid = threadIdx.x >> 6;
  const int lane = threadIdx.x & 63;
  const int row0 = blockIdx.x * 8 + wid * 2;
  const int b = row0 / V;
  const int base = b * V;
  const int i0 = row0 % V;

  float xi[2], yi[2], zi[2], sqi[2];
#pragma unroll
  for (int t = 0; t < 2; ++t) {
    float4 q = pk[base + i0 + t];
    xi[t] = q.x; yi[t] = q.y; zi[t] = q.z; sqi[t] = q.w;
  }

  unsigned long long q0[2] = {~0ULL, ~0ULL}, q1[2] = {~0ULL, ~0ULL}, q2[2] = {~0ULL, ~0ULL};
#pragma unroll 4
  for (int c = 0; c < VCAND; ++c) {
    int j = c * 64 + lane;
    float4 cj = pk[base + j];
    float xj = cj.x, yj = cj.y, zj = cj.z, sqj = cj.w;
#pragma unroll
    for (int t = 0; t < 2; ++t) {
      float dot = xi[t] * xj + yi[t] * yj + zi[t] * zj;
      float dd = (sqi[t] + sqj) - 2.0f * dot;
      unsigned long long k = (((unsigned long long)fmap(dd)) << 32) | (unsigned)j;
      if (k < q2[t]) {
        if (k < q1[t]) {
          q2[t] = q1[t];
          if (k < q0[t]) { q1[t] = q0[t]; q0[t] = k; } else { q1[t] = k; }
        } else {
          q2[t] = k;
        }
      }
    }
  }

  for (int r = 0; r < 21; ++r) {
    unsigned h0 = (unsigned)(q0[0] >> 32);
    unsigned h1 = (unsigned)(q0[1] >> 32);
    unsigned m0 = h0, m1 = h1;
    dpp_min_bcast2(m0, m1);
    unsigned long long mk0 = __ballot(h0 == m0);
    unsigned long long mk1 = __ballot(h1 == m1);
    bool win0, win1;
    if (__popcll(mk0) > 1) {  // rare: dist-bit tie across lanes -> index min
      unsigned jj = (h0 == m0) ? (unsigned)q0[0] : 0xFFFFFFFFu;
      unsigned jm = dpp_min_bcast1(jj);
      win0 = (h0 == m0) && ((unsigned)q0[0] == jm);
    } else {
      win0 = (h0 == m0);
    }
    if (__popcll(mk1) > 1) {
      unsigned jj = (h1 == m1) ? (unsigned)q0[1] : 0xFFFFFFFFu;
      unsigned jm = dpp_min_bcast1(jj);
      win1 = (h1 == m1) && ((unsigned)q0[1] == jm);
    } else {
      win1 = (h1 == m1);
    }
    if (win0) {
      if (r > 0) nidx[(size_t)row0 * NEI + (r - 1)] = (int)(unsigned)q0[0];
      unsigned long long bound = q0[0];
      q0[0] = q1[0]; q1[0] = q2[0]; q2[0] = ~0ULL;
      if (q0[0] == ~0ULL) {
        unsigned long long nm = ~0ULL;
        for (int c = 0; c < VCAND; ++c) {
          int j = c * 64 + lane;
          float4 cj = pk[base + j];
          float dot = xi[0] * cj.x + yi[0] * cj.y + zi[0] * cj.z;
          float dd = (sqi[0] + cj.w) - 2.0f * dot;
          unsigned long long k = (((unsigned long long)fmap(dd)) << 32) | (unsigned)j;
          if (k > bound && k < nm) nm = k;
        }
        q0[0] = nm;
      }
    }
    if (win1) {
      if (r > 0) nidx[(size_t)(row0 + 1) * NEI + (r - 1)] = (int)(unsigned)q0[1];
      unsigned long long bound = q0[1];
      q0[1] = q1[1]; q1[1] = q2[1]; q2[1] = ~0ULL;
      if (q0[1] == ~0ULL) {
        unsigned long long nm = ~0ULL;
        for (int c = 0; c < VCAND; ++c) {
          int j = c * 64 + lane;
          float4 cj = pk[base + j];
          float dot = xi[1] * cj.x + yi[1] * cj.y + zi[1] * cj.z;
          float dd = (sqi[1] + cj.w) - 2.0f * dot;
          unsigned long long k = (((unsigned long long)fmap(dd)) << 32) | (unsigned)j;
          if (k > bound && k < nm) nm = k;
        }
        q0[1] = nm;
      }
    }
  }
}

// conv_surface: C=32, E=128. One block (128 thr) per (b,v).
__global__ __launch_bounds__(128) void k_conv_surface(const float* __restrict__ verts,
                                                      const int* __restrict__ nidx,
                                                      const float* __restrict__ sd,
                                                      float* __restrict__ fm, int V) {
  int row = blockIdx.x;
  int b = row / V, v = row % V;
  const float* vb = verts + (size_t)b * V * 3;
  __shared__ float nd[60];
  __shared__ float mcol[128];
  int tid = threadIdx.x;
  if (tid < NEI) {
    int j = nidx[(size_t)row * NEI + tid];
    float dx = vb[3 * j] - vb[3 * v];
    float dy = vb[3 * j + 1] - vb[3 * v + 1];
    float dz = vb[3 * j + 2] - vb[3 * v + 2];
    float nrm = sqrtf(dx * dx + dy * dy + dz * dz);
    float m = fmaxf(nrm, 1e-12f);
    nd[tid * 3] = dx / m; nd[tid * 3 + 1] = dy / m; nd[tid * 3 + 2] = dz / m;
  }
  __syncthreads();
  {
    int e = tid;
    float s0 = sd[e], s1 = sd[128 + e], s2 = sd[256 + e];
    float me = 0.0f;
#pragma unroll
    for (int n = 0; n < NEI; ++n) {
      float th = nd[3 * n] * s0 + nd[3 * n + 1] * s1 + nd[3 * n + 2] * s2;
      th = fmaxf(th, 0.0f);
      me = fmaxf(me, th);
    }
    mcol[e] = me;
  }
  __syncthreads();
  if (tid < 32) {
    float o = mcol[tid] + mcol[32 + tid] + mcol[64 + tid] + mcol[96 + tid];
    o = fmaxf(o, 0.0f);
    fm[(size_t)row * 32 + tid] = o;
  }
}

// fp32 tiled GEMM 64x64x16 (guarded; used for layer1): C = A*W + bias
__global__ __launch_bounds__(256) void k_gemm_bias(const float* __restrict__ A,
                                                   const float* __restrict__ W,
                                                   const float* __restrict__ bias,
                                                   float* __restrict__ Cm,
                                                   int M, int N, int K) {
  __shared__ float As[16][68];
  __shared__ float Bs[16][68];
  int n0 = blockIdx.x * 64, m0 = blockIdx.y * 64;
  int tx = threadIdx.x & 15, ty = threadIdx.x >> 4;
  float acc[4][4] = {};
  for (int k0 = 0; k0 < K; k0 += 16) {
    for (int t = threadIdx.x; t < 1024; t += 256) {
      int mm = t >> 4, kk = t & 15;
      int m = m0 + mm;
      As[kk][mm] = (m < M) ? A[(size_t)m * K + (k0 + kk)] : 0.0f;
    }
    for (int t = threadIdx.x; t < 1024; t += 256) {
      int kk = t >> 6, nn = t & 63;
      int n = n0 + nn;
      Bs[kk][nn] = (n < N) ? san(W[(size_t)(k0 + kk) * N + n]) : 0.0f;
    }
    __syncthreads();
#pragma unroll
    for (int kk = 0; kk < 16; ++kk) {
      float4 av = *(const float4*)&As[kk][ty << 2];
      float4 bv = *(const float4*)&Bs[kk][tx << 2];
      float a[4] = {av.x, av.y, av.z, av.w};
      float bb[4] = {bv.x, bv.y, bv.z, bv.w};
#pragma unroll
      for (int i = 0; i < 4; ++i)
#pragma unroll
        for (int j = 0; j < 4; ++j) acc[i][j] += a[i] * bb[j];
    }
    __syncthreads();
  }
  for (int i = 0; i < 4; ++i)
    for (int j = 0; j < 4; ++j) {
      int m = m0 + (ty << 2) + i, n = n0 + (tx << 2) + j;
      if (m < M && n < N) Cm[(size_t)m * N + n] = acc[i][j] + san(bias[n]);
    }
}

// ===================== split-bf16 MFMA GEMM path =====================
typedef __attribute__((ext_vector_type(8))) short v8h;
typedef __attribute__((ext_vector_type(4))) float v4f;

// RNE fp32 -> bf16 bit pattern (inputs finite: san'd or internally produced)
__device__ __forceinline__ unsigned short f2bf(float f) {
  unsigned u = __float_as_uint(f);
  u = u + 0x7FFFu + ((u >> 16) & 1u);
  return (unsigned short)(u >> 16);
}
__device__ __forceinline__ float bf2f(unsigned short h) {
  return __uint_as_float((unsigned)h << 16);
}

// elementwise split fp32 -> (hi, lo) bf16 bits; n % 256 == 0 at call sites
__global__ __launch_bounds__(256) void k_split(const float* __restrict__ in,
                                               unsigned short* __restrict__ hi,
                                               unsigned short* __restrict__ lo, int n) {
  int i = blockIdx.x * 256 + threadIdx.x;
  if (i >= n) return;
  float a = in[i];
  unsigned short h = f2bf(a);
  hi[i] = h;
  lo[i] = f2bf(a - bf2f(h));
}

// transpose + split: W [K][N] fp32 (san applied, matching old k_gemm128
// staging) -> WhT, WlT [N][K] bf16 bits. 32x32 LDS tile transpose.
__global__ __launch_bounds__(256) void k_split_wT(const float* __restrict__ W,
                                                  unsigned short* __restrict__ hiT,
                                                  unsigned short* __restrict__ loT,
                                                  int K, int N) {
  __shared__ float tile[32][33];
  int k0 = blockIdx.y * 32, n0 = blockIdx.x * 32;
  int tx = threadIdx.x & 31, ty4 = threadIdx.x >> 5;
#pragma unroll
  for (int j = 0; j < 4; ++j)
    tile[ty4 * 4 + j][tx] = san(W[(size_t)(k0 + ty4 * 4 + j) * N + n0 + tx]);
  __syncthreads();
#pragma unroll
  for (int j = 0; j < 4; ++j) {
    int n = n0 + ty4 * 4 + j;
    float a = tile[tx][ty4 * 4 + j];
    unsigned short h = f2bf(a);
    hiT[(size_t)n * K + k0 + tx] = h;
    loT[(size_t)n * K + k0 + tx] = f2bf(a - bf2f(h));
  }
}

// C = A*W + bias via 3-term split-bf16 MFMA: ab ~= ah*bh + ah*bl + al*bh
// (al*bl ~ 2^-18 rel, dropped). fp32 accumulation in MFMA; rel err ~2e-5.
// A as (Ah,Al) [M][K]; W as (BhT,BlT) [N][K] (transposed so both sides stage
// row-major, k-contiguous). M%128==0, N%128==0, K%32==0.
// 256 thr = 4 waves in 2x2; each wave computes 64x64 = 4x4 tiles of 16x16,
// K-step 32 (one mfma_f32_16x16x32_bf16 per tile per term).
// Layout notes: C/D mapping col=lane&15, row=(lane>>4)*4+reg is HW-verified
// (m89). Per-lane k-slot order is ANY bijection as long as A and B frags use
// the same one (dot pairs slot s of A-lane(row,kb) with slot s of
// B-lane(col,kb)) — we use k = (lane>>4)*8 + e, a single 16B LDS read.
__global__ __launch_bounds__(256) void k_gemm128_mfma(
    const unsigned short* __restrict__ Ah, const unsigned short* __restrict__ Al,
    const unsigned short* __restrict__ BhT, const unsigned short* __restrict__ BlT,
    const float* __restrict__ bias, float* __restrict__ Cm, int M, int N, int K) {
  __shared__ __attribute__((aligned(16))) unsigned short sAh[128 * 40];
  __shared__ __attribute__((aligned(16))) unsigned short sAl[128 * 40];
  __shared__ __attribute__((aligned(16))) unsigned short sBh[128 * 40];
  __shared__ __attribute__((aligned(16))) unsigned short sBl[128 * 40];
  const int n0 = blockIdx.x * 128, m0 = blockIdx.y * 128;
  const int l = threadIdx.x & 63;
  const int w = threadIdx.x >> 6;
  const int wr = (w >> 1) * 64, wc = (w & 1) * 64;
  const int lr = l & 15;
  const int kb8 = (l >> 4) * 8;

  v4f acc[4][4];
#pragma unroll
  for (int i = 0; i < 4; ++i)
#pragma unroll
    for (int j = 0; j < 4; ++j) acc[i][j] = (v4f){0.f, 0.f, 0.f, 0.f};

  for (int k0 = 0; k0 < K; k0 += 32) {
    // stage 4 arrays: 128 rows x 32 k (bf16) each; 512 16B-chunks per array
#pragma unroll
    for (int q = 0; q < 2; ++q) {
      int lin = (int)threadIdx.x + (q << 8);
      int r = lin >> 2, kc = (lin & 3) << 3;
      *(uint4*)&sAh[r * 40 + kc] = *(const uint4*)&Ah[(size_t)(m0 + r) * K + k0 + kc];
      *(uint4*)&sAl[r * 40 + kc] = *(const uint4*)&Al[(size_t)(m0 + r) * K + k0 + kc];
      *(uint4*)&sBh[r * 40 + kc] = *(const uint4*)&BhT[(size_t)(n0 + r) * K + k0 + kc];
      *(uint4*)&sBl[r * 40 + kc] = *(const uint4*)&BlT[(size_t)(n0 + r) * K + k0 + kc];
    }
    __syncthreads();
    v8h fah[4], fal[4], fbh[4], fbl[4];
#pragma unroll
    for (int t = 0; t < 4; ++t) {
      fah[t] = *(const v8h*)&sAh[(wr + t * 16 + lr) * 40 + kb8];
      fal[t] = *(const v8h*)&sAl[(wr + t * 16 + lr) * 40 + kb8];
      fbh[t] = *(const v8h*)&sBh[(wc + t * 16 + lr) * 40 + kb8];
      fbl[t] = *(const v8h*)&sBl[(wc + t * 16 + lr) * 40 + kb8];
    }
#pragma unroll
    for (int i = 0; i < 4; ++i)
#pragma unroll
      for (int j = 0; j < 4; ++j) {
        acc[i][j] = __builtin_amdgcn_mfma_f32_16x16x32_bf16(fah[i], fbh[j], acc[i][j], 0, 0, 0);
        acc[i][j] = __builtin_amdgcn_mfma_f32_16x16x32_bf16(fah[i], fbl[j], acc[i][j], 0, 0, 0);
        acc[i][j] = __builtin_amdgcn_mfma_f32_16x16x32_bf16(fal[i], fbh[j], acc[i][j], 0, 0, 0);
      }
    __syncthreads();
  }
  float bs[4];
#pragma unroll
  for (int j = 0; j < 4; ++j) bs[j] = san(bias[n0 + wc + j * 16 + lr]);
  const int rowb = m0 + wr + (l >> 4) * 4;
#pragma unroll
  for (int i = 0; i < 4; ++i)
#pragma unroll
    for (int j = 0; j < 4; ++j) {
      int col = n0 + wc + j * 16 + lr;
#pragma unroll
      for (int v = 0; v < 4; ++v)
        Cm[(size_t)(rowb + i * 16 + v) * N + col] = acc[i][j][v] + bs[j];
    }
}

// conv layer (scalar, R15-proven; float4-gather variants regressed — closed)
__global__ __launch_bounds__(256) void k_conv_layer(const float* __restrict__ f,
                                                    const float* __restrict__ verts,
                                                    const int* __restrict__ nidx,
                                                    const float* __restrict__ sd,
                                                    float* __restrict__ outf,
                                                    int V, int C, int relu_out) {
  int row = blockIdx.x;
  int b = row / V, v = row % V;
  int E = 4 * C;
  extern __shared__ float sm[];
  float* mcol = sm;
  float* nd = sm + E;
  int* jr = (int*)(nd + 60);
  int tid = threadIdx.x;
  const float* vb = verts + (size_t)b * V * 3;
  if (tid < NEI) {
    int j = nidx[(size_t)row * NEI + tid];
    jr[tid] = j;
    float dx = vb[3 * j] - vb[3 * v];
    float dy = vb[3 * j + 1] - vb[3 * v + 1];
    float dz = vb[3 * j + 2] - vb[3 * v + 2];
    float nrm = sqrtf(dx * dx + dy * dy + dz * dz);
    float m = fmaxf(nrm, 1e-12f);
    nd[tid * 3] = dx / m; nd[tid * 3 + 1] = dy / m; nd[tid * 3 + 2] = dz / m;
  }
  __syncthreads();
  size_t fb = (size_t)b * V;
  int fivec = 5 * C;
  for (int e = tid; e < E; e += blockDim.x) {
    float s0 = sd[e], s1 = sd[E + e], s2 = sd[2 * E + e];
    float me = -INFINITY;
#pragma unroll
    for (int n = 0; n < NEI; ++n) {
      float th = nd[3 * n] * s0 + nd[3 * n + 1] * s1 + nd[3 * n + 2] * s2;
      th = fmaxf(th, 0.0f);
      float fv = f[(fb + jr[n]) * (size_t)fivec + C + e];
      me = fmaxf(me, th * fv);
    }
    mcol[e] = me;
  }
  __syncthreads();
  for (int c = tid; c < C; c += blockDim.x) {
    float o = f[(size_t)row * fivec + c] + mcol[c] + mcol[C + c] + mcol[2 * C + c] + mcol[3 * C + c];
    if (relu_out) o = fmaxf(o, 0.0f);
    outf[(size_t)row * C + c] = o;
  }
}

// 1024-thread clone for the layer-4 conv (bit-exact vs 256-thr version)
__global__ __launch_bounds__(1024) void k_conv_layer_big(const float* __restrict__ f,
                                                         const float* __restrict__ verts,
                                                         const int* __restrict__ nidx,
                                                         const float* __restrict__ sd,
                                                         float* __restrict__ outf,
                                                         int V, int C, int relu_out) {
  int row = blockIdx.x;
  int b = row / V, v = row % V;
  int E = 4 * C;
  extern __shared__ float sm[];
  float* mcol = sm;
  float* nd = sm + E;
  int* jr = (int*)(nd + 60);
  int tid = threadIdx.x;
  const float* vb = verts + (size_t)b * V * 3;
  if (tid < NEI) {
    int j = nidx[(size_t)row * NEI + tid];
    jr[tid] = j;
    float dx = vb[3 * j] - vb[3 * v];
    float dy = vb[3 * j + 1] - vb[3 * v + 1];
    float dz = vb[3 * j + 2] - vb[3 * v + 2];
    float nrm = sqrtf(dx * dx + dy * dy + dz * dz);
    float m = fmaxf(nrm, 1e-12f);
    nd[tid * 3] = dx / m; nd[tid * 3 + 1] = dy / m; nd[tid * 3 + 2] = dz / m;
  }
  __syncthreads();
  size_t fb = (size_t)b * V;
  int fivec = 5 * C;
  for (int e = tid; e < E; e += blockDim.x) {
    float s0 = sd[e], s1 = sd[E + e], s2 = sd[2 * E + e];
    float me = -INFINITY;
#pragma unroll
    for (int n = 0; n < NEI; ++n) {
      float th = nd[3 * n] * s0 + nd[3 * n + 1] * s1 + nd[3 * n + 2] * s2;
      th = fmaxf(th, 0.0f);
      float fv = f[(fb + jr[n]) * (size_t)fivec + C + e];
      me = fmaxf(me, th * fv);
    }
    mcol[e] = me;
  }
  __syncthreads();
  for (int c = tid; c < C; c += blockDim.x) {
    float o = f[(size_t)row * fivec + c] + mcol[c] + mcol[C + c] + mcol[2 * C + c] + mcol[3 * C + c];
    if (relu_out) o = fmaxf(o, 0.0f);
    outf[(size_t)row * C + c] = o;
  }
}

// transpose (B, V, C) -> (B, C, V), 32x32 LDS tiles, coalesced both sides
__global__ __launch_bounds__(256) void k_transpose_vc(const float* __restrict__ in,
                                                      float* __restrict__ out,
                                                      int V, int C) {
  __shared__ float tile[32][33];
  int b = blockIdx.z;
  int c0 = blockIdx.x * 32, v0 = blockIdx.y * 32;
  int tx = threadIdx.x & 31, ty4 = threadIdx.x >> 5;
#pragma unroll
  for (int j = 0; j < 4; ++j) {
    int v = v0 + ty4 * 4 + j;
    tile[ty4 * 4 + j][tx] = in[((size_t)b * V + v) * C + c0 + tx];
  }
  __syncthreads();
#pragma unroll
  for (int j = 0; j < 4; ++j) {
    int c = c0 + ty4 * 4 + j;
    out[((size_t)b * C + c) * V + v0 + tx] = tile[tx][ty4 * 4 + j];
  }
}

// fused pool (max over neighbors at selected rows) + pooled-vertex gather
__global__ void k_pool_sel(const float* __restrict__ fm, const int* __restrict__ nidx,
                           const int* __restrict__ sel, float* __restrict__ outp,
                           const float* __restrict__ vinA, float* __restrict__ voutA,
                           float4* __restrict__ pkout,
                           int Vin, int Vout, int C) {
  int t = blockIdx.x * blockDim.x + threadIdx.x;
  if (t < 4 * Vout) {
    int p = t % Vout;
    int b = t / Vout;
    int src = b * Vin + sel[p];
    float x = vinA[3 * src], y = vinA[3 * src + 1], z = vinA[3 * src + 2];
    int dst = b * Vout + p;
    voutA[3 * dst] = x; voutA[3 * dst + 1] = y; voutA[3 * dst + 2] = z;
    pkout[dst] = make_float4(x, y, z, x * x + y * y + z * z);
  }
  int total = 4 * Vout * C;
  if (t >= total) return;
  int c = t % C;
  int p = (t / C) % Vout;
  int b = t / (C * Vout);
  int sv = sel[p];
  const int* ir = nidx + ((size_t)b * Vin + sv) * NEI;
  float m = -INFINITY;
#pragma unroll
  for (int n = 0; n < NEI; ++n)
    m = fmaxf(m, fm[((size_t)b * Vin + ir[n]) * C + c]);
  outp[((size_t)b * Vout + p) * C + c] = m;
}

// ===================== launch =====================
extern "C" void kernel_launch(void* const* d_in, const int* in_sizes, int n_in,
                              void* d_out, int out_size, void* d_ws, size_t ws_size,
                              hipStream_t stream) {
  (void)in_sizes; (void)n_in; (void)out_size; (void)ws_size;
  const int B = 4, V1 = 4096, V2 = 1024, V3 = 256;

  const float* vin   = (const float*)d_in[0];
  const float* dirs0 = (const float*)d_in[1];
  const float* W1 = (const float*)d_in[2];
  const float* b1 = (const float*)d_in[3];
  const float* D1 = (const float*)d_in[4];
  const float* W2 = (const float*)d_in[5];
  const float* b2 = (const float*)d_in[6];
  const float* D2 = (const float*)d_in[7];
  const float* W3 = (const float*)d_in[8];
  const float* b3 = (const float*)d_in[9];
  const float* D3 = (const float*)d_in[10];
  const float* W4 = (const float*)d_in[11];
  const float* b4 = (const float*)d_in[12];
  const float* D4 = (const float*)d_in[13];
  float* out = (float*)d_out;

  char* ws = (char*)d_ws;
  size_t off = 0;
  auto alloc = [&](size_t bytes) -> char* {
    char* p = ws + off;
    off = (off + bytes + 255) & ~(size_t)255;
    return p;
  };
  int* sel1 = (int*)alloc((size_t)V2 * 4);
  int* sel2 = (int*)alloc((size_t)V3 * 4);
  float* verts1 = (float*)alloc((size_t)B * V1 * 3 * 4);
  float* verts2 = (float*)alloc((size_t)B * V2 * 3 * 4);
  float* verts3 = (float*)alloc((size_t)B * V3 * 3 * 4);
  float4* pk1 = (float4*)alloc((size_t)B * V1 * 16);
  float4* pk2 = (float4*)alloc((size_t)B * V2 * 16);
  float4* pk3 = (float4*)alloc((size_t)B * V3 * 16);
  int* idx1 = (int*)alloc((size_t)B * V1 * NEI * 4);
  int* idx2 = (int*)alloc((size_t)B * V2 * NEI * 4);
  int* idx3 = (int*)alloc((size_t)B * V3 * NEI * 4);
  float* sd0 = (float*)alloc(3 * 128 * 4);
  float* sd1 = (float*)alloc(3 * 256 * 4);
  float* sd2 = (float*)alloc(3 * 512 * 4);
  float* sd3 = (float*)alloc(3 * 1024 * 4);
  float* sd4 = (float*)alloc(3 * 4096 * 4);
  float* bufA = (float*)alloc((size_t)B * V1 * 32 * 4);
  float* bufB = (float*)alloc((size_t)B * V1 * 64 * 4);
  float* bufC = (float*)alloc((size_t)B * V2 * 64 * 4);
  float* fbuf = (float*)alloc((size_t)B * V1 * 320 * 4);
  // split-bf16 buffers (MFMA GEMM path)
  unsigned short* w2hT = (unsigned short*)alloc((size_t)640 * 64 * 2);
  unsigned short* w2lT = (unsigned short*)alloc((size_t)640 * 64 * 2);
  unsigned short* w3hT = (unsigned short*)alloc((size_t)1280 * 128 * 2);
  unsigned short* w3lT = (unsigned short*)alloc((size_t)1280 * 128 * 2);
  unsigned short* w4hT = (unsigned short*)alloc((size_t)5120 * 256 * 2);
  unsigned short* w4lT = (unsigned short*)alloc((size_t)5120 * 256 * 2);
  unsigned short* aSh = (unsigned short*)alloc((size_t)4096 * 128 * 2);
  unsigned short* aSl = (unsigned short*)alloc((size_t)4096 * 128 * 2);
  float* fm0 = bufA, *fm2 = bufA;
  float* fm1 = bufB, *fm3 = bufB;
  float* fm1p = bufC, *fm3p = bufC;
  float* conv4out = bufB;

  static int perm1[4096];
  static int perm2[1024];
  static int selh[1280];
  jax_permutation(42u, 4096, 2, perm1);
  jax_permutation(43u, 1024, 1, perm2);
  memcpy(selh, perm1, 1024 * sizeof(int));
  memcpy(selh + 1024, perm2, 256 * sizeof(int));
  hipMemcpyAsync(sel1, selh, 1024 * sizeof(int), hipMemcpyHostToDevice, stream);
  hipMemcpyAsync(sel2, selh + 1024, 256 * sizeof(int), hipMemcpyHostToDevice, stream);

  // fused sanitize + dirs normalize
  k_setup<<<88, 256, 0, stream>>>(vin, verts1, pk1, B * V1,
                                  dirs0, D1, D2, D3, D4, sd0, sd1, sd2, sd3, sd4);
  // weight transpose+split pre-passes (independent of data flow)
  k_split_wT<<<dim3(640 / 32, 64 / 32), 256, 0, stream>>>(W2, w2hT, w2lT, 64, 640);
  k_split_wT<<<dim3(1280 / 32, 128 / 32), 256, 0, stream>>>(W3, w3hT, w3lT, 128, 1280);
  k_split_wT<<<dim3(5120 / 32, 256 / 32), 256, 0, stream>>>(W4, w4hT, w4lT, 256, 5120);
  // knn level 1 (VCAND = 64), 2 queries/wave, 8 queries/block
  k_knn8<64><<<B * V1 / 8, 256, 0, stream>>>(pk1, idx1, V1);
  k_conv_surface<<<B * V1, 128, 0, stream>>>(verts1, idx1, sd0, fm0, V1);
  // layer1 (N=320 not /128 -> fp32 64-tile)
  k_gemm_bias<<<dim3(5, 256), 256, 0, stream>>>(fm0, W1, b1, fbuf, B * V1, 320, 32);
  k_conv_layer<<<B * V1, 256, (4 * 64 + 80) * 4, stream>>>(fbuf, verts1, idx1, sd1, fm1, V1, 64, 1);
  // pool1 (fused pool + vertex gather)
  {
    int total = B * V2 * 64;
    k_pool_sel<<<(total + 255) / 256, 256, 0, stream>>>(fm1, idx1, sel1, fm1p,
                                                        verts1, verts2, pk2,
                                                        V1, V2, 64);
  }
  // knn level 2 (VCAND = 16)
  k_knn8<16><<<B * V2 / 8, 256, 0, stream>>>(pk2, idx2, V2);
  // layer2: 4096x640x64 via split-bf16 MFMA
  k_split<<<(B * V2 * 64) / 256, 256, 0, stream>>>(fm1p, aSh, aSl, B * V2 * 64);
  k_gemm128_mfma<<<dim3(640 / 128, 4096 / 128), 256, 0, stream>>>(aSh, aSl, w2hT, w2lT, b2, fbuf, B * V2, 640, 64);
  k_conv_layer<<<B * V2, 256, (4 * 128 + 80) * 4, stream>>>(fbuf, verts2, idx2, sd2, fm2, V2, 128, 1);
  // layer3: 4096x1280x128 via split-bf16 MFMA
  k_split<<<(B * V2 * 128) / 256, 256, 0, stream>>>(fm2, aSh, aSl, B * V2 * 128);
  k_gemm128_mfma<<<dim3(1280 / 128, 4096 / 128), 256, 0, stream>>>(aSh, aSl, w3hT, w3lT, b3, fbuf, B * V2, 1280, 128);
  k_conv_layer<<<B * V2, 256, (4 * 256 + 80) * 4, stream>>>(fbuf, verts2, idx2, sd3, fm3, V2, 256, 1);
  // pool2 (fused)
  {
    int total = B * V3 * 256;
    k_pool_sel<<<(total + 255) / 256, 256, 0, stream>>>(fm3, idx2, sel2, fm3p,
                                                        verts2, verts3, pk3,
                                                        V2, V3, 256);
  }
  // knn level 3 (VCAND = 4)
  k_knn8<4><<<B * V3 / 8, 256, 0, stream>>>(pk3, idx3, V3);
  // layer4: 1024x5120x256 via split-bf16 MFMA, conv C=1024, transpose
  k_split<<<(B * V3 * 256) / 256, 256, 0, stream>>>(fm3p, aSh, aSl, B * V3 * 256);
  k_gemm128_mfma<<<dim3(5120 / 128, 1024 / 128), 256, 0, stream>>>(aSh, aSl, w4hT, w4lT, b4, fbuf, B * V3, 5120, 256);
  k_conv_layer_big<<<B * V3, 1024, (4 * 1024 + 80) * 4, stream>>>(fbuf, verts3, idx3, sd4, conv4out, V3, 1024, 0);
  k_transpose_vc<<<dim3(1024 / 32, 256 / 32, B), 256, 0, stream>>>(conv4out, out, V3, 1024);
}

// Round 9
// 399.136 us; speedup vs baseline: 1.1609x; 1.0103x over previous
//
#include <hip/hip_runtime.h>
#include <vector>
#include <algorithm>
#include <cstdint>
#include <cstring>
#include <cmath>

// ===================== host-side JAX threefry replication =====================
static inline uint32_t tf_rotl(uint32_t x, int r) { return (x << r) | (x >> (32 - r)); }

static void tf2x32(uint32_t k0, uint32_t k1, uint32_t x0, uint32_t x1,
                   uint32_t* o0, uint32_t* o1) {
  uint32_t ks2 = k0 ^ k1 ^ 0x1BD11BDAu;
  uint32_t v0 = x0 + k0, v1 = x1 + k1;
  static const int R0[4] = {13, 15, 26, 6}, R1[4] = {17, 29, 16, 24};
#define RND4(R) do { for (int i_ = 0; i_ < 4; ++i_) { v0 += v1; v1 = tf_rotl(v1, R[i_]); v1 ^= v0; } } while (0)
  RND4(R0); v0 += k1;  v1 += ks2 + 1u;
  RND4(R1); v0 += ks2; v1 += k0 + 2u;
  RND4(R0); v0 += k0;  v1 += k1 + 3u;
  RND4(R1); v0 += k1;  v1 += ks2 + 4u;
  RND4(R0); v0 += ks2; v1 += k0 + 5u;
#undef RND4
  *o0 = v0; *o1 = v1;
}

static void jax_permutation(uint32_t seed, int n, int rounds, int* x) {
  uint32_t k0 = 0u, k1 = seed;
  for (int i = 0; i < n; ++i) x[i] = i;
  std::vector<uint32_t> bits(n);
  std::vector<int> ord(n), xn(n);
  for (int r = 0; r < rounds; ++r) {
    uint32_t nk0, nk1, sk0, sk1;
    tf2x32(k0, k1, 0u, 0u, &nk0, &nk1);
    tf2x32(k0, k1, 0u, 1u, &sk0, &sk1);
    for (int i = 0; i < n; ++i) {
      uint32_t h, l;
      tf2x32(sk0, sk1, 0u, (uint32_t)i, &h, &l);
      bits[i] = h ^ l;
    }
    for (int i = 0; i < n; ++i) ord[i] = i;
    std::stable_sort(ord.begin(), ord.end(),
                     [&](int a, int b) { return bits[a] < bits[b]; });
    for (int i = 0; i < n; ++i) xn[i] = x[ord[i]];
    memcpy(x, xn.data(), (size_t)n * sizeof(int));
    k0 = nk0; k1 = nk1;
  }
}

// ===================== device kernels =====================
#define NEI 20

__device__ __forceinline__ float san(float v) {
  v = (v != v) ? 0.0f : v;
  return fmaxf(-1e4f, fminf(v, 1e4f));
}

// fused setup: blocks 0..63 sanitize vertices -> AoS + packed float4{x,y,z,sq};
// blocks 64..87 normalize the 5 direction matrices.
__global__ void k_setup(const float* __restrict__ vin, float* __restrict__ outA,
                        float4* __restrict__ pk, int nverts,
                        const float* __restrict__ d0, const float* __restrict__ d1,
                        const float* __restrict__ d2, const float* __restrict__ d3,
                        const float* __restrict__ d4,
                        float* __restrict__ s0, float* __restrict__ s1,
                        float* __restrict__ s2, float* __restrict__ s3,
                        float* __restrict__ s4) {
  int blk = blockIdx.x;
  if (blk < 64) {
    int i = blk * 256 + threadIdx.x;
    if (i >= nverts) return;
    float x = san(vin[3 * i]), y = san(vin[3 * i + 1]), z = san(vin[3 * i + 2]);
    outA[3 * i] = x; outA[3 * i + 1] = y; outA[3 * i + 2] = z;
    pk[i] = make_float4(x, y, z, x * x + y * y + z * z);
    return;
  }
  int t = (blk - 64) * 256 + threadIdx.x;
  const float* d; float* s; int E, e;
  if (t < 128)       { d = d0; s = s0; E = 128;  e = t; }
  else if (t < 384)  { d = d1; s = s1; E = 256;  e = t - 128; }
  else if (t < 896)  { d = d2; s = s2; E = 512;  e = t - 384; }
  else if (t < 1920) { d = d3; s = s3; E = 1024; e = t - 896; }
  else if (t < 6016) { d = d4; s = s4; E = 4096; e = t - 1920; }
  else return;
  float a = san(d[e]);
  float b = san(d[E + e]);
  float c = san(d[2 * E + e]);
  float nrm = sqrtf(a * a + b * b + c * c);
  float m = fmaxf(nrm, 1e-12f);
  s[e] = a / m; s[E + e] = b / m; s[2 * E + e] = c / m;
}

// total-order map for fp32 bits: monotone u32 for any float (handles negatives)
__device__ __forceinline__ unsigned fmap(float f) {
  unsigned u = __float_as_uint(f);
  return u ^ ((u & 0x80000000u) ? 0xFFFFFFFFu : 0x80000000u);
}

// --- 64-lane u32 min, broadcast via readlane (SGPR, no LDS round-trip) ---
__device__ __forceinline__ unsigned dpp_min_bcast1(unsigned a) {
  unsigned t;
  t = (unsigned)__builtin_amdgcn_update_dpp((int)a, (int)a, 0xB1, 0xF, 0xF, true);
  a = t < a ? t : a;
  t = (unsigned)__builtin_amdgcn_update_dpp((int)a, (int)a, 0x4E, 0xF, 0xF, true);
  a = t < a ? t : a;
  t = (unsigned)__builtin_amdgcn_update_dpp((int)a, (int)a, 0x141, 0xF, 0xF, true);
  a = t < a ? t : a;
  t = (unsigned)__builtin_amdgcn_update_dpp((int)a, (int)a, 0x140, 0xF, 0xF, true);
  a = t < a ? t : a;
  t = (unsigned)__builtin_amdgcn_update_dpp((int)a, (int)a, 0x142, 0xA, 0xF, false);
  a = t < a ? t : a;
  t = (unsigned)__builtin_amdgcn_update_dpp((int)a, (int)a, 0x143, 0xC, 0xF, false);
  a = t < a ? t : a;
  return (unsigned)__builtin_amdgcn_readlane((int)a, 63);
}

__device__ __forceinline__ void dpp_min_bcast2(unsigned& a, unsigned& b) {
  unsigned t0, t1;
#define STEP_DPP(ctrl, rm, bc)                                                           \
  t0 = (unsigned)__builtin_amdgcn_update_dpp((int)a, (int)a, ctrl, rm, 0xF, bc);         \
  t1 = (unsigned)__builtin_amdgcn_update_dpp((int)b, (int)b, ctrl, rm, 0xF, bc);         \
  a = t0 < a ? t0 : a; b = t1 < b ? t1 : b;
  STEP_DPP(0xB1, 0xF, true)
  STEP_DPP(0x4E, 0xF, true)
  STEP_DPP(0x141, 0xF, true)
  STEP_DPP(0x140, 0xF, true)
  STEP_DPP(0x142, 0xA, false)
  STEP_DPP(0x143, 0xC, false)
#undef STEP_DPP
  a = (unsigned)__builtin_amdgcn_readlane((int)a, 63);
  b = (unsigned)__builtin_amdgcn_readlane((int)b, 63);
}

// KNN v10 (R15-proven, ~90 µs): u64-key sorted top-3 queues, float4 loads,
// readlane broadcasts. CLOSED lines: u32 pre-filter (R19: +6 µs — exec-mask
// means the insert body issues anyway); split u64 key (R13 fail, root cause
// never fully pinned); dual-queue (R11/R12: scratch spills). Terminal form.
template <int VCAND>
__global__ __launch_bounds__(256, 8) void k_knn8(const float4* __restrict__ pk,
                                                 int* __restrict__ nidx, int V) {
  const int wid = threadIdx.x >> 6;
  const int lane = threadIdx.x & 63;
  const int row0 = blockIdx.x * 8 + wid * 2;
  const int b = row0 / V;
  const int base = b * V;
  const int i0 = row0 % V;

  float xi[2], yi[2], zi[2], sqi[2];
#pragma unroll
  for (int t = 0; t < 2; ++t) {
    float4 q = pk[base + i0 + t];
    xi[t] = q.x; yi[t] = q.y; zi[t] = q.z; sqi[t] = q.w;
  }

  unsigned long long q0[2] = {~0ULL, ~0ULL}, q1[2] = {~0ULL, ~0ULL}, q2[2] = {~0ULL, ~0ULL};
#pragma unroll 4
  for (int c = 0; c < VCAND; ++c) {
    int j = c * 64 + lane;
    float4 cj = pk[base + j];
    float xj = cj.x, yj = cj.y, zj = cj.z, sqj = cj.w;
#pragma unroll
    for (int t = 0; t < 2; ++t) {
      float dot = xi[t] * xj + yi[t] * yj + zi[t] * zj;
      float dd = (sqi[t] + sqj) - 2.0f * dot;
      unsigned long long k = (((unsigned long long)fmap(dd)) << 32) | (unsigned)j;
      if (k < q2[t]) {
        if (k < q1[t]) {
          q2[t] = q1[t];
          if (k < q0[t]) { q1[t] = q0[t]; q0[t] = k; } else { q1[t] = k; }
        } else {
          q2[t] = k;
        }
      }
    }
  }

  for (int r = 0; r < 21; ++r) {
    unsigned h0 = (unsigned)(q0[0] >> 32);
    unsigned h1 = (unsigned)(q0[1] >> 32);
    unsigned m0 = h0, m1 = h1;
    dpp_min_bcast2(m0, m1);
    unsigned long long mk0 = __ballot(h0 == m0);
    unsigned long long mk1 = __ballot(h1 == m1);
    bool win0, win1;
    if (__popcll(mk0) > 1) {  // rare: dist-bit tie across lanes -> index min
      unsigned jj = (h0 == m0) ? (unsigned)q0[0] : 0xFFFFFFFFu;
      unsigned jm = dpp_min_bcast1(jj);
      win0 = (h0 == m0) && ((unsigned)q0[0] == jm);
    } else {
      win0 = (h0 == m0);
    }
    if (__popcll(mk1) > 1) {
      unsigned jj = (h1 == m1) ? (unsigned)q0[1] : 0xFFFFFFFFu;
      unsigned jm = dpp_min_bcast1(jj);
      win1 = (h1 == m1) && ((unsigned)q0[1] == jm);
    } else {
      win1 = (h1 == m1);
    }
    if (win0) {
      if (r > 0) nidx[(size_t)row0 * NEI + (r - 1)] = (int)(unsigned)q0[0];
      unsigned long long bound = q0[0];
      q0[0] = q1[0]; q1[0] = q2[0]; q2[0] = ~0ULL;
      if (q0[0] == ~0ULL) {
        unsigned long long nm = ~0ULL;
        for (int c = 0; c < VCAND; ++c) {
          int j = c * 64 + lane;
          float4 cj = pk[base + j];
          float dot = xi[0] * cj.x + yi[0] * cj.y + zi[0] * cj.z;
          float dd = (sqi[0] + cj.w) - 2.0f * dot;
          unsigned long long k = (((unsigned long long)fmap(dd)) << 32) | (unsigned)j;
          if (k > bound && k < nm) nm = k;
        }
        q0[0] = nm;
      }
    }
    if (win1) {
      if (r > 0) nidx[(size_t)(row0 + 1) * NEI + (r - 1)] = (int)(unsigned)q0[1];
      unsigned long long bound = q0[1];
      q0[1] = q1[1]; q1[1] = q2[1]; q2[1] = ~0ULL;
      if (q0[1] == ~0ULL) {
        unsigned long long nm = ~0ULL;
        for (int c = 0; c < VCAND; ++c) {
          int j = c * 64 + lane;
          float4 cj = pk[base + j];
          float dot = xi[1] * cj.x + yi[1] * cj.y + zi[1] * cj.z;
          float dd = (sqi[1] + cj.w) - 2.0f * dot;
          unsigned long long k = (((unsigned long long)fmap(dd)) << 32) | (unsigned)j;
          if (k > bound && k < nm) nm = k;
        }
        q0[1] = nm;
      }
    }
  }
}

// conv_surface: C=32, E=128. One block (128 thr) per (b,v).
__global__ __launch_bounds__(128) void k_conv_surface(const float* __restrict__ verts,
                                                      const int* __restrict__ nidx,
                                                      const float* __restrict__ sd,
                                                      float* __restrict__ fm, int V) {
  int row = blockIdx.x;
  int b = row / V, v = row % V;
  const float* vb = verts + (size_t)b * V * 3;
  __shared__ float nd[60];
  __shared__ float mcol[128];
  int tid = threadIdx.x;
  if (tid < NEI) {
    int j = nidx[(size_t)row * NEI + tid];
    float dx = vb[3 * j] - vb[3 * v];
    float dy = vb[3 * j + 1] - vb[3 * v + 1];
    float dz = vb[3 * j + 2] - vb[3 * v + 2];
    float nrm = sqrtf(dx * dx + dy * dy + dz * dz);
    float m = fmaxf(nrm, 1e-12f);
    nd[tid * 3] = dx / m; nd[tid * 3 + 1] = dy / m; nd[tid * 3 + 2] = dz / m;
  }
  __syncthreads();
  {
    int e = tid;
    float s0 = sd[e], s1 = sd[128 + e], s2 = sd[256 + e];
    float me = 0.0f;
#pragma unroll
    for (int n = 0; n < NEI; ++n) {
      float th = nd[3 * n] * s0 + nd[3 * n + 1] * s1 + nd[3 * n + 2] * s2;
      th = fmaxf(th, 0.0f);
      me = fmaxf(me, th);
    }
    mcol[e] = me;
  }
  __syncthreads();
  if (tid < 32) {
    float o = mcol[tid] + mcol[32 + tid] + mcol[64 + tid] + mcol[96 + tid];
    o = fmaxf(o, 0.0f);
    fm[(size_t)row * 32 + tid] = o;
  }
}

// fp32 tiled GEMM 64x64x16 (layer1): writes split output — center cols [0,C)
// fp32, support cols [C,N) fp16 (conv gather reads these; fp16 rel err 2^-12
// is below the harness's bf16 output quantum).
__global__ __launch_bounds__(256) void k_gemm_bias(const float* __restrict__ A,
                                                   const float* __restrict__ W,
                                                   const float* __restrict__ bias,
                                                   float* __restrict__ fc,
                                                   _Float16* __restrict__ fs,
                                                   int M, int N, int K, int Cc) {
  __shared__ float As[16][68];
  __shared__ float Bs[16][68];
  int n0 = blockIdx.x * 64, m0 = blockIdx.y * 64;
  int tx = threadIdx.x & 15, ty = threadIdx.x >> 4;
  float acc[4][4] = {};
  for (int k0 = 0; k0 < K; k0 += 16) {
    for (int t = threadIdx.x; t < 1024; t += 256) {
      int mm = t >> 4, kk = t & 15;
      int m = m0 + mm;
      As[kk][mm] = (m < M) ? A[(size_t)m * K + (k0 + kk)] : 0.0f;
    }
    for (int t = threadIdx.x; t < 1024; t += 256) {
      int kk = t >> 6, nn = t & 63;
      int n = n0 + nn;
      Bs[kk][nn] = (n < N) ? san(W[(size_t)(k0 + kk) * N + n]) : 0.0f;
    }
    __syncthreads();
#pragma unroll
    for (int kk = 0; kk < 16; ++kk) {
      float4 av = *(const float4*)&As[kk][ty << 2];
      float4 bv = *(const float4*)&Bs[kk][tx << 2];
      float a[4] = {av.x, av.y, av.z, av.w};
      float bb[4] = {bv.x, bv.y, bv.z, bv.w};
#pragma unroll
      for (int i = 0; i < 4; ++i)
#pragma unroll
        for (int j = 0; j < 4; ++j) acc[i][j] += a[i] * bb[j];
    }
    __syncthreads();
  }
  int SW = N - Cc;
  for (int i = 0; i < 4; ++i)
    for (int j = 0; j < 4; ++j) {
      int m = m0 + (ty << 2) + i, n = n0 + (tx << 2) + j;
      if (m < M && n < N) {
        float val = acc[i][j] + san(bias[n]);
        if (n < Cc) fc[(size_t)m * Cc + n] = val;
        else fs[(size_t)m * SW + (n - Cc)] = (_Float16)val;
      }
    }
}

// ===================== split-bf16 MFMA GEMM path =====================
typedef __attribute__((ext_vector_type(8))) short v8h;
typedef __attribute__((ext_vector_type(4))) float v4f;

// RNE fp32 -> bf16 bit pattern (inputs finite: san'd or internally produced)
__device__ __forceinline__ unsigned short f2bf(float f) {
  unsigned u = __float_as_uint(f);
  u = u + 0x7FFFu + ((u >> 16) & 1u);
  return (unsigned short)(u >> 16);
}
__device__ __forceinline__ float bf2f(unsigned short h) {
  return __uint_as_float((unsigned)h << 16);
}

// elementwise split fp32 -> (hi, lo) bf16 bits; n % 256 == 0 at call sites
__global__ __launch_bounds__(256) void k_split(const float* __restrict__ in,
                                               unsigned short* __restrict__ hi,
                                               unsigned short* __restrict__ lo, int n) {
  int i = blockIdx.x * 256 + threadIdx.x;
  if (i >= n) return;
  float a = in[i];
  unsigned short h = f2bf(a);
  hi[i] = h;
  lo[i] = f2bf(a - bf2f(h));
}

// transpose + split: W [K][N] fp32 (san applied) -> WhT, WlT [N][K] bf16 bits.
__global__ __launch_bounds__(256) void k_split_wT(const float* __restrict__ W,
                                                  unsigned short* __restrict__ hiT,
                                                  unsigned short* __restrict__ loT,
                                                  int K, int N) {
  __shared__ float tile[32][33];
  int k0 = blockIdx.y * 32, n0 = blockIdx.x * 32;
  int tx = threadIdx.x & 31, ty4 = threadIdx.x >> 5;
#pragma unroll
  for (int j = 0; j < 4; ++j)
    tile[ty4 * 4 + j][tx] = san(W[(size_t)(k0 + ty4 * 4 + j) * N + n0 + tx]);
  __syncthreads();
#pragma unroll
  for (int j = 0; j < 4; ++j) {
    int n = n0 + ty4 * 4 + j;
    float a = tile[tx][ty4 * 4 + j];
    unsigned short h = f2bf(a);
    hiT[(size_t)n * K + k0 + tx] = h;
    loT[(size_t)n * K + k0 + tx] = f2bf(a - bf2f(h));
  }
}

// C = A*W + bias via 3-term split-bf16 MFMA (R20-proven, absmax 9.77e-4).
// Output split: center cols [0,Cc) -> fc fp32 [M][Cc]; support cols [Cc,N)
// -> fs fp16 [M][N-Cc]. Cc % 128 == 0 at call sites -> whole 128-col block
// is one side (block-uniform branch, no per-element cost).
__global__ __launch_bounds__(256) void k_gemm128_mfma(
    const unsigned short* __restrict__ Ah, const unsigned short* __restrict__ Al,
    const unsigned short* __restrict__ BhT, const unsigned short* __restrict__ BlT,
    const float* __restrict__ bias, float* __restrict__ fc, _Float16* __restrict__ fs,
    int M, int N, int K, int Cc) {
  __shared__ __attribute__((aligned(16))) unsigned short sAh[128 * 40];
  __shared__ __attribute__((aligned(16))) unsigned short sAl[128 * 40];
  __shared__ __attribute__((aligned(16))) unsigned short sBh[128 * 40];
  __shared__ __attribute__((aligned(16))) unsigned short sBl[128 * 40];
  const int n0 = blockIdx.x * 128, m0 = blockIdx.y * 128;
  const int l = threadIdx.x & 63;
  const int w = threadIdx.x >> 6;
  const int wr = (w >> 1) * 64, wc = (w & 1) * 64;
  const int lr = l & 15;
  const int kb8 = (l >> 4) * 8;

  v4f acc[4][4];
#pragma unroll
  for (int i = 0; i < 4; ++i)
#pragma unroll
    for (int j = 0; j < 4; ++j) acc[i][j] = (v4f){0.f, 0.f, 0.f, 0.f};

  for (int k0 = 0; k0 < K; k0 += 32) {
#pragma unroll
    for (int q = 0; q < 2; ++q) {
      int lin = (int)threadIdx.x + (q << 8);
      int r = lin >> 2, kc = (lin & 3) << 3;
      *(uint4*)&sAh[r * 40 + kc] = *(const uint4*)&Ah[(size_t)(m0 + r) * K + k0 + kc];
      *(uint4*)&sAl[r * 40 + kc] = *(const uint4*)&Al[(size_t)(m0 + r) * K + k0 + kc];
      *(uint4*)&sBh[r * 40 + kc] = *(const uint4*)&BhT[(size_t)(n0 + r) * K + k0 + kc];
      *(uint4*)&sBl[r * 40 + kc] = *(const uint4*)&BlT[(size_t)(n0 + r) * K + k0 + kc];
    }
    __syncthreads();
    v8h fah[4], fal[4], fbh[4], fbl[4];
#pragma unroll
    for (int t = 0; t < 4; ++t) {
      fah[t] = *(const v8h*)&sAh[(wr + t * 16 + lr) * 40 + kb8];
      fal[t] = *(const v8h*)&sAl[(wr + t * 16 + lr) * 40 + kb8];
      fbh[t] = *(const v8h*)&sBh[(wc + t * 16 + lr) * 40 + kb8];
      fbl[t] = *(const v8h*)&sBl[(wc + t * 16 + lr) * 40 + kb8];
    }
#pragma unroll
    for (int i = 0; i < 4; ++i)
#pragma unroll
      for (int j = 0; j < 4; ++j) {
        acc[i][j] = __builtin_amdgcn_mfma_f32_16x16x32_bf16(fah[i], fbh[j], acc[i][j], 0, 0, 0);
        acc[i][j] = __builtin_amdgcn_mfma_f32_16x16x32_bf16(fah[i], fbl[j], acc[i][j], 0, 0, 0);
        acc[i][j] = __builtin_amdgcn_mfma_f32_16x16x32_bf16(fal[i], fbh[j], acc[i][j], 0, 0, 0);
      }
    __syncthreads();
  }
  float bs[4];
#pragma unroll
  for (int j = 0; j < 4; ++j) bs[j] = san(bias[n0 + wc + j * 16 + lr]);
  const int rowb = m0 + wr + (l >> 4) * 4;
  if (n0 + 128 <= Cc) {  // whole block in center region (fp32)
#pragma unroll
    for (int i = 0; i < 4; ++i)
#pragma unroll
      for (int j = 0; j < 4; ++j) {
        int col = n0 + wc + j * 16 + lr;
#pragma unroll
        for (int v = 0; v < 4; ++v)
          fc[(size_t)(rowb + i * 16 + v) * Cc + col] = acc[i][j][v] + bs[j];
      }
  } else {               // whole block in support region (fp16)
    int SW = N - Cc;
#pragma unroll
    for (int i = 0; i < 4; ++i)
#pragma unroll
      for (int j = 0; j < 4; ++j) {
        int col = n0 + wc + j * 16 + lr - Cc;
#pragma unroll
        for (int v = 0; v < 4; ++v)
          fs[(size_t)(rowb + i * 16 + v) * SW + col] = (_Float16)(acc[i][j][v] + bs[j]);
      }
  }
}

// conv layer (scalar gather, R15-proven structure): center from fc fp32,
// support gathered from fs fp16 (half the gather bytes — the conv layers are
// cache-BW-bound; float4-widening closed in R16/R17, bytes are the lever).
__global__ __launch_bounds__(256) void k_conv_layer(const float* __restrict__ fc,
                                                    const _Float16* __restrict__ fs,
                                                    const float* __restrict__ verts,
                                                    const int* __restrict__ nidx,
                                                    const float* __restrict__ sd,
                                                    float* __restrict__ outf,
                                                    int V, int C, int relu_out) {
  int row = blockIdx.x;
  int b = row / V, v = row % V;
  int E = 4 * C;
  extern __shared__ float sm[];
  float* mcol = sm;
  float* nd = sm + E;
  int* jr = (int*)(nd + 60);
  int tid = threadIdx.x;
  const float* vb = verts + (size_t)b * V * 3;
  if (tid < NEI) {
    int j = nidx[(size_t)row * NEI + tid];
    jr[tid] = j;
    float dx = vb[3 * j] - vb[3 * v];
    float dy = vb[3 * j + 1] - vb[3 * v + 1];
    float dz = vb[3 * j + 2] - vb[3 * v + 2];
    float nrm = sqrtf(dx * dx + dy * dy + dz * dz);
    float m = fmaxf(nrm, 1e-12f);
    nd[tid * 3] = dx / m; nd[tid * 3 + 1] = dy / m; nd[tid * 3 + 2] = dz / m;
  }
  __syncthreads();
  size_t fb = (size_t)b * V;
  for (int e = tid; e < E; e += blockDim.x) {
    float s0 = sd[e], s1 = sd[E + e], s2 = sd[2 * E + e];
    float me = -INFINITY;
#pragma unroll
    for (int n = 0; n < NEI; ++n) {
      float th = nd[3 * n] * s0 + nd[3 * n + 1] * s1 + nd[3 * n + 2] * s2;
      th = fmaxf(th, 0.0f);
      float fv = (float)fs[(fb + jr[n]) * (size_t)E + e];
      me = fmaxf(me, th * fv);
    }
    mcol[e] = me;
  }
  __syncthreads();
  for (int c = tid; c < C; c += blockDim.x) {
    float o = fc[(size_t)row * C + c] + mcol[c] + mcol[C + c] + mcol[2 * C + c] + mcol[3 * C + c];
    if (relu_out) o = fmaxf(o, 0.0f);
    outf[(size_t)row * C + c] = o;
  }
}

// 1024-thread clone for the layer-4 conv (same work assignment -> same values)
__global__ __launch_bounds__(1024) void k_conv_layer_big(const float* __restrict__ fc,
                                                         const _Float16* __restrict__ fs,
                                                         const float* __restrict__ verts,
                                                         const int* __restrict__ nidx,
                                                         const float* __restrict__ sd,
                                                         float* __restrict__ outf,
                                                         int V, int C, int relu_out) {
  int row = blockIdx.x;
  int b = row / V, v = row % V;
  int E = 4 * C;
  extern __shared__ float sm[];
  float* mcol = sm;
  float* nd = sm + E;
  int* jr = (int*)(nd + 60);
  int tid = threadIdx.x;
  const float* vb = verts + (size_t)b * V * 3;
  if (tid < NEI) {
    int j = nidx[(size_t)row * NEI + tid];
    jr[tid] = j;
    float dx = vb[3 * j] - vb[3 * v];
    float dy = vb[3 * j + 1] - vb[3 * v + 1];
    float dz = vb[3 * j + 2] - vb[3 * v + 2];
    float nrm = sqrtf(dx * dx + dy * dy + dz * dz);
    float m = fmaxf(nrm, 1e-12f);
    nd[tid * 3] = dx / m; nd[tid * 3 + 1] = dy / m; nd[tid * 3 + 2] = dz / m;
  }
  __syncthreads();
  size_t fb = (size_t)b * V;
  for (int e = tid; e < E; e += blockDim.x) {
    float s0 = sd[e], s1 = sd[E + e], s2 = sd[2 * E + e];
    float me = -INFINITY;
#pragma unroll
    for (int n = 0; n < NEI; ++n) {
      float th = nd[3 * n] * s0 + nd[3 * n + 1] * s1 + nd[3 * n + 2] * s2;
      th = fmaxf(th, 0.0f);
      float fv = (float)fs[(fb + jr[n]) * (size_t)E + e];
      me = fmaxf(me, th * fv);
    }
    mcol[e] = me;
  }
  __syncthreads();
  for (int c = tid; c < C; c += blockDim.x) {
    float o = fc[(size_t)row * C + c] + mcol[c] + mcol[C + c] + mcol[2 * C + c] + mcol[3 * C + c];
    if (relu_out) o = fmaxf(o, 0.0f);
    outf[(size_t)row * C + c] = o;
  }
}

// transpose (B, V, C) -> (B, C, V), 32x32 LDS tiles, coalesced both sides
__global__ __launch_bounds__(256) void k_transpose_vc(const float* __restrict__ in,
                                                      float* __restrict__ out,
                                                      int V, int C) {
  __shared__ float tile[32][33];
  int b = blockIdx.z;
  int c0 = blockIdx.x * 32, v0 = blockIdx.y * 32;
  int tx = threadIdx.x & 31, ty4 = threadIdx.x >> 5;
#pragma unroll
  for (int j = 0; j < 4; ++j) {
    int v = v0 + ty4 * 4 + j;
    tile[ty4 * 4 + j][tx] = in[((size_t)b * V + v) * C + c0 + tx];
  }
  __syncthreads();
#pragma unroll
  for (int j = 0; j < 4; ++j) {
    int c = c0 + ty4 * 4 + j;
    out[((size_t)b * C + c) * V + v0 + tx] = tile[tx][ty4 * 4 + j];
  }
}

// fused pool (max over neighbors at selected rows) + pooled-vertex gather
__global__ void k_pool_sel(const float* __restrict__ fm, const int* __restrict__ nidx,
                           const int* __restrict__ sel, float* __restrict__ outp,
                           const float* __restrict__ vinA, float* __restrict__ voutA,
                           float4* __restrict__ pkout,
                           int Vin, int Vout, int C) {
  int t = blockIdx.x * blockDim.x + threadIdx.x;
  if (t < 4 * Vout) {
    int p = t % Vout;
    int b = t / Vout;
    int src = b * Vin + sel[p];
    float x = vinA[3 * src], y = vinA[3 * src + 1], z = vinA[3 * src + 2];
    int dst = b * Vout + p;
    voutA[3 * dst] = x; voutA[3 * dst + 1] = y; voutA[3 * dst + 2] = z;
    pkout[dst] = make_float4(x, y, z, x * x + y * y + z * z);
  }
  int total = 4 * Vout * C;
  if (t >= total) return;
  int c = t % C;
  int p = (t / C) % Vout;
  int b = t / (C * Vout);
  int sv = sel[p];
  const int* ir = nidx + ((size_t)b * Vin + sv) * NEI;
  float m = -INFINITY;
#pragma unroll
  for (int n = 0; n < NEI; ++n)
    m = fmaxf(m, fm[((size_t)b * Vin + ir[n]) * C + c]);
  outp[((size_t)b * Vout + p) * C + c] = m;
}

// ===================== launch =====================
extern "C" void kernel_launch(void* const* d_in, const int* in_sizes, int n_in,
                              void* d_out, int out_size, void* d_ws, size_t ws_size,
                              hipStream_t stream) {
  (void)in_sizes; (void)n_in; (void)out_size; (void)ws_size;
  const int B = 4, V1 = 4096, V2 = 1024, V3 = 256;

  const float* vin   = (const float*)d_in[0];
  const float* dirs0 = (const float*)d_in[1];
  const float* W1 = (const float*)d_in[2];
  const float* b1 = (const float*)d_in[3];
  const float* D1 = (const float*)d_in[4];
  const float* W2 = (const float*)d_in[5];
  const float* b2 = (const float*)d_in[6];
  const float* D2 = (const float*)d_in[7];
  const float* W3 = (const float*)d_in[8];
  const float* b3 = (const float*)d_in[9];
  const float* D3 = (const float*)d_in[10];
  const float* W4 = (const float*)d_in[11];
  const float* b4 = (const float*)d_in[12];
  const float* D4 = (const float*)d_in[13];
  float* out = (float*)d_out;

  char* ws = (char*)d_ws;
  size_t off = 0;
  auto alloc = [&](size_t bytes) -> char* {
    char* p = ws + off;
    off = (off + bytes + 255) & ~(size_t)255;
    return p;
  };
  int* sel1 = (int*)alloc((size_t)V2 * 4);
  int* sel2 = (int*)alloc((size_t)V3 * 4);
  float* verts1 = (float*)alloc((size_t)B * V1 * 3 * 4);
  float* verts2 = (float*)alloc((size_t)B * V2 * 3 * 4);
  float* verts3 = (float*)alloc((size_t)B * V3 * 3 * 4);
  float4* pk1 = (float4*)alloc((size_t)B * V1 * 16);
  float4* pk2 = (float4*)alloc((size_t)B * V2 * 16);
  float4* pk3 = (float4*)alloc((size_t)B * V3 * 16);
  int* idx1 = (int*)alloc((size_t)B * V1 * NEI * 4);
  int* idx2 = (int*)alloc((size_t)B * V2 * NEI * 4);
  int* idx3 = (int*)alloc((size_t)B * V3 * NEI * 4);
  float* sd0 = (float*)alloc(3 * 128 * 4);
  float* sd1 = (float*)alloc(3 * 256 * 4);
  float* sd2 = (float*)alloc(3 * 512 * 4);
  float* sd3 = (float*)alloc(3 * 1024 * 4);
  float* sd4 = (float*)alloc(3 * 4096 * 4);
  float* bufA = (float*)alloc((size_t)B * V1 * 32 * 4);
  float* bufB = (float*)alloc((size_t)B * V1 * 64 * 4);
  float* bufC = (float*)alloc((size_t)B * V2 * 64 * 4);
  // split GEMM output: center fp32 (max 4 MB) + support fp16 (max 8 MB)
  float* fcb = (float*)alloc((size_t)B * V1 * 64 * 4);        // >= all center sizes
  _Float16* fsb = (_Float16*)alloc((size_t)B * V1 * 256 * 2); // >= all support sizes
  // split-bf16 buffers (MFMA GEMM path)
  unsigned short* w2hT = (unsigned short*)alloc((size_t)640 * 64 * 2);
  unsigned short* w2lT = (unsigned short*)alloc((size_t)640 * 64 * 2);
  unsigned short* w3hT = (unsigned short*)alloc((size_t)1280 * 128 * 2);
  unsigned short* w3lT = (unsigned short*)alloc((size_t)1280 * 128 * 2);
  unsigned short* w4hT = (unsigned short*)alloc((size_t)5120 * 256 * 2);
  unsigned short* w4lT = (unsigned short*)alloc((size_t)5120 * 256 * 2);
  unsigned short* aSh = (unsigned short*)alloc((size_t)4096 * 128 * 2);
  unsigned short* aSl = (unsigned short*)alloc((size_t)4096 * 128 * 2);
  float* fm0 = bufA, *fm2 = bufA;
  float* fm1 = bufB, *fm3 = bufB;
  float* fm1p = bufC, *fm3p = bufC;
  float* conv4out = bufB;

  static int perm1[4096];
  static int perm2[1024];
  static int selh[1280];
  jax_permutation(42u, 4096, 2, perm1);
  jax_permutation(43u, 1024, 1, perm2);
  memcpy(selh, perm1, 1024 * sizeof(int));
  memcpy(selh + 1024, perm2, 256 * sizeof(int));
  hipMemcpyAsync(sel1, selh, 1024 * sizeof(int), hipMemcpyHostToDevice, stream);
  hipMemcpyAsync(sel2, selh + 1024, 256 * sizeof(int), hipMemcpyHostToDevice, stream);

  // fused sanitize + dirs normalize
  k_setup<<<88, 256, 0, stream>>>(vin, verts1, pk1, B * V1,
                                  dirs0, D1, D2, D3, D4, sd0, sd1, sd2, sd3, sd4);
  // weight transpose+split pre-passes (independent of data flow)
  k_split_wT<<<dim3(640 / 32, 64 / 32), 256, 0, stream>>>(W2, w2hT, w2lT, 64, 640);
  k_split_wT<<<dim3(1280 / 32, 128 / 32), 256, 0, stream>>>(W3, w3hT, w3lT, 128, 1280);
  k_split_wT<<<dim3(5120 / 32, 256 / 32), 256, 0, stream>>>(W4, w4hT, w4lT, 256, 5120);
  // knn level 1 (VCAND = 64), 2 queries/wave, 8 queries/block
  k_knn8<64><<<B * V1 / 8, 256, 0, stream>>>(pk1, idx1, V1);
  k_conv_surface<<<B * V1, 128, 0, stream>>>(verts1, idx1, sd0, fm0, V1);
  // layer1 (N=320 -> fp32 64-tile GEMM, split center/support output)
  k_gemm_bias<<<dim3(5, 256), 256, 0, stream>>>(fm0, W1, b1, fcb, fsb, B * V1, 320, 32, 64);
  k_conv_layer<<<B * V1, 256, (4 * 64 + 80) * 4, stream>>>(fcb, fsb, verts1, idx1, sd1, fm1, V1, 64, 1);
  // pool1 (fused pool + vertex gather)
  {
    int total = B * V2 * 64;
    k_pool_sel<<<(total + 255) / 256, 256, 0, stream>>>(fm1, idx1, sel1, fm1p,
                                                        verts1, verts2, pk2,
                                                        V1, V2, 64);
  }
  // knn level 2 (VCAND = 16)
  k_knn8<16><<<B * V2 / 8, 256, 0, stream>>>(pk2, idx2, V2);
  // layer2: 4096x640x64 via split-bf16 MFMA
  k_split<<<(B * V2 * 64) / 256, 256, 0, stream>>>(fm1p, aSh, aSl, B * V2 * 64);
  k_gemm128_mfma<<<dim3(640 / 128, 4096 / 128), 256, 0, stream>>>(aSh, aSl, w2hT, w2lT, b2, fcb, fsb, B * V2, 640, 64, 128);
  k_conv_layer<<<B * V2, 256, (4 * 128 + 80) * 4, stream>>>(fcb, fsb, verts2, idx2, sd2, fm2, V2, 128, 1);
  // layer3: 4096x1280x128 via split-bf16 MFMA
  k_split<<<(B * V2 * 128) / 256, 256, 0, stream>>>(fm2, aSh, aSl, B * V2 * 128);
  k_gemm128_mfma<<<dim3(1280 / 128, 4096 / 128), 256, 0, stream>>>(aSh, aSl, w3hT, w3lT, b3, fcb, fsb, B * V2, 1280, 128, 256);
  k_conv_layer<<<B * V2, 256, (4 * 256 + 80) * 4, stream>>>(fcb, fsb, verts2, idx2, sd3, fm3, V2, 256, 1);
  // pool2 (fused)
  {
    int total = B * V3 * 256;
    k_pool_sel<<<(total + 255) / 256, 256, 0, stream>>>(fm3, idx2, sel2, fm3p,
                                                        verts2, verts3, pk3,
                                                        V2, V3, 256);
  }
  // knn level 3 (VCAND = 4)
  k_knn8<4><<<B * V3 / 8, 256, 0, stream>>>(pk3, idx3, V3);
  // layer4: 1024x5120x256 via split-bf16 MFMA, conv C=1024, transpose
  k_split<<<(B * V3 * 256) / 256, 256, 0, stream>>>(fm3p, aSh, aSl, B * V3 * 256);
  k_gemm128_mfma<<<dim3(5120 / 128, 1024 / 128), 256, 0, stream>>>(aSh, aSl, w4hT, w4lT, b4, fcb, fsb, B * V3, 5120, 256, 1024);
  k_conv_layer_big<<<B * V3, 1024, (4 * 1024 + 80) * 4, stream>>>(fcb, fsb, verts3, idx3, sd4, conv4out, V3, 1024, 0);
  k_transpose_vc<<<dim3(1024 / 32, 256 / 32, B), 256, 0, stream>>>(conv4out, out, V3, 1024);
}

// Round 10
// 388.754 us; speedup vs baseline: 1.1919x; 1.0267x over previous
//
#include <hip/hip_runtime.h>
#include <vector>
#include <algorithm>
#include <cstdint>
#include <cstring>
#include <cmath>

// ===================== host-side JAX threefry replication =====================
static inline uint32_t tf_rotl(uint32_t x, int r) { return (x << r) | (x >> (32 - r)); }

static void tf2x32(uint32_t k0, uint32_t k1, uint32_t x0, uint32_t x1,
                   uint32_t* o0, uint32_t* o1) {
  uint32_t ks2 = k0 ^ k1 ^ 0x1BD11BDAu;
  uint32_t v0 = x0 + k0, v1 = x1 + k1;
  static const int R0[4] = {13, 15, 26, 6}, R1[4] = {17, 29, 16, 24};
#define RND4(R) do { for (int i_ = 0; i_ < 4; ++i_) { v0 += v1; v1 = tf_rotl(v1, R[i_]); v1 ^= v0; } } while (0)
  RND4(R0); v0 += k1;  v1 += ks2 + 1u;
  RND4(R1); v0 += ks2; v1 += k0 + 2u;
  RND4(R0); v0 += k0;  v1 += k1 + 3u;
  RND4(R1); v0 += k1;  v1 += ks2 + 4u;
  RND4(R0); v0 += ks2; v1 += k0 + 5u;
#undef RND4
  *o0 = v0; *o1 = v1;
}

static void jax_permutation(uint32_t seed, int n, int rounds, int* x) {
  uint32_t k0 = 0u, k1 = seed;
  for (int i = 0; i < n; ++i) x[i] = i;
  std::vector<uint32_t> bits(n);
  std::vector<int> ord(n), xn(n);
  for (int r = 0; r < rounds; ++r) {
    uint32_t nk0, nk1, sk0, sk1;
    tf2x32(k0, k1, 0u, 0u, &nk0, &nk1);
    tf2x32(k0, k1, 0u, 1u, &sk0, &sk1);
    for (int i = 0; i < n; ++i) {
      uint32_t h, l;
      tf2x32(sk0, sk1, 0u, (uint32_t)i, &h, &l);
      bits[i] = h ^ l;
    }
    for (int i = 0; i < n; ++i) ord[i] = i;
    std::stable_sort(ord.begin(), ord.end(),
                     [&](int a, int b) { return bits[a] < bits[b]; });
    for (int i = 0; i < n; ++i) xn[i] = x[ord[i]];
    memcpy(x, xn.data(), (size_t)n * sizeof(int));
    k0 = nk0; k1 = nk1;
  }
}

// ===================== device kernels =====================
#define NEI 20

__device__ __forceinline__ float san(float v) {
  v = (v != v) ? 0.0f : v;
  return fmaxf(-1e4f, fminf(v, 1e4f));
}

// fused setup: blocks 0..63 sanitize vertices -> AoS + packed float4{x,y,z,sq};
// blocks 64..87 normalize the 5 direction matrices.
__global__ void k_setup(const float* __restrict__ vin, float* __restrict__ outA,
                        float4* __restrict__ pk, int nverts,
                        const float* __restrict__ d0, const float* __restrict__ d1,
                        const float* __restrict__ d2, const float* __restrict__ d3,
                        const float* __restrict__ d4,
                        float* __restrict__ s0, float* __restrict__ s1,
                        float* __restrict__ s2, float* __restrict__ s3,
                        float* __restrict__ s4) {
  int blk = blockIdx.x;
  if (blk < 64) {
    int i = blk * 256 + threadIdx.x;
    if (i >= nverts) return;
    float x = san(vin[3 * i]), y = san(vin[3 * i + 1]), z = san(vin[3 * i + 2]);
    outA[3 * i] = x; outA[3 * i + 1] = y; outA[3 * i + 2] = z;
    pk[i] = make_float4(x, y, z, x * x + y * y + z * z);
    return;
  }
  int t = (blk - 64) * 256 + threadIdx.x;
  const float* d; float* s; int E, e;
  if (t < 128)       { d = d0; s = s0; E = 128;  e = t; }
  else if (t < 384)  { d = d1; s = s1; E = 256;  e = t - 128; }
  else if (t < 896)  { d = d2; s = s2; E = 512;  e = t - 384; }
  else if (t < 1920) { d = d3; s = s3; E = 1024; e = t - 896; }
  else if (t < 6016) { d = d4; s = s4; E = 4096; e = t - 1920; }
  else return;
  float a = san(d[e]);
  float b = san(d[E + e]);
  float c = san(d[2 * E + e]);
  float nrm = sqrtf(a * a + b * b + c * c);
  float m = fmaxf(nrm, 1e-12f);
  s[e] = a / m; s[E + e] = b / m; s[2 * E + e] = c / m;
}

// total-order map for fp32 bits: monotone u32 for any float (handles negatives)
__device__ __forceinline__ unsigned fmap(float f) {
  unsigned u = __float_as_uint(f);
  return u ^ ((u & 0x80000000u) ? 0xFFFFFFFFu : 0x80000000u);
}

// --- 64-lane u32 min, broadcast via readlane (SGPR, no LDS round-trip) ---
__device__ __forceinline__ unsigned dpp_min_bcast1(unsigned a) {
  unsigned t;
  t = (unsigned)__builtin_amdgcn_update_dpp((int)a, (int)a, 0xB1, 0xF, 0xF, true);
  a = t < a ? t : a;
  t = (unsigned)__builtin_amdgcn_update_dpp((int)a, (int)a, 0x4E, 0xF, 0xF, true);
  a = t < a ? t : a;
  t = (unsigned)__builtin_amdgcn_update_dpp((int)a, (int)a, 0x141, 0xF, 0xF, true);
  a = t < a ? t : a;
  t = (unsigned)__builtin_amdgcn_update_dpp((int)a, (int)a, 0x140, 0xF, 0xF, true);
  a = t < a ? t : a;
  t = (unsigned)__builtin_amdgcn_update_dpp((int)a, (int)a, 0x142, 0xA, 0xF, false);
  a = t < a ? t : a;
  t = (unsigned)__builtin_amdgcn_update_dpp((int)a, (int)a, 0x143, 0xC, 0xF, false);
  a = t < a ? t : a;
  return (unsigned)__builtin_amdgcn_readlane((int)a, 63);
}

__device__ __forceinline__ void dpp_min_bcast2(unsigned& a, unsigned& b) {
  unsigned t0, t1;
#define STEP_DPP(ctrl, rm, bc)                                                           \
  t0 = (unsigned)__builtin_amdgcn_update_dpp((int)a, (int)a, ctrl, rm, 0xF, bc);         \
  t1 = (unsigned)__builtin_amdgcn_update_dpp((int)b, (int)b, ctrl, rm, 0xF, bc);         \
  a = t0 < a ? t0 : a; b = t1 < b ? t1 : b;
  STEP_DPP(0xB1, 0xF, true)
  STEP_DPP(0x4E, 0xF, true)
  STEP_DPP(0x141, 0xF, true)
  STEP_DPP(0x140, 0xF, true)
  STEP_DPP(0x142, 0xA, false)
  STEP_DPP(0x143, 0xC, false)
#undef STEP_DPP
  a = (unsigned)__builtin_amdgcn_readlane((int)a, 63);
  b = (unsigned)__builtin_amdgcn_readlane((int)b, 63);
}

// KNN v10 (R15-proven, ~90 µs): u64-key sorted top-3 queues, float4 loads,
// readlane broadcasts. CLOSED lines: u32 pre-filter (R19: +6 µs — exec-mask
// means the insert body issues anyway); split u64 key (R13 bug); dual-queue
// (R11/R12: scratch spills). Terminal form of this algorithm.
template <int VCAND>
__global__ __launch_bounds__(256, 8) void k_knn8(const float4* __restrict__ pk,
                                                 int* __restrict__ nidx, int V) {
  const int wid = threadIdx.x >> 6;
  const int lane = threadIdx.x & 63;
  const int row0 = blockIdx.x * 8 + wid * 2;
  const int b = row0 / V;
  const int base = b * V;
  const int i0 = row0 % V;

  float xi[2], yi[2], zi[2], sqi[2];
#pragma unroll
  for (int t = 0; t < 2; ++t) {
    float4 q = pk[base + i0 + t];
    xi[t] = q.x; yi[t] = q.y; zi[t] = q.z; sqi[t] = q.w;
  }

  unsigned long long q0[2] = {~0ULL, ~0ULL}, q1[2] = {~0ULL, ~0ULL}, q2[2] = {~0ULL, ~0ULL};
#pragma unroll 4
  for (int c = 0; c < VCAND; ++c) {
    int j = c * 64 + lane;
    float4 cj = pk[base + j];
    float xj = cj.x, yj = cj.y, zj = cj.z, sqj = cj.w;
#pragma unroll
    for (int t = 0; t < 2; ++t) {
      float dot = xi[t] * xj + yi[t] * yj + zi[t] * zj;
      float dd = (sqi[t] + sqj) - 2.0f * dot;
      unsigned long long k = (((unsigned long long)fmap(dd)) << 32) | (unsigned)j;
      if (k < q2[t]) {
        if (k < q1[t]) {
          q2[t] = q1[t];
          if (k < q0[t]) { q1[t] = q0[t]; q0[t] = k; } else { q1[t] = k; }
        } else {
          q2[t] = k;
        }
      }
    }
  }

  for (int r = 0; r < 21; ++r) {
    unsigned h0 = (unsigned)(q0[0] >> 32);
    unsigned h1 = (unsigned)(q0[1] >> 32);
    unsigned m0 = h0, m1 = h1;
    dpp_min_bcast2(m0, m1);
    unsigned long long mk0 = __ballot(h0 == m0);
    unsigned long long mk1 = __ballot(h1 == m1);
    bool win0, win1;
    if (__popcll(mk0) > 1) {  // rare: dist-bit tie across lanes -> index min
      unsigned jj = (h0 == m0) ? (unsigned)q0[0] : 0xFFFFFFFFu;
      unsigned jm = dpp_min_bcast1(jj);
      win0 = (h0 == m0) && ((unsigned)q0[0] == jm);
    } else {
      win0 = (h0 == m0);
    }
    if (__popcll(mk1) > 1) {
      unsigned jj = (h1 == m1) ? (unsigned)q0[1] : 0xFFFFFFFFu;
      unsigned jm = dpp_min_bcast1(jj);
      win1 = (h1 == m1) && ((unsigned)q0[1] == jm);
    } else {
      win1 = (h1 == m1);
    }
    if (win0) {
      if (r > 0) nidx[(size_t)row0 * NEI + (r - 1)] = (int)(unsigned)q0[0];
      unsigned long long bound = q0[0];
      q0[0] = q1[0]; q1[0] = q2[0]; q2[0] = ~0ULL;
      if (q0[0] == ~0ULL) {
        unsigned long long nm = ~0ULL;
        for (int c = 0; c < VCAND; ++c) {
          int j = c * 64 + lane;
          float4 cj = pk[base + j];
          float dot = xi[0] * cj.x + yi[0] * cj.y + zi[0] * cj.z;
          float dd = (sqi[0] + cj.w) - 2.0f * dot;
          unsigned long long k = (((unsigned long long)fmap(dd)) << 32) | (unsigned)j;
          if (k > bound && k < nm) nm = k;
        }
        q0[0] = nm;
      }
    }
    if (win1) {
      if (r > 0) nidx[(size_t)(row0 + 1) * NEI + (r - 1)] = (int)(unsigned)q0[1];
      unsigned long long bound = q0[1];
      q0[1] = q1[1]; q1[1] = q2[1]; q2[1] = ~0ULL;
      if (q0[1] == ~0ULL) {
        unsigned long long nm = ~0ULL;
        for (int c = 0; c < VCAND; ++c) {
          int j = c * 64 + lane;
          float4 cj = pk[base + j];
          float dot = xi[1] * cj.x + yi[1] * cj.y + zi[1] * cj.z;
          float dd = (sqi[1] + cj.w) - 2.0f * dot;
          unsigned long long k = (((unsigned long long)fmap(dd)) << 32) | (unsigned)j;
          if (k > bound && k < nm) nm = k;
        }
        q0[1] = nm;
      }
    }
  }
}

// conv_surface: C=32, E=128. One block (128 thr) per (b,v).
__global__ __launch_bounds__(128) void k_conv_surface(const float* __restrict__ verts,
                                                      const int* __restrict__ nidx,
                                                      const float* __restrict__ sd,
                                                      float* __restrict__ fm, int V) {
  int row = blockIdx.x;
  int b = row / V, v = row % V;
  const float* vb = verts + (size_t)b * V * 3;
  __shared__ float nd[60];
  __shared__ float mcol[128];
  int tid = threadIdx.x;
  if (tid < NEI) {
    int j = nidx[(size_t)row * NEI + tid];
    float dx = vb[3 * j] - vb[3 * v];
    float dy = vb[3 * j + 1] - vb[3 * v + 1];
    float dz = vb[3 * j + 2] - vb[3 * v + 2];
    float nrm = sqrtf(dx * dx + dy * dy + dz * dz);
    float m = fmaxf(nrm, 1e-12f);
    nd[tid * 3] = dx / m; nd[tid * 3 + 1] = dy / m; nd[tid * 3 + 2] = dz / m;
  }
  __syncthreads();
  {
    int e = tid;
    float s0 = sd[e], s1 = sd[128 + e], s2 = sd[256 + e];
    float me = 0.0f;
#pragma unroll
    for (int n = 0; n < NEI; ++n) {
      float th = nd[3 * n] * s0 + nd[3 * n + 1] * s1 + nd[3 * n + 2] * s2;
      th = fmaxf(th, 0.0f);
      me = fmaxf(me, th);
    }
    mcol[e] = me;
  }
  __syncthreads();
  if (tid < 32) {
    float o = mcol[tid] + mcol[32 + tid] + mcol[64 + tid] + mcol[96 + tid];
    o = fmaxf(o, 0.0f);
    fm[(size_t)row * 32 + tid] = o;
  }
}

// fp32 tiled GEMM 64x64x16 (layer1): split output — center fp32, support fp16.
__global__ __launch_bounds__(256) void k_gemm_bias(const float* __restrict__ A,
                                                   const float* __restrict__ W,
                                                   const float* __restrict__ bias,
                                                   float* __restrict__ fc,
                                                   _Float16* __restrict__ fs,
                                                   int M, int N, int K, int Cc) {
  __shared__ float As[16][68];
  __shared__ float Bs[16][68];
  int n0 = blockIdx.x * 64, m0 = blockIdx.y * 64;
  int tx = threadIdx.x & 15, ty = threadIdx.x >> 4;
  float acc[4][4] = {};
  for (int k0 = 0; k0 < K; k0 += 16) {
    for (int t = threadIdx.x; t < 1024; t += 256) {
      int mm = t >> 4, kk = t & 15;
      int m = m0 + mm;
      As[kk][mm] = (m < M) ? A[(size_t)m * K + (k0 + kk)] : 0.0f;
    }
    for (int t = threadIdx.x; t < 1024; t += 256) {
      int kk = t >> 6, nn = t & 63;
      int n = n0 + nn;
      Bs[kk][nn] = (n < N) ? san(W[(size_t)(k0 + kk) * N + n]) : 0.0f;
    }
    __syncthreads();
#pragma unroll
    for (int kk = 0; kk < 16; ++kk) {
      float4 av = *(const float4*)&As[kk][ty << 2];
      float4 bv = *(const float4*)&Bs[kk][tx << 2];
      float a[4] = {av.x, av.y, av.z, av.w};
      float bb[4] = {bv.x, bv.y, bv.z, bv.w};
#pragma unroll
      for (int i = 0; i < 4; ++i)
#pragma unroll
        for (int j = 0; j < 4; ++j) acc[i][j] += a[i] * bb[j];
    }
    __syncthreads();
  }
  int SW = N - Cc;
  for (int i = 0; i < 4; ++i)
    for (int j = 0; j < 4; ++j) {
      int m = m0 + (ty << 2) + i, n = n0 + (tx << 2) + j;
      if (m < M && n < N) {
        float val = acc[i][j] + san(bias[n]);
        if (n < Cc) fc[(size_t)m * Cc + n] = val;
        else fs[(size_t)m * SW + (n - Cc)] = (_Float16)val;
      }
    }
}

// ===================== split-bf16 MFMA GEMM path =====================
typedef __attribute__((ext_vector_type(8))) short v8h;
typedef __attribute__((ext_vector_type(4))) float v4f;

// RNE fp32 -> bf16 bit pattern (inputs finite: san'd or internally produced)
__device__ __forceinline__ unsigned short f2bf(float f) {
  unsigned u = __float_as_uint(f);
  u = u + 0x7FFFu + ((u >> 16) & 1u);
  return (unsigned short)(u >> 16);
}
__device__ __forceinline__ float bf2f(unsigned short h) {
  return __uint_as_float((unsigned)h << 16);
}

// merged weight transpose+split for W2/W3/W4 in ONE dispatch (grid-segmented).
// Per 32x32 tile: W [K][N] fp32 (san) -> WhT, WlT [N][K] bf16 bits.
__global__ __launch_bounds__(256) void k_split_wT_all(
    const float* __restrict__ W2, unsigned short* __restrict__ w2h, unsigned short* __restrict__ w2l,
    const float* __restrict__ W3, unsigned short* __restrict__ w3h, unsigned short* __restrict__ w3l,
    const float* __restrict__ W4, unsigned short* __restrict__ w4h, unsigned short* __restrict__ w4l) {
  // W2: K=64,N=640 -> 20x2=40 tiles; W3: K=128,N=1280 -> 40x4=160; W4: K=256,N=5120 -> 160x8=1280
  int blk = blockIdx.x;
  const float* W; unsigned short *hiT, *loT; int K, N, nt, local;
  if (blk < 40)        { W = W2; hiT = w2h; loT = w2l; K = 64;  N = 640;  nt = 20;  local = blk; }
  else if (blk < 200)  { W = W3; hiT = w3h; loT = w3l; K = 128; N = 1280; nt = 40;  local = blk - 40; }
  else                 { W = W4; hiT = w4h; loT = w4l; K = 256; N = 5120; nt = 160; local = blk - 200; }
  int n0 = (local % nt) * 32, k0 = (local / nt) * 32;
  __shared__ float tile[32][33];
  int tx = threadIdx.x & 31, ty4 = threadIdx.x >> 5;
#pragma unroll
  for (int j = 0; j < 4; ++j)
    tile[ty4 * 4 + j][tx] = san(W[(size_t)(k0 + ty4 * 4 + j) * N + n0 + tx]);
  __syncthreads();
#pragma unroll
  for (int j = 0; j < 4; ++j) {
    int n = n0 + ty4 * 4 + j;
    float a = tile[tx][ty4 * 4 + j];
    unsigned short h = f2bf(a);
    hiT[(size_t)n * K + k0 + tx] = h;
    loT[(size_t)n * K + k0 + tx] = f2bf(a - bf2f(h));
  }
}

// C = A*W + bias via 3-term split-bf16 MFMA (R20-proven, absmax 9.77e-4).
// Output split: center cols [0,Cc) -> fc fp32; support cols [Cc,N) -> fs fp16.
__global__ __launch_bounds__(256) void k_gemm128_mfma(
    const unsigned short* __restrict__ Ah, const unsigned short* __restrict__ Al,
    const unsigned short* __restrict__ BhT, const unsigned short* __restrict__ BlT,
    const float* __restrict__ bias, float* __restrict__ fc, _Float16* __restrict__ fs,
    int M, int N, int K, int Cc) {
  __shared__ __attribute__((aligned(16))) unsigned short sAh[128 * 40];
  __shared__ __attribute__((aligned(16))) unsigned short sAl[128 * 40];
  __shared__ __attribute__((aligned(16))) unsigned short sBh[128 * 40];
  __shared__ __attribute__((aligned(16))) unsigned short sBl[128 * 40];
  const int n0 = blockIdx.x * 128, m0 = blockIdx.y * 128;
  const int l = threadIdx.x & 63;
  const int w = threadIdx.x >> 6;
  const int wr = (w >> 1) * 64, wc = (w & 1) * 64;
  const int lr = l & 15;
  const int kb8 = (l >> 4) * 8;

  v4f acc[4][4];
#pragma unroll
  for (int i = 0; i < 4; ++i)
#pragma unroll
    for (int j = 0; j < 4; ++j) acc[i][j] = (v4f){0.f, 0.f, 0.f, 0.f};

  for (int k0 = 0; k0 < K; k0 += 32) {
#pragma unroll
    for (int q = 0; q < 2; ++q) {
      int lin = (int)threadIdx.x + (q << 8);
      int r = lin >> 2, kc = (lin & 3) << 3;
      *(uint4*)&sAh[r * 40 + kc] = *(const uint4*)&Ah[(size_t)(m0 + r) * K + k0 + kc];
      *(uint4*)&sAl[r * 40 + kc] = *(const uint4*)&Al[(size_t)(m0 + r) * K + k0 + kc];
      *(uint4*)&sBh[r * 40 + kc] = *(const uint4*)&BhT[(size_t)(n0 + r) * K + k0 + kc];
      *(uint4*)&sBl[r * 40 + kc] = *(const uint4*)&BlT[(size_t)(n0 + r) * K + k0 + kc];
    }
    __syncthreads();
    v8h fah[4], fal[4], fbh[4], fbl[4];
#pragma unroll
    for (int t = 0; t < 4; ++t) {
      fah[t] = *(const v8h*)&sAh[(wr + t * 16 + lr) * 40 + kb8];
      fal[t] = *(const v8h*)&sAl[(wr + t * 16 + lr) * 40 + kb8];
      fbh[t] = *(const v8h*)&sBh[(wc + t * 16 + lr) * 40 + kb8];
      fbl[t] = *(const v8h*)&sBl[(wc + t * 16 + lr) * 40 + kb8];
    }
#pragma unroll
    for (int i = 0; i < 4; ++i)
#pragma unroll
      for (int j = 0; j < 4; ++j) {
        acc[i][j] = __builtin_amdgcn_mfma_f32_16x16x32_bf16(fah[i], fbh[j], acc[i][j], 0, 0, 0);
        acc[i][j] = __builtin_amdgcn_mfma_f32_16x16x32_bf16(fah[i], fbl[j], acc[i][j], 0, 0, 0);
        acc[i][j] = __builtin_amdgcn_mfma_f32_16x16x32_bf16(fal[i], fbh[j], acc[i][j], 0, 0, 0);
      }
    __syncthreads();
  }
  float bs[4];
#pragma unroll
  for (int j = 0; j < 4; ++j) bs[j] = san(bias[n0 + wc + j * 16 + lr]);
  const int rowb = m0 + wr + (l >> 4) * 4;
  if (n0 + 128 <= Cc) {  // whole block in center region (fp32)
#pragma unroll
    for (int i = 0; i < 4; ++i)
#pragma unroll
      for (int j = 0; j < 4; ++j) {
        int col = n0 + wc + j * 16 + lr;
#pragma unroll
        for (int v = 0; v < 4; ++v)
          fc[(size_t)(rowb + i * 16 + v) * Cc + col] = acc[i][j][v] + bs[j];
      }
  } else {               // whole block in support region (fp16)
    int SW = N - Cc;
#pragma unroll
    for (int i = 0; i < 4; ++i)
#pragma unroll
      for (int j = 0; j < 4; ++j) {
        int col = n0 + wc + j * 16 + lr - Cc;
#pragma unroll
        for (int v = 0; v < 4; ++v)
          fs[(size_t)(rowb + i * 16 + v) * SW + col] = (_Float16)(acc[i][j][v] + bs[j]);
      }
  }
}

// conv layer (scalar gather, R15-proven structure): center fp32, support fp16.
__global__ __launch_bounds__(256) void k_conv_layer(const float* __restrict__ fc,
                                                    const _Float16* __restrict__ fs,
                                                    const float* __restrict__ verts,
                                                    const int* __restrict__ nidx,
                                                    const float* __restrict__ sd,
                                                    float* __restrict__ outf,
                                                    int V, int C, int relu_out) {
  int row = blockIdx.x;
  int b = row / V, v = row % V;
  int E = 4 * C;
  extern __shared__ float sm[];
  float* mcol = sm;
  float* nd = sm + E;
  int* jr = (int*)(nd + 60);
  int tid = threadIdx.x;
  const float* vb = verts + (size_t)b * V * 3;
  if (tid < NEI) {
    int j = nidx[(size_t)row * NEI + tid];
    jr[tid] = j;
    float dx = vb[3 * j] - vb[3 * v];
    float dy = vb[3 * j + 1] - vb[3 * v + 1];
    float dz = vb[3 * j + 2] - vb[3 * v + 2];
    float nrm = sqrtf(dx * dx + dy * dy + dz * dz);
    float m = fmaxf(nrm, 1e-12f);
    nd[tid * 3] = dx / m; nd[tid * 3 + 1] = dy / m; nd[tid * 3 + 2] = dz / m;
  }
  __syncthreads();
  size_t fb = (size_t)b * V;
  for (int e = tid; e < E; e += blockDim.x) {
    float s0 = sd[e], s1 = sd[E + e], s2 = sd[2 * E + e];
    float me = -INFINITY;
#pragma unroll
    for (int n = 0; n < NEI; ++n) {
      float th = nd[3 * n] * s0 + nd[3 * n + 1] * s1 + nd[3 * n + 2] * s2;
      th = fmaxf(th, 0.0f);
      float fv = (float)fs[(fb + jr[n]) * (size_t)E + e];
      me = fmaxf(me, th * fv);
    }
    mcol[e] = me;
  }
  __syncthreads();
  for (int c = tid; c < C; c += blockDim.x) {
    float o = fc[(size_t)row * C + c] + mcol[c] + mcol[C + c] + mcol[2 * C + c] + mcol[3 * C + c];
    if (relu_out) o = fmaxf(o, 0.0f);
    outf[(size_t)row * C + c] = o;
  }
}

// conv layer variant writing split-bf16 output (consumer is the next GEMM's
// A operand only — identical f2bf arithmetic as the removed k_split pass).
__global__ __launch_bounds__(256) void k_conv_layer_split(const float* __restrict__ fc,
                                                          const _Float16* __restrict__ fs,
                                                          const float* __restrict__ verts,
                                                          const int* __restrict__ nidx,
                                                          const float* __restrict__ sd,
                                                          unsigned short* __restrict__ outh,
                                                          unsigned short* __restrict__ outl,
                                                          int V, int C, int relu_out) {
  int row = blockIdx.x;
  int b = row / V, v = row % V;
  int E = 4 * C;
  extern __shared__ float sm[];
  float* mcol = sm;
  float* nd = sm + E;
  int* jr = (int*)(nd + 60);
  int tid = threadIdx.x;
  const float* vb = verts + (size_t)b * V * 3;
  if (tid < NEI) {
    int j = nidx[(size_t)row * NEI + tid];
    jr[tid] = j;
    float dx = vb[3 * j] - vb[3 * v];
    float dy = vb[3 * j + 1] - vb[3 * v + 1];
    float dz = vb[3 * j + 2] - vb[3 * v + 2];
    float nrm = sqrtf(dx * dx + dy * dy + dz * dz);
    float m = fmaxf(nrm, 1e-12f);
    nd[tid * 3] = dx / m; nd[tid * 3 + 1] = dy / m; nd[tid * 3 + 2] = dz / m;
  }
  __syncthreads();
  size_t fb = (size_t)b * V;
  for (int e = tid; e < E; e += blockDim.x) {
    float s0 = sd[e], s1 = sd[E + e], s2 = sd[2 * E + e];
    float me = -INFINITY;
#pragma unroll
    for (int n = 0; n < NEI; ++n) {
      float th = nd[3 * n] * s0 + nd[3 * n + 1] * s1 + nd[3 * n + 2] * s2;
      th = fmaxf(th, 0.0f);
      float fv = (float)fs[(fb + jr[n]) * (size_t)E + e];
      me = fmaxf(me, th * fv);
    }
    mcol[e] = me;
  }
  __syncthreads();
  for (int c = tid; c < C; c += blockDim.x) {
    float o = fc[(size_t)row * C + c] + mcol[c] + mcol[C + c] + mcol[2 * C + c] + mcol[3 * C + c];
    if (relu_out) o = fmaxf(o, 0.0f);
    unsigned short h = f2bf(o);
    outh[(size_t)row * C + c] = h;
    outl[(size_t)row * C + c] = f2bf(o - bf2f(h));
  }
}

// 1024-thread clone for the layer-4 conv (same work assignment -> same values)
__global__ __launch_bounds__(1024) void k_conv_layer_big(const float* __restrict__ fc,
                                                         const _Float16* __restrict__ fs,
                                                         const float* __restrict__ verts,
                                                         const int* __restrict__ nidx,
                                                         const float* __restrict__ sd,
                                                         float* __restrict__ outf,
                                                         int V, int C, int relu_out) {
  int row = blockIdx.x;
  int b = row / V, v = row % V;
  int E = 4 * C;
  extern __shared__ float sm[];
  float* mcol = sm;
  float* nd = sm + E;
  int* jr = (int*)(nd + 60);
  int tid = threadIdx.x;
  const float* vb = verts + (size_t)b * V * 3;
  if (tid < NEI) {
    int j = nidx[(size_t)row * NEI + tid];
    jr[tid] = j;
    float dx = vb[3 * j] - vb[3 * v];
    float dy = vb[3 * j + 1] - vb[3 * v + 1];
    float dz = vb[3 * j + 2] - vb[3 * v + 2];
    float nrm = sqrtf(dx * dx + dy * dy + dz * dz);
    float m = fmaxf(nrm, 1e-12f);
    nd[tid * 3] = dx / m; nd[tid * 3 + 1] = dy / m; nd[tid * 3 + 2] = dz / m;
  }
  __syncthreads();
  size_t fb = (size_t)b * V;
  for (int e = tid; e < E; e += blockDim.x) {
    float s0 = sd[e], s1 = sd[E + e], s2 = sd[2 * E + e];
    float me = -INFINITY;
#pragma unroll
    for (int n = 0; n < NEI; ++n) {
      float th = nd[3 * n] * s0 + nd[3 * n + 1] * s1 + nd[3 * n + 2] * s2;
      th = fmaxf(th, 0.0f);
      float fv = (float)fs[(fb + jr[n]) * (size_t)E + e];
      me = fmaxf(me, th * fv);
    }
    mcol[e] = me;
  }
  __syncthreads();
  for (int c = tid; c < C; c += blockDim.x) {
    float o = fc[(size_t)row * C + c] + mcol[c] + mcol[C + c] + mcol[2 * C + c] + mcol[3 * C + c];
    if (relu_out) o = fmaxf(o, 0.0f);
    outf[(size_t)row * C + c] = o;
  }
}

// transpose (B, V, C) -> (B, C, V), 32x32 LDS tiles, coalesced both sides
__global__ __launch_bounds__(256) void k_transpose_vc(const float* __restrict__ in,
                                                      float* __restrict__ out,
                                                      int V, int C) {
  __shared__ float tile[32][33];
  int b = blockIdx.z;
  int c0 = blockIdx.x * 32, v0 = blockIdx.y * 32;
  int tx = threadIdx.x & 31, ty4 = threadIdx.x >> 5;
#pragma unroll
  for (int j = 0; j < 4; ++j) {
    int v = v0 + ty4 * 4 + j;
    tile[ty4 * 4 + j][tx] = in[((size_t)b * V + v) * C + c0 + tx];
  }
  __syncthreads();
#pragma unroll
  for (int j = 0; j < 4; ++j) {
    int c = c0 + ty4 * 4 + j;
    out[((size_t)b * C + c) * V + v0 + tx] = tile[tx][ty4 * 4 + j];
  }
}

// fused pool + pooled-vertex gather, writing split-bf16 output directly
// (pool output is consumed only by the next GEMM's A operand; split math
// identical to the removed k_split pass -> bit-identical pipeline).
__global__ void k_pool_sel_split(const float* __restrict__ fm, const int* __restrict__ nidx,
                                 const int* __restrict__ sel,
                                 unsigned short* __restrict__ outh,
                                 unsigned short* __restrict__ outl,
                                 const float* __restrict__ vinA, float* __restrict__ voutA,
                                 float4* __restrict__ pkout,
                                 int Vin, int Vout, int C) {
  int t = blockIdx.x * blockDim.x + threadIdx.x;
  if (t < 4 * Vout) {
    int p = t % Vout;
    int b = t / Vout;
    int src = b * Vin + sel[p];
    float x = vinA[3 * src], y = vinA[3 * src + 1], z = vinA[3 * src + 2];
    int dst = b * Vout + p;
    voutA[3 * dst] = x; voutA[3 * dst + 1] = y; voutA[3 * dst + 2] = z;
    pkout[dst] = make_float4(x, y, z, x * x + y * y + z * z);
  }
  int total = 4 * Vout * C;
  if (t >= total) return;
  int c = t % C;
  int p = (t / C) % Vout;
  int b = t / (C * Vout);
  int sv = sel[p];
  const int* ir = nidx + ((size_t)b * Vin + sv) * NEI;
  float m = -INFINITY;
#pragma unroll
  for (int n = 0; n < NEI; ++n)
    m = fmaxf(m, fm[((size_t)b * Vin + ir[n]) * C + c]);
  size_t o = ((size_t)b * Vout + p) * C + c;
  unsigned short h = f2bf(m);
  outh[o] = h;
  outl[o] = f2bf(m - bf2f(h));
}

// ===================== launch =====================
extern "C" void kernel_launch(void* const* d_in, const int* in_sizes, int n_in,
                              void* d_out, int out_size, void* d_ws, size_t ws_size,
                              hipStream_t stream) {
  (void)in_sizes; (void)n_in; (void)out_size; (void)ws_size;
  const int B = 4, V1 = 4096, V2 = 1024, V3 = 256;

  const float* vin   = (const float*)d_in[0];
  const float* dirs0 = (const float*)d_in[1];
  const float* W1 = (const float*)d_in[2];
  const float* b1 = (const float*)d_in[3];
  const float* D1 = (const float*)d_in[4];
  const float* W2 = (const float*)d_in[5];
  const float* b2 = (const float*)d_in[6];
  const float* D2 = (const float*)d_in[7];
  const float* W3 = (const float*)d_in[8];
  const float* b3 = (const float*)d_in[9];
  const float* D3 = (const float*)d_in[10];
  const float* W4 = (const float*)d_in[11];
  const float* b4 = (const float*)d_in[12];
  const float* D4 = (const float*)d_in[13];
  float* out = (float*)d_out;

  char* ws = (char*)d_ws;
  size_t off = 0;
  auto alloc = [&](size_t bytes) -> char* {
    char* p = ws + off;
    off = (off + bytes + 255) & ~(size_t)255;
    return p;
  };
  int* sel1 = (int*)alloc((size_t)V2 * 4);
  int* sel2 = (int*)alloc((size_t)V3 * 4);
  float* verts1 = (float*)alloc((size_t)B * V1 * 3 * 4);
  float* verts2 = (float*)alloc((size_t)B * V2 * 3 * 4);
  float* verts3 = (float*)alloc((size_t)B * V3 * 3 * 4);
  float4* pk1 = (float4*)alloc((size_t)B * V1 * 16);
  float4* pk2 = (float4*)alloc((size_t)B * V2 * 16);
  float4* pk3 = (float4*)alloc((size_t)B * V3 * 16);
  int* idx1 = (int*)alloc((size_t)B * V1 * NEI * 4);
  int* idx2 = (int*)alloc((size_t)B * V2 * NEI * 4);
  int* idx3 = (int*)alloc((size_t)B * V3 * NEI * 4);
  float* sd0 = (float*)alloc(3 * 128 * 4);
  float* sd1 = (float*)alloc(3 * 256 * 4);
  float* sd2 = (float*)alloc(3 * 512 * 4);
  float* sd3 = (float*)alloc(3 * 1024 * 4);
  float* sd4 = (float*)alloc(3 * 4096 * 4);
  float* bufA = (float*)alloc((size_t)B * V1 * 32 * 4);
  float* bufB = (float*)alloc((size_t)B * V1 * 64 * 4);
  // split GEMM output: center fp32 + support fp16
  float* fcb = (float*)alloc((size_t)B * V1 * 64 * 4);        // >= all center sizes
  _Float16* fsb = (_Float16*)alloc((size_t)B * V1 * 256 * 2); // >= all support sizes
  // split-bf16 buffers (MFMA GEMM path)
  unsigned short* w2hT = (unsigned short*)alloc((size_t)640 * 64 * 2);
  unsigned short* w2lT = (unsigned short*)alloc((size_t)640 * 64 * 2);
  unsigned short* w3hT = (unsigned short*)alloc((size_t)1280 * 128 * 2);
  unsigned short* w3lT = (unsigned short*)alloc((size_t)1280 * 128 * 2);
  unsigned short* w4hT = (unsigned short*)alloc((size_t)5120 * 256 * 2);
  unsigned short* w4lT = (unsigned short*)alloc((size_t)5120 * 256 * 2);
  unsigned short* aSh = (unsigned short*)alloc((size_t)4096 * 128 * 2);
  unsigned short* aSl = (unsigned short*)alloc((size_t)4096 * 128 * 2);
  float* fm0 = bufA;
  float* fm1 = bufB, *fm3 = bufB;
  float* conv4out = bufB;

  static int perm1[4096];
  static int perm2[1024];
  static int selh[1280];
  jax_permutation(42u, 4096, 2, perm1);
  jax_permutation(43u, 1024, 1, perm2);
  memcpy(selh, perm1, 1024 * sizeof(int));
  memcpy(selh + 1024, perm2, 256 * sizeof(int));
  hipMemcpyAsync(sel1, selh, 1024 * sizeof(int), hipMemcpyHostToDevice, stream);
  hipMemcpyAsync(sel2, selh + 1024, 256 * sizeof(int), hipMemcpyHostToDevice, stream);

  // fused sanitize + dirs normalize
  k_setup<<<88, 256, 0, stream>>>(vin, verts1, pk1, B * V1,
                                  dirs0, D1, D2, D3, D4, sd0, sd1, sd2, sd3, sd4);
  // merged weight transpose+split (W2,W3,W4) — one dispatch
  k_split_wT_all<<<1480, 256, 0, stream>>>(W2, w2hT, w2lT, W3, w3hT, w3lT, W4, w4hT, w4lT);
  // knn level 1 (VCAND = 64), 2 queries/wave, 8 queries/block
  k_knn8<64><<<B * V1 / 8, 256, 0, stream>>>(pk1, idx1, V1);
  k_conv_surface<<<B * V1, 128, 0, stream>>>(verts1, idx1, sd0, fm0, V1);
  // layer1 (N=320 -> fp32 64-tile GEMM, split center/support output)
  k_gemm_bias<<<dim3(5, 256), 256, 0, stream>>>(fm0, W1, b1, fcb, fsb, B * V1, 320, 32, 64);
  k_conv_layer<<<B * V1, 256, (4 * 64 + 80) * 4, stream>>>(fcb, fsb, verts1, idx1, sd1, fm1, V1, 64, 1);
  // pool1: fused pool + vertex gather + split-bf16 output (feeds gemm2 A)
  {
    int total = B * V2 * 64;
    k_pool_sel_split<<<(total + 255) / 256, 256, 0, stream>>>(fm1, idx1, sel1, aSh, aSl,
                                                              verts1, verts2, pk2,
                                                              V1, V2, 64);
  }
  // knn level 2 (VCAND = 16)
  k_knn8<16><<<B * V2 / 8, 256, 0, stream>>>(pk2, idx2, V2);
  // layer2: 4096x640x64 via split-bf16 MFMA
  k_gemm128_mfma<<<dim3(640 / 128, 4096 / 128), 256, 0, stream>>>(aSh, aSl, w2hT, w2lT, b2, fcb, fsb, B * V2, 640, 64, 128);
  // conv2 writes split-bf16 directly (feeds gemm3 A)
  k_conv_layer_split<<<B * V2, 256, (4 * 128 + 80) * 4, stream>>>(fcb, fsb, verts2, idx2, sd2, aSh, aSl, V2, 128, 1);
  // layer3: 4096x1280x128 via split-bf16 MFMA
  k_gemm128_mfma<<<dim3(1280 / 128, 4096 / 128), 256, 0, stream>>>(aSh, aSl, w3hT, w3lT, b3, fcb, fsb, B * V2, 1280, 128, 256);
  k_conv_layer<<<B * V2, 256, (4 * 256 + 80) * 4, stream>>>(fcb, fsb, verts2, idx2, sd3, fm3, V2, 256, 1);
  // pool2: fused pool + vertex gather + split-bf16 output (feeds gemm4 A)
  {
    int total = B * V3 * 256;
    k_pool_sel_split<<<(total + 255) / 256, 256, 0, stream>>>(fm3, idx2, sel2, aSh, aSl,
                                                              verts2, verts3, pk3,
                                                              V2, V3, 256);
  }
  // knn level 3 (VCAND = 4)
  k_knn8<4><<<B * V3 / 8, 256, 0, stream>>>(pk3, idx3, V3);
  // layer4: 1024x5120x256 via split-bf16 MFMA, conv C=1024, transpose
  k_gemm128_mfma<<<dim3(5120 / 128, 1024 / 128), 256, 0, stream>>>(aSh, aSl, w4hT, w4lT, b4, fcb, fsb, B * V3, 5120, 256, 1024);
  k_conv_layer_big<<<B * V3, 1024, (4 * 1024 + 80) * 4, stream>>>(fcb, fsb, verts3, idx3, sd4, conv4out, V3, 1024, 0);
  k_transpose_vc<<<dim3(1024 / 32, 256 / 32, B), 256, 0, stream>>>(conv4out, out, V3, 1024);
}

// Round 11
// 368.701 us; speedup vs baseline: 1.2568x; 1.0544x over previous
//
#include <hip/hip_runtime.h>
#include <vector>
#include <algorithm>
#include <cstdint>
#include <cstring>
#include <cmath>

// ===================== host-side JAX threefry replication =====================
static inline uint32_t tf_rotl(uint32_t x, int r) { return (x << r) | (x >> (32 - r)); }

static void tf2x32(uint32_t k0, uint32_t k1, uint32_t x0, uint32_t x1,
                   uint32_t* o0, uint32_t* o1) {
  uint32_t ks2 = k0 ^ k1 ^ 0x1BD11BDAu;
  uint32_t v0 = x0 + k0, v1 = x1 + k1;
  static const int R0[4] = {13, 15, 26, 6}, R1[4] = {17, 29, 16, 24};
#define RND4(R) do { for (int i_ = 0; i_ < 4; ++i_) { v0 += v1; v1 = tf_rotl(v1, R[i_]); v1 ^= v0; } } while (0)
  RND4(R0); v0 += k1;  v1 += ks2 + 1u;
  RND4(R1); v0 += ks2; v1 += k0 + 2u;
  RND4(R0); v0 += k0;  v1 += k1 + 3u;
  RND4(R1); v0 += k1;  v1 += ks2 + 4u;
  RND4(R0); v0 += ks2; v1 += k0 + 5u;
#undef RND4
  *o0 = v0; *o1 = v1;
}

static void jax_permutation(uint32_t seed, int n, int rounds, int* x) {
  uint32_t k0 = 0u, k1 = seed;
  for (int i = 0; i < n; ++i) x[i] = i;
  std::vector<uint32_t> bits(n);
  std::vector<int> ord(n), xn(n);
  for (int r = 0; r < rounds; ++r) {
    uint32_t nk0, nk1, sk0, sk1;
    tf2x32(k0, k1, 0u, 0u, &nk0, &nk1);
    tf2x32(k0, k1, 0u, 1u, &sk0, &sk1);
    for (int i = 0; i < n; ++i) {
      uint32_t h, l;
      tf2x32(sk0, sk1, 0u, (uint32_t)i, &h, &l);
      bits[i] = h ^ l;
    }
    for (int i = 0; i < n; ++i) ord[i] = i;
    std::stable_sort(ord.begin(), ord.end(),
                     [&](int a, int b) { return bits[a] < bits[b]; });
    for (int i = 0; i < n; ++i) xn[i] = x[ord[i]];
    memcpy(x, xn.data(), (size_t)n * sizeof(int));
    k0 = nk0; k1 = nk1;
  }
}

// ===================== device kernels =====================
#define NEI 20

typedef _Float16 f16x2 __attribute__((ext_vector_type(2)));

__device__ __forceinline__ float san(float v) {
  v = (v != v) ? 0.0f : v;
  return fmaxf(-1e4f, fminf(v, 1e4f));
}

// fused setup: blocks 0..63 sanitize vertices -> AoS + packed float4{x,y,z,sq};
// blocks 64..87 normalize the 5 direction matrices.
__global__ void k_setup(const float* __restrict__ vin, float* __restrict__ outA,
                        float4* __restrict__ pk, int nverts,
                        const float* __restrict__ d0, const float* __restrict__ d1,
                        const float* __restrict__ d2, const float* __restrict__ d3,
                        const float* __restrict__ d4,
                        float* __restrict__ s0, float* __restrict__ s1,
                        float* __restrict__ s2, float* __restrict__ s3,
                        float* __restrict__ s4) {
  int blk = blockIdx.x;
  if (blk < 64) {
    int i = blk * 256 + threadIdx.x;
    if (i >= nverts) return;
    float x = san(vin[3 * i]), y = san(vin[3 * i + 1]), z = san(vin[3 * i + 2]);
    outA[3 * i] = x; outA[3 * i + 1] = y; outA[3 * i + 2] = z;
    pk[i] = make_float4(x, y, z, x * x + y * y + z * z);
    return;
  }
  int t = (blk - 64) * 256 + threadIdx.x;
  const float* d; float* s; int E, e;
  if (t < 128)       { d = d0; s = s0; E = 128;  e = t; }
  else if (t < 384)  { d = d1; s = s1; E = 256;  e = t - 128; }
  else if (t < 896)  { d = d2; s = s2; E = 512;  e = t - 384; }
  else if (t < 1920) { d = d3; s = s3; E = 1024; e = t - 896; }
  else if (t < 6016) { d = d4; s = s4; E = 4096; e = t - 1920; }
  else return;
  float a = san(d[e]);
  float b = san(d[E + e]);
  float c = san(d[2 * E + e]);
  float nrm = sqrtf(a * a + b * b + c * c);
  float m = fmaxf(nrm, 1e-12f);
  s[e] = a / m; s[E + e] = b / m; s[2 * E + e] = c / m;
}

// total-order map for fp32 bits: monotone u32 for any float (handles negatives)
__device__ __forceinline__ unsigned fmap(float f) {
  unsigned u = __float_as_uint(f);
  return u ^ ((u & 0x80000000u) ? 0xFFFFFFFFu : 0x80000000u);
}

// --- 64-lane u32 min, broadcast via readlane (SGPR, no LDS round-trip) ---
__device__ __forceinline__ unsigned dpp_min_bcast1(unsigned a) {
  unsigned t;
  t = (unsigned)__builtin_amdgcn_update_dpp((int)a, (int)a, 0xB1, 0xF, 0xF, true);
  a = t < a ? t : a;
  t = (unsigned)__builtin_amdgcn_update_dpp((int)a, (int)a, 0x4E, 0xF, 0xF, true);
  a = t < a ? t : a;
  t = (unsigned)__builtin_amdgcn_update_dpp((int)a, (int)a, 0x141, 0xF, 0xF, true);
  a = t < a ? t : a;
  t = (unsigned)__builtin_amdgcn_update_dpp((int)a, (int)a, 0x140, 0xF, 0xF, true);
  a = t < a ? t : a;
  t = (unsigned)__builtin_amdgcn_update_dpp((int)a, (int)a, 0x142, 0xA, 0xF, false);
  a = t < a ? t : a;
  t = (unsigned)__builtin_amdgcn_update_dpp((int)a, (int)a, 0x143, 0xC, 0xF, false);
  a = t < a ? t : a;
  return (unsigned)__builtin_amdgcn_readlane((int)a, 63);
}

__device__ __forceinline__ void dpp_min_bcast2(unsigned& a, unsigned& b) {
  unsigned t0, t1;
#define STEP_DPP(ctrl, rm, bc)                                                           \
  t0 = (unsigned)__builtin_amdgcn_update_dpp((int)a, (int)a, ctrl, rm, 0xF, bc);         \
  t1 = (unsigned)__builtin_amdgcn_update_dpp((int)b, (int)b, ctrl, rm, 0xF, bc);         \
  a = t0 < a ? t0 : a; b = t1 < b ? t1 : b;
  STEP_DPP(0xB1, 0xF, true)
  STEP_DPP(0x4E, 0xF, true)
  STEP_DPP(0x141, 0xF, true)
  STEP_DPP(0x140, 0xF, true)
  STEP_DPP(0x142, 0xA, false)
  STEP_DPP(0x143, 0xC, false)
#undef STEP_DPP
  a = (unsigned)__builtin_amdgcn_readlane((int)a, 63);
  b = (unsigned)__builtin_amdgcn_readlane((int)b, 63);
}

// KNN v10 (R15-proven, ~90 µs): u64-key sorted top-3 queues, float4 loads,
// readlane broadcasts. CLOSED lines: u32 pre-filter (R19); split u64 key
// (R13); dual-queue (R11/R12). Terminal form of this algorithm.
template <int VCAND>
__global__ __launch_bounds__(256, 8) void k_knn8(const float4* __restrict__ pk,
                                                 int* __restrict__ nidx, int V) {
  const int wid = threadIdx.x >> 6;
  const int lane = threadIdx.x & 63;
  const int row0 = blockIdx.x * 8 + wid * 2;
  const int b = row0 / V;
  const int base = b * V;
  const int i0 = row0 % V;

  float xi[2], yi[2], zi[2], sqi[2];
#pragma unroll
  for (int t = 0; t < 2; ++t) {
    float4 q = pk[base + i0 + t];
    xi[t] = q.x; yi[t] = q.y; zi[t] = q.z; sqi[t] = q.w;
  }

  unsigned long long q0[2] = {~0ULL, ~0ULL}, q1[2] = {~0ULL, ~0ULL}, q2[2] = {~0ULL, ~0ULL};
#pragma unroll 4
  for (int c = 0; c < VCAND; ++c) {
    int j = c * 64 + lane;
    float4 cj = pk[base + j];
    float xj = cj.x, yj = cj.y, zj = cj.z, sqj = cj.w;
#pragma unroll
    for (int t = 0; t < 2; ++t) {
      float dot = xi[t] * xj + yi[t] * yj + zi[t] * zj;
      float dd = (sqi[t] + sqj) - 2.0f * dot;
      unsigned long long k = (((unsigned long long)fmap(dd)) << 32) | (unsigned)j;
      if (k < q2[t]) {
        if (k < q1[t]) {
          q2[t] = q1[t];
          if (k < q0[t]) { q1[t] = q0[t]; q0[t] = k; } else { q1[t] = k; }
        } else {
          q2[t] = k;
        }
      }
    }
  }

  for (int r = 0; r < 21; ++r) {
    unsigned h0 = (unsigned)(q0[0] >> 32);
    unsigned h1 = (unsigned)(q0[1] >> 32);
    unsigned m0 = h0, m1 = h1;
    dpp_min_bcast2(m0, m1);
    unsigned long long mk0 = __ballot(h0 == m0);
    unsigned long long mk1 = __ballot(h1 == m1);
    bool win0, win1;
    if (__popcll(mk0) > 1) {  // rare: dist-bit tie across lanes -> index min
      unsigned jj = (h0 == m0) ? (unsigned)q0[0] : 0xFFFFFFFFu;
      unsigned jm = dpp_min_bcast1(jj);
      win0 = (h0 == m0) && ((unsigned)q0[0] == jm);
    } else {
      win0 = (h0 == m0);
    }
    if (__popcll(mk1) > 1) {
      unsigned jj = (h1 == m1) ? (unsigned)q0[1] : 0xFFFFFFFFu;
      unsigned jm = dpp_min_bcast1(jj);
      win1 = (h1 == m1) && ((unsigned)q0[1] == jm);
    } else {
      win1 = (h1 == m1);
    }
    if (win0) {
      if (r > 0) nidx[(size_t)row0 * NEI + (r - 1)] = (int)(unsigned)q0[0];
      unsigned long long bound = q0[0];
      q0[0] = q1[0]; q1[0] = q2[0]; q2[0] = ~0ULL;
      if (q0[0] == ~0ULL) {
        unsigned long long nm = ~0ULL;
        for (int c = 0; c < VCAND; ++c) {
          int j = c * 64 + lane;
          float4 cj = pk[base + j];
          float dot = xi[0] * cj.x + yi[0] * cj.y + zi[0] * cj.z;
          float dd = (sqi[0] + cj.w) - 2.0f * dot;
          unsigned long long k = (((unsigned long long)fmap(dd)) << 32) | (unsigned)j;
          if (k > bound && k < nm) nm = k;
        }
        q0[0] = nm;
      }
    }
    if (win1) {
      if (r > 0) nidx[(size_t)(row0 + 1) * NEI + (r - 1)] = (int)(unsigned)q0[1];
      unsigned long long bound = q0[1];
      q0[1] = q1[1]; q1[1] = q2[1]; q2[1] = ~0ULL;
      if (q0[1] == ~0ULL) {
        unsigned long long nm = ~0ULL;
        for (int c = 0; c < VCAND; ++c) {
          int j = c * 64 + lane;
          float4 cj = pk[base + j];
          float dot = xi[1] * cj.x + yi[1] * cj.y + zi[1] * cj.z;
          float dd = (sqi[1] + cj.w) - 2.0f * dot;
          unsigned long long k = (((unsigned long long)fmap(dd)) << 32) | (unsigned)j;
          if (k > bound && k < nm) nm = k;
        }
        q0[1] = nm;
      }
    }
  }
}

// ===================== split-bf16 helpers =====================
typedef __attribute__((ext_vector_type(8))) short v8h;
typedef __attribute__((ext_vector_type(4))) float v4f;

// RNE fp32 -> bf16 bit pattern (inputs finite: san'd or internally produced)
__device__ __forceinline__ unsigned short f2bf(float f) {
  unsigned u = __float_as_uint(f);
  u = u + 0x7FFFu + ((u >> 16) & 1u);
  return (unsigned short)(u >> 16);
}
__device__ __forceinline__ float bf2f(unsigned short h) {
  return __uint_as_float((unsigned)h << 16);
}

// conv_surface: C=32, E=128. One block (128 thr) per (b,v). Output feeds ONLY
// gemm1's A operand -> write (hi,lo) bf16 split directly (same f2bf math as a
// separate split pass).
__global__ __launch_bounds__(128) void k_conv_surface(const float* __restrict__ verts,
                                                      const int* __restrict__ nidx,
                                                      const float* __restrict__ sd,
                                                      unsigned short* __restrict__ outh,
                                                      unsigned short* __restrict__ outl,
                                                      int V) {
  int row = blockIdx.x;
  int b = row / V, v = row % V;
  const float* vb = verts + (size_t)b * V * 3;
  __shared__ float nd[60];
  __shared__ float mcol[128];
  int tid = threadIdx.x;
  if (tid < NEI) {
    int j = nidx[(size_t)row * NEI + tid];
    float dx = vb[3 * j] - vb[3 * v];
    float dy = vb[3 * j + 1] - vb[3 * v + 1];
    float dz = vb[3 * j + 2] - vb[3 * v + 2];
    float nrm = sqrtf(dx * dx + dy * dy + dz * dz);
    float m = fmaxf(nrm, 1e-12f);
    nd[tid * 3] = dx / m; nd[tid * 3 + 1] = dy / m; nd[tid * 3 + 2] = dz / m;
  }
  __syncthreads();
  {
    int e = tid;
    float s0 = sd[e], s1 = sd[128 + e], s2 = sd[256 + e];
    float me = 0.0f;
#pragma unroll
    for (int n = 0; n < NEI; ++n) {
      float th = nd[3 * n] * s0 + nd[3 * n + 1] * s1 + nd[3 * n + 2] * s2;
      th = fmaxf(th, 0.0f);
      me = fmaxf(me, th);
    }
    mcol[e] = me;
  }
  __syncthreads();
  if (tid < 32) {
    float o = mcol[tid] + mcol[32 + tid] + mcol[64 + tid] + mcol[96 + tid];
    o = fmaxf(o, 0.0f);
    unsigned short h = f2bf(o);
    outh[(size_t)row * 32 + tid] = h;
    outl[(size_t)row * 32 + tid] = f2bf(o - bf2f(h));
  }
}

// merged weight transpose+split for W1/W2/W3/W4 in ONE dispatch.
// W1 padded to 384 N-rows (zeros) so the MFMA kernel's 128-tiles cover N=320.
__global__ __launch_bounds__(256) void k_split_wT_all(
    const float* __restrict__ W1, unsigned short* __restrict__ w1h, unsigned short* __restrict__ w1l,
    const float* __restrict__ W2, unsigned short* __restrict__ w2h, unsigned short* __restrict__ w2l,
    const float* __restrict__ W3, unsigned short* __restrict__ w3h, unsigned short* __restrict__ w3l,
    const float* __restrict__ W4, unsigned short* __restrict__ w4h, unsigned short* __restrict__ w4l) {
  // W1: K=32,N=320(pad 384) -> 12x1 tiles; W2: 20x2=40; W3: 40x4=160; W4: 160x8=1280
  int blk = blockIdx.x;
  const float* W; unsigned short *hiT, *loT; int K, N, Nreal, nt, local;
  if (blk < 12)        { W = W1; hiT = w1h; loT = w1l; K = 32;  N = 384;  Nreal = 320;  nt = 12;  local = blk; }
  else if (blk < 52)   { W = W2; hiT = w2h; loT = w2l; K = 64;  N = 640;  Nreal = 640;  nt = 20;  local = blk - 12; }
  else if (blk < 212)  { W = W3; hiT = w3h; loT = w3l; K = 128; N = 1280; Nreal = 1280; nt = 40;  local = blk - 52; }
  else                 { W = W4; hiT = w4h; loT = w4l; K = 256; N = 5120; Nreal = 5120; nt = 160; local = blk - 212; }
  int n0 = (local % nt) * 32, k0 = (local / nt) * 32;
  __shared__ float tile[32][33];
  int tx = threadIdx.x & 31, ty4 = threadIdx.x >> 5;
  if (n0 >= Nreal) {  // pure padding tile -> zeros
#pragma unroll
    for (int j = 0; j < 4; ++j) {
      int n = n0 + ty4 * 4 + j;
      hiT[(size_t)n * K + k0 + tx] = 0;
      loT[(size_t)n * K + k0 + tx] = 0;
    }
    return;
  }
#pragma unroll
  for (int j = 0; j < 4; ++j)
    tile[ty4 * 4 + j][tx] = san(W[(size_t)(k0 + ty4 * 4 + j) * Nreal + n0 + tx]);
  __syncthreads();
#pragma unroll
  for (int j = 0; j < 4; ++j) {
    int n = n0 + ty4 * 4 + j;
    float a = tile[tx][ty4 * 4 + j];
    unsigned short h = f2bf(a);
    hiT[(size_t)n * K + k0 + tx] = h;
    loT[(size_t)n * K + k0 + tx] = f2bf(a - bf2f(h));
  }
}

// C = A*W + bias via 3-term split-bf16 MFMA (R20-proven, absmax 9.77e-4).
// General per-element epilogue: col<Cc -> fc fp32; Cc<=col<N -> fs fp16;
// col>=N discarded (N-padding for layer1). Bias read guarded by col<N.
__global__ __launch_bounds__(256) void k_gemm128_mfma(
    const unsigned short* __restrict__ Ah, const unsigned short* __restrict__ Al,
    const unsigned short* __restrict__ BhT, const unsigned short* __restrict__ BlT,
    const float* __restrict__ bias, float* __restrict__ fc, _Float16* __restrict__ fs,
    int M, int N, int K, int Cc) {
  __shared__ __attribute__((aligned(16))) unsigned short sAh[128 * 40];
  __shared__ __attribute__((aligned(16))) unsigned short sAl[128 * 40];
  __shared__ __attribute__((aligned(16))) unsigned short sBh[128 * 40];
  __shared__ __attribute__((aligned(16))) unsigned short sBl[128 * 40];
  const int n0 = blockIdx.x * 128, m0 = blockIdx.y * 128;
  const int l = threadIdx.x & 63;
  const int w = threadIdx.x >> 6;
  const int wr = (w >> 1) * 64, wc = (w & 1) * 64;
  const int lr = l & 15;
  const int kb8 = (l >> 4) * 8;

  v4f acc[4][4];
#pragma unroll
  for (int i = 0; i < 4; ++i)
#pragma unroll
    for (int j = 0; j < 4; ++j) acc[i][j] = (v4f){0.f, 0.f, 0.f, 0.f};

  for (int k0 = 0; k0 < K; k0 += 32) {
#pragma unroll
    for (int q = 0; q < 2; ++q) {
      int lin = (int)threadIdx.x + (q << 8);
      int r = lin >> 2, kc = (lin & 3) << 3;
      *(uint4*)&sAh[r * 40 + kc] = *(const uint4*)&Ah[(size_t)(m0 + r) * K + k0 + kc];
      *(uint4*)&sAl[r * 40 + kc] = *(const uint4*)&Al[(size_t)(m0 + r) * K + k0 + kc];
      *(uint4*)&sBh[r * 40 + kc] = *(const uint4*)&BhT[(size_t)(n0 + r) * K + k0 + kc];
      *(uint4*)&sBl[r * 40 + kc] = *(const uint4*)&BlT[(size_t)(n0 + r) * K + k0 + kc];
    }
    __syncthreads();
    v8h fah[4], fal[4], fbh[4], fbl[4];
#pragma unroll
    for (int t = 0; t < 4; ++t) {
      fah[t] = *(const v8h*)&sAh[(wr + t * 16 + lr) * 40 + kb8];
      fal[t] = *(const v8h*)&sAl[(wr + t * 16 + lr) * 40 + kb8];
      fbh[t] = *(const v8h*)&sBh[(wc + t * 16 + lr) * 40 + kb8];
      fbl[t] = *(const v8h*)&sBl[(wc + t * 16 + lr) * 40 + kb8];
    }
#pragma unroll
    for (int i = 0; i < 4; ++i)
#pragma unroll
      for (int j = 0; j < 4; ++j) {
        acc[i][j] = __builtin_amdgcn_mfma_f32_16x16x32_bf16(fah[i], fbh[j], acc[i][j], 0, 0, 0);
        acc[i][j] = __builtin_amdgcn_mfma_f32_16x16x32_bf16(fah[i], fbl[j], acc[i][j], 0, 0, 0);
        acc[i][j] = __builtin_amdgcn_mfma_f32_16x16x32_bf16(fal[i], fbh[j], acc[i][j], 0, 0, 0);
      }
    __syncthreads();
  }
  const int SW = N - Cc;
  float bs[4];
#pragma unroll
  for (int j = 0; j < 4; ++j) {
    int col = n0 + wc + j * 16 + lr;
    bs[j] = (col < N) ? san(bias[col]) : 0.0f;
  }
  const int rowb = m0 + wr + (l >> 4) * 4;
#pragma unroll
  for (int i = 0; i < 4; ++i)
#pragma unroll
    for (int j = 0; j < 4; ++j) {
      int col = n0 + wc + j * 16 + lr;
#pragma unroll
      for (int v = 0; v < 4; ++v) {
        float val = acc[i][j][v] + bs[j];
        int row = rowb + i * 16 + v;
        if (col < Cc) fc[(size_t)row * Cc + col] = val;
        else if (col < N) fs[(size_t)row * SW + (col - Cc)] = (_Float16)val;
      }
    }
}

// conv layer (pair-gather v2): 2 channels/thread via 4B f16x2 loads — same
// 256 B/wave footprint as the R15-proven fp32-scalar config, half the load
// instructions of scalar-fp16 (R21). Per-channel math identical -> bit-exact.
// CLOSED: 16B float4 gather (R16/R17, +22 µs).
__global__ __launch_bounds__(256) void k_conv_layer(const float* __restrict__ fc,
                                                    const _Float16* __restrict__ fs,
                                                    const float* __restrict__ verts,
                                                    const int* __restrict__ nidx,
                                                    const float* __restrict__ sd,
                                                    float* __restrict__ outf,
                                                    int V, int C, int relu_out) {
  int row = blockIdx.x;
  int b = row / V, v = row % V;
  int E = 4 * C;
  extern __shared__ float sm[];
  float* mcol = sm;
  float* nd = sm + E;
  int* jr = (int*)(nd + 60);
  int tid = threadIdx.x;
  const float* vb = verts + (size_t)b * V * 3;
  if (tid < NEI) {
    int j = nidx[(size_t)row * NEI + tid];
    jr[tid] = j;
    float dx = vb[3 * j] - vb[3 * v];
    float dy = vb[3 * j + 1] - vb[3 * v + 1];
    float dz = vb[3 * j + 2] - vb[3 * v + 2];
    float nrm = sqrtf(dx * dx + dy * dy + dz * dz);
    float m = fmaxf(nrm, 1e-12f);
    nd[tid * 3] = dx / m; nd[tid * 3 + 1] = dy / m; nd[tid * 3 + 2] = dz / m;
  }
  __syncthreads();
  size_t fb = (size_t)b * V;
  int H = E >> 1;
  for (int g = tid; g < H; g += blockDim.x) {
    int e = g << 1;
    float2 sp0 = *(const float2*)&sd[e];
    float2 sp1 = *(const float2*)&sd[E + e];
    float2 sp2 = *(const float2*)&sd[2 * E + e];
    float me0 = -INFINITY, me1 = -INFINITY;
#pragma unroll
    for (int n = 0; n < NEI; ++n) {
      float n0 = nd[3 * n], n1 = nd[3 * n + 1], n2 = nd[3 * n + 2];
      f16x2 fv = *(const f16x2*)&fs[(fb + jr[n]) * (size_t)E + e];
      float th0 = fmaxf(n0 * sp0.x + n1 * sp1.x + n2 * sp2.x, 0.0f);
      float th1 = fmaxf(n0 * sp0.y + n1 * sp1.y + n2 * sp2.y, 0.0f);
      me0 = fmaxf(me0, th0 * (float)fv.x);
      me1 = fmaxf(me1, th1 * (float)fv.y);
    }
    mcol[e] = me0; mcol[e + 1] = me1;
  }
  __syncthreads();
  for (int c = tid; c < C; c += blockDim.x) {
    float o = fc[(size_t)row * C + c] + mcol[c] + mcol[C + c] + mcol[2 * C + c] + mcol[3 * C + c];
    if (relu_out) o = fmaxf(o, 0.0f);
    outf[(size_t)row * C + c] = o;
  }
}

// pair-gather conv writing split-bf16 output (feeds next GEMM's A operand)
__global__ __launch_bounds__(256) void k_conv_layer_split(const float* __restrict__ fc,
                                                          const _Float16* __restrict__ fs,
                                                          const float* __restrict__ verts,
                                                          const int* __restrict__ nidx,
                                                          const float* __restrict__ sd,
                                                          unsigned short* __restrict__ outh,
                                                          unsigned short* __restrict__ outl,
                                                          int V, int C, int relu_out) {
  int row = blockIdx.x;
  int b = row / V, v = row % V;
  int E = 4 * C;
  extern __shared__ float sm[];
  float* mcol = sm;
  float* nd = sm + E;
  int* jr = (int*)(nd + 60);
  int tid = threadIdx.x;
  const float* vb = verts + (size_t)b * V * 3;
  if (tid < NEI) {
    int j = nidx[(size_t)row * NEI + tid];
    jr[tid] = j;
    float dx = vb[3 * j] - vb[3 * v];
    float dy = vb[3 * j + 1] - vb[3 * v + 1];
    float dz = vb[3 * j + 2] - vb[3 * v + 2];
    float nrm = sqrtf(dx * dx + dy * dy + dz * dz);
    float m = fmaxf(nrm, 1e-12f);
    nd[tid * 3] = dx / m; nd[tid * 3 + 1] = dy / m; nd[tid * 3 + 2] = dz / m;
  }
  __syncthreads();
  size_t fb = (size_t)b * V;
  int H = E >> 1;
  for (int g = tid; g < H; g += blockDim.x) {
    int e = g << 1;
    float2 sp0 = *(const float2*)&sd[e];
    float2 sp1 = *(const float2*)&sd[E + e];
    float2 sp2 = *(const float2*)&sd[2 * E + e];
    float me0 = -INFINITY, me1 = -INFINITY;
#pragma unroll
    for (int n = 0; n < NEI; ++n) {
      float n0 = nd[3 * n], n1 = nd[3 * n + 1], n2 = nd[3 * n + 2];
      f16x2 fv = *(const f16x2*)&fs[(fb + jr[n]) * (size_t)E + e];
      float th0 = fmaxf(n0 * sp0.x + n1 * sp1.x + n2 * sp2.x, 0.0f);
      float th1 = fmaxf(n0 * sp0.y + n1 * sp1.y + n2 * sp2.y, 0.0f);
      me0 = fmaxf(me0, th0 * (float)fv.x);
      me1 = fmaxf(me1, th1 * (float)fv.y);
    }
    mcol[e] = me0; mcol[e + 1] = me1;
  }
  __syncthreads();
  for (int c = tid; c < C; c += blockDim.x) {
    float o = fc[(size_t)row * C + c] + mcol[c] + mcol[C + c] + mcol[2 * C + c] + mcol[3 * C + c];
    if (relu_out) o = fmaxf(o, 0.0f);
    unsigned short h = f2bf(o);
    outh[(size_t)row * C + c] = h;
    outl[(size_t)row * C + c] = f2bf(o - bf2f(h));
  }
}

// 1024-thread pair-gather clone for the layer-4 conv
__global__ __launch_bounds__(1024) void k_conv_layer_big(const float* __restrict__ fc,
                                                         const _Float16* __restrict__ fs,
                                                         const float* __restrict__ verts,
                                                         const int* __restrict__ nidx,
                                                         const float* __restrict__ sd,
                                                         float* __restrict__ outf,
                                                         int V, int C, int relu_out) {
  int row = blockIdx.x;
  int b = row / V, v = row % V;
  int E = 4 * C;
  extern __shared__ float sm[];
  float* mcol = sm;
  float* nd = sm + E;
  int* jr = (int*)(nd + 60);
  int tid = threadIdx.x;
  const float* vb = verts + (size_t)b * V * 3;
  if (tid < NEI) {
    int j = nidx[(size_t)row * NEI + tid];
    jr[tid] = j;
    float dx = vb[3 * j] - vb[3 * v];
    float dy = vb[3 * j + 1] - vb[3 * v + 1];
    float dz = vb[3 * j + 2] - vb[3 * v + 2];
    float nrm = sqrtf(dx * dx + dy * dy + dz * dz);
    float m = fmaxf(nrm, 1e-12f);
    nd[tid * 3] = dx / m; nd[tid * 3 + 1] = dy / m; nd[tid * 3 + 2] = dz / m;
  }
  __syncthreads();
  size_t fb = (size_t)b * V;
  int H = E >> 1;
  for (int g = tid; g < H; g += blockDim.x) {
    int e = g << 1;
    float2 sp0 = *(const float2*)&sd[e];
    float2 sp1 = *(const float2*)&sd[E + e];
    float2 sp2 = *(const float2*)&sd[2 * E + e];
    float me0 = -INFINITY, me1 = -INFINITY;
#pragma unroll
    for (int n = 0; n < NEI; ++n) {
      float n0 = nd[3 * n], n1 = nd[3 * n + 1], n2 = nd[3 * n + 2];
      f16x2 fv = *(const f16x2*)&fs[(fb + jr[n]) * (size_t)E + e];
      float th0 = fmaxf(n0 * sp0.x + n1 * sp1.x + n2 * sp2.x, 0.0f);
      float th1 = fmaxf(n0 * sp0.y + n1 * sp1.y + n2 * sp2.y, 0.0f);
      me0 = fmaxf(me0, th0 * (float)fv.x);
      me1 = fmaxf(me1, th1 * (float)fv.y);
    }
    mcol[e] = me0; mcol[e + 1] = me1;
  }
  __syncthreads();
  for (int c = tid; c < C; c += blockDim.x) {
    float o = fc[(size_t)row * C + c] + mcol[c] + mcol[C + c] + mcol[2 * C + c] + mcol[3 * C + c];
    if (relu_out) o = fmaxf(o, 0.0f);
    outf[(size_t)row * C + c] = o;
  }
}

// transpose (B, V, C) -> (B, C, V), 32x32 LDS tiles, coalesced both sides
__global__ __launch_bounds__(256) void k_transpose_vc(const float* __restrict__ in,
                                                      float* __restrict__ out,
                                                      int V, int C) {
  __shared__ float tile[32][33];
  int b = blockIdx.z;
  int c0 = blockIdx.x * 32, v0 = blockIdx.y * 32;
  int tx = threadIdx.x & 31, ty4 = threadIdx.x >> 5;
#pragma unroll
  for (int j = 0; j < 4; ++j) {
    int v = v0 + ty4 * 4 + j;
    tile[ty4 * 4 + j][tx] = in[((size_t)b * V + v) * C + c0 + tx];
  }
  __syncthreads();
#pragma unroll
  for (int j = 0; j < 4; ++j) {
    int c = c0 + ty4 * 4 + j;
    out[((size_t)b * C + c) * V + v0 + tx] = tile[tx][ty4 * 4 + j];
  }
}

// fused pool + pooled-vertex gather, writing split-bf16 output directly
__global__ void k_pool_sel_split(const float* __restrict__ fm, const int* __restrict__ nidx,
                                 const int* __restrict__ sel,
                                 unsigned short* __restrict__ outh,
                                 unsigned short* __restrict__ outl,
                                 const float* __restrict__ vinA, float* __restrict__ voutA,
                                 float4* __restrict__ pkout,
                                 int Vin, int Vout, int C) {
  int t = blockIdx.x * blockDim.x + threadIdx.x;
  if (t < 4 * Vout) {
    int p = t % Vout;
    int b = t / Vout;
    int src = b * Vin + sel[p];
    float x = vinA[3 * src], y = vinA[3 * src + 1], z = vinA[3 * src + 2];
    int dst = b * Vout + p;
    voutA[3 * dst] = x; voutA[3 * dst + 1] = y; voutA[3 * dst + 2] = z;
    pkout[dst] = make_float4(x, y, z, x * x + y * y + z * z);
  }
  int total = 4 * Vout * C;
  if (t >= total) return;
  int c = t % C;
  int p = (t / C) % Vout;
  int b = t / (C * Vout);
  int sv = sel[p];
  const int* ir = nidx + ((size_t)b * Vin + sv) * NEI;
  float m = -INFINITY;
#pragma unroll
  for (int n = 0; n < NEI; ++n)
    m = fmaxf(m, fm[((size_t)b * Vin + ir[n]) * C + c]);
  size_t o = ((size_t)b * Vout + p) * C + c;
  unsigned short h = f2bf(m);
  outh[o] = h;
  outl[o] = f2bf(m - bf2f(h));
}

// ===================== launch =====================
extern "C" void kernel_launch(void* const* d_in, const int* in_sizes, int n_in,
                              void* d_out, int out_size, void* d_ws, size_t ws_size,
                              hipStream_t stream) {
  (void)in_sizes; (void)n_in; (void)out_size; (void)ws_size;
  const int B = 4, V1 = 4096, V2 = 1024, V3 = 256;

  const float* vin   = (const float*)d_in[0];
  const float* dirs0 = (const float*)d_in[1];
  const float* W1 = (const float*)d_in[2];
  const float* b1 = (const float*)d_in[3];
  const float* D1 = (const float*)d_in[4];
  const float* W2 = (const float*)d_in[5];
  const float* b2 = (const float*)d_in[6];
  const float* D2 = (const float*)d_in[7];
  const float* W3 = (const float*)d_in[8];
  const float* b3 = (const float*)d_in[9];
  const float* D3 = (const float*)d_in[10];
  const float* W4 = (const float*)d_in[11];
  const float* b4 = (const float*)d_in[12];
  const float* D4 = (const float*)d_in[13];
  float* out = (float*)d_out;

  char* ws = (char*)d_ws;
  size_t off = 0;
  auto alloc = [&](size_t bytes) -> char* {
    char* p = ws + off;
    off = (off + bytes + 255) & ~(size_t)255;
    return p;
  };
  int* sel1 = (int*)alloc((size_t)V2 * 4);
  int* sel2 = (int*)alloc((size_t)V3 * 4);
  float* verts1 = (float*)alloc((size_t)B * V1 * 3 * 4);
  float* verts2 = (float*)alloc((size_t)B * V2 * 3 * 4);
  float* verts3 = (float*)alloc((size_t)B * V3 * 3 * 4);
  float4* pk1 = (float4*)alloc((size_t)B * V1 * 16);
  float4* pk2 = (float4*)alloc((size_t)B * V2 * 16);
  float4* pk3 = (float4*)alloc((size_t)B * V3 * 16);
  int* idx1 = (int*)alloc((size_t)B * V1 * NEI * 4);
  int* idx2 = (int*)alloc((size_t)B * V2 * NEI * 4);
  int* idx3 = (int*)alloc((size_t)B * V3 * NEI * 4);
  float* sd0 = (float*)alloc(3 * 128 * 4);
  float* sd1 = (float*)alloc(3 * 256 * 4);
  float* sd2 = (float*)alloc(3 * 512 * 4);
  float* sd3 = (float*)alloc(3 * 1024 * 4);
  float* sd4 = (float*)alloc(3 * 4096 * 4);
  float* bufB = (float*)alloc((size_t)B * V1 * 64 * 4);
  // split GEMM output: center fp32 + support fp16
  float* fcb = (float*)alloc((size_t)B * V1 * 64 * 4);        // >= all center sizes
  _Float16* fsb = (_Float16*)alloc((size_t)B * V1 * 256 * 2); // >= all support sizes
  // split-bf16 buffers (MFMA GEMM path)
  unsigned short* w1hT = (unsigned short*)alloc((size_t)384 * 32 * 2);
  unsigned short* w1lT = (unsigned short*)alloc((size_t)384 * 32 * 2);
  unsigned short* w2hT = (unsigned short*)alloc((size_t)640 * 64 * 2);
  unsigned short* w2lT = (unsigned short*)alloc((size_t)640 * 64 * 2);
  unsigned short* w3hT = (unsigned short*)alloc((size_t)1280 * 128 * 2);
  unsigned short* w3lT = (unsigned short*)alloc((size_t)1280 * 128 * 2);
  unsigned short* w4hT = (unsigned short*)alloc((size_t)5120 * 256 * 2);
  unsigned short* w4lT = (unsigned short*)alloc((size_t)5120 * 256 * 2);
  unsigned short* aSh = (unsigned short*)alloc((size_t)4096 * 128 * 2);
  unsigned short* aSl = (unsigned short*)alloc((size_t)4096 * 128 * 2);
  float* fm1 = bufB, *fm3 = bufB;
  float* conv4out = bufB;

  static int perm1[4096];
  static int perm2[1024];
  static int selh[1280];
  jax_permutation(42u, 4096, 2, perm1);
  jax_permutation(43u, 1024, 1, perm2);
  memcpy(selh, perm1, 1024 * sizeof(int));
  memcpy(selh + 1024, perm2, 256 * sizeof(int));
  hipMemcpyAsync(sel1, selh, 1024 * sizeof(int), hipMemcpyHostToDevice, stream);
  hipMemcpyAsync(sel2, selh + 1024, 256 * sizeof(int), hipMemcpyHostToDevice, stream);

  // fused sanitize + dirs normalize
  k_setup<<<88, 256, 0, stream>>>(vin, verts1, pk1, B * V1,
                                  dirs0, D1, D2, D3, D4, sd0, sd1, sd2, sd3, sd4);
  // merged weight transpose+split (W1..W4) — one dispatch
  k_split_wT_all<<<1492, 256, 0, stream>>>(W1, w1hT, w1lT, W2, w2hT, w2lT,
                                           W3, w3hT, w3lT, W4, w4hT, w4lT);
  // knn level 1 (VCAND = 64), 2 queries/wave, 8 queries/block
  k_knn8<64><<<B * V1 / 8, 256, 0, stream>>>(pk1, idx1, V1);
  // conv_surface writes split-bf16 (feeds gemm1 A)
  k_conv_surface<<<B * V1, 128, 0, stream>>>(verts1, idx1, sd0, aSh, aSl, V1);
  // layer1: 16384x320x32 via split-bf16 MFMA (N padded to 384 in weights)
  k_gemm128_mfma<<<dim3(3, 128), 256, 0, stream>>>(aSh, aSl, w1hT, w1lT, b1, fcb, fsb, B * V1, 320, 32, 64);
  k_conv_layer<<<B * V1, 128, (4 * 64 + 80) * 4, stream>>>(fcb, fsb, verts1, idx1, sd1, fm1, V1, 64, 1);
  // pool1: fused pool + vertex gather + split-bf16 output (feeds gemm2 A)
  {
    int total = B * V2 * 64;
    k_pool_sel_split<<<(total + 255) / 256, 256, 0, stream>>>(fm1, idx1, sel1, aSh, aSl,
                                                              verts1, verts2, pk2,
                                                              V1, V2, 64);
  }
  // knn level 2 (VCAND = 16)
  k_knn8<16><<<B * V2 / 8, 256, 0, stream>>>(pk2, idx2, V2);
  // layer2: 4096x640x64 via split-bf16 MFMA
  k_gemm128_mfma<<<dim3(640 / 128, 4096 / 128), 256, 0, stream>>>(aSh, aSl, w2hT, w2lT, b2, fcb, fsb, B * V2, 640, 64, 128);
  // conv2 writes split-bf16 directly (feeds gemm3 A)
  k_conv_layer_split<<<B * V2, 256, (4 * 128 + 80) * 4, stream>>>(fcb, fsb, verts2, idx2, sd2, aSh, aSl, V2, 128, 1);
  // layer3: 4096x1280x128 via split-bf16 MFMA
  k_gemm128_mfma<<<dim3(1280 / 128, 4096 / 128), 256, 0, stream>>>(aSh, aSl, w3hT, w3lT, b3, fcb, fsb, B * V2, 1280, 128, 256);
  k_conv_layer<<<B * V2, 256, (4 * 256 + 80) * 4, stream>>>(fcb, fsb, verts2, idx2, sd3, fm3, V2, 256, 1);
  // pool2: fused pool + vertex gather + split-bf16 output (feeds gemm4 A)
  {
    int total = B * V3 * 256;
    k_pool_sel_split<<<(total + 255) / 256, 256, 0, stream>>>(fm3, idx2, sel2, aSh, aSl,
                                                              verts2, verts3, pk3,
                                                              V2, V3, 256);
  }
  // knn level 3 (VCAND = 4)
  k_knn8<4><<<B * V3 / 8, 256, 0, stream>>>(pk3, idx3, V3);
  // layer4: 1024x5120x256 via split-bf16 MFMA, conv C=1024, transpose
  k_gemm128_mfma<<<dim3(5120 / 128, 1024 / 128), 256, 0, stream>>>(aSh, aSl, w4hT, w4lT, b4, fcb, fsb, B * V3, 5120, 256, 1024);
  k_conv_layer_big<<<B * V3, 1024, (4 * 1024 + 80) * 4, stream>>>(fcb, fsb, verts3, idx3, sd4, conv4out, V3, 1024, 0);
  k_transpose_vc<<<dim3(1024 / 32, 256 / 32, B), 256, 0, stream>>>(conv4out, out, V3, 1024);
}